// Round 2
// baseline (1397.317 us; speedup 1.0000x reference)
//
#include <hip/hip_runtime.h>

#define NNODES 128000
#define NEDGES 640000
#define BB 128
#define CC 12
#define DD 128
#define NROWS (BB*CC)   // 1536

// ---------------- CSR build ----------------
__global__ __launch_bounds__(256) void count_edges(const int* __restrict__ col, int* __restrict__ cnt){
    int e = blockIdx.x*256 + threadIdx.x;
    if (e < NEDGES) atomicAdd(&cnt[col[e]], 1);
}

__global__ __launch_bounds__(256) void compute_dinv(const int* __restrict__ cnt, float* __restrict__ dinv){
    int i = blockIdx.x*256 + threadIdx.x;
    if (i < NNODES) dinv[i] = rsqrtf((float)cnt[i] + 1.0f);
}

__global__ __launch_bounds__(256) void scan_a(const int* __restrict__ cnt, int* __restrict__ offs, int* __restrict__ bsum){
    __shared__ int tmp[256];
    int tid = threadIdx.x;
    int g = blockIdx.x*256 + tid;
    int v = cnt[g];
    tmp[tid] = v;
    __syncthreads();
    for (int o=1;o<256;o<<=1){
        int a = (tid>=o)? tmp[tid-o] : 0;
        __syncthreads();
        tmp[tid] += a;
        __syncthreads();
    }
    offs[g] = tmp[tid] - v;           // block-local exclusive
    if (tid==255) bsum[blockIdx.x] = tmp[255];
}

__global__ __launch_bounds__(512) void scan_b(int* __restrict__ bsum, int NB){
    __shared__ int tmp[512];
    int tid = threadIdx.x;
    int v = (tid<NB)? bsum[tid] : 0;
    tmp[tid] = v;
    __syncthreads();
    for (int o=1;o<512;o<<=1){
        int a = (tid>=o)? tmp[tid-o] : 0;
        __syncthreads();
        tmp[tid] += a;
        __syncthreads();
    }
    if (tid<NB) bsum[tid] = tmp[tid] - v;  // exclusive
}

__global__ __launch_bounds__(256) void scan_c(int* __restrict__ offs, const int* __restrict__ bsum){
    int g = blockIdx.x*256 + threadIdx.x;
    offs[g] += bsum[g>>8];
    if (g==0) offs[NNODES] = NEDGES;
}

__global__ __launch_bounds__(256) void fill_csr(const int* __restrict__ row, const int* __restrict__ col,
        const int* __restrict__ offs, int* __restrict__ cur, const float* __restrict__ dinv,
        int* __restrict__ src, float* __restrict__ ew){
    int e = blockIdx.x*256 + threadIdx.x;
    if (e >= NEDGES) return;
    int c = col[e], r = row[e];
    int p = atomicAdd(&cur[c], 1);
    int idx = offs[c] + p;
    src[idx] = r;
    ew[idx] = dinv[r]*dinv[c];
}

// ---------------- input projection: h = x @ in_w.T + in_b ----------------
__global__ __launch_bounds__(256) void in_proj(const float* __restrict__ x, const float* __restrict__ W,
        const float* __restrict__ bias, float* __restrict__ h){
    __shared__ float ws[128*17];
    __shared__ float bs[128];
    int tid = threadIdx.x;
    for (int i=tid;i<2048;i+=256) ws[(i>>4)*17 + (i&15)] = W[i];
    if (tid<128) bs[tid] = bias[tid];
    __syncthreads();
    size_t idx = (size_t)blockIdx.x*256 + tid;
    int m = (int)(idx>>7), n = (int)(idx&127);
    const float4* xr = (const float4*)(x + (size_t)m*16);
    float4 x0=xr[0], x1=xr[1], x2=xr[2], x3=xr[3];
    const float* wr = ws + n*17;
    float a = bs[n];
    a += x0.x*wr[0]+x0.y*wr[1]+x0.z*wr[2]+x0.w*wr[3];
    a += x1.x*wr[4]+x1.y*wr[5]+x1.z*wr[6]+x1.w*wr[7];
    a += x2.x*wr[8]+x2.y*wr[9]+x2.z*wr[10]+x2.w*wr[11];
    a += x3.x*wr[12]+x3.y*wr[13]+x3.z*wr[14]+x3.w*wr[15];
    h[idx] = a;
}

// ---------------- big GEMM: out[m][n] = sum_k A[m][k]*W[n][k] (+bias) ----------------
// M = NNODES, K = N = 128. Tile 64 rows/block, K chunked by 64, transposed LDS staging.
__global__ __launch_bounds__(256) void gemm128(const float* __restrict__ A, const float* __restrict__ W,
        const float* __restrict__ bias, float* __restrict__ out){
    __shared__ __align__(16) float hs[64][68];    // [k][m]
    __shared__ __align__(16) float ws[64][132];   // [k][n]
    int tid = threadIdx.x;
    int m0 = blockIdx.x * 64;
    int tn = tid >> 4, tm = tid & 15;   // 16x16 thread grid: 4 rows x 8 cols each
    float acc[4][8];
    #pragma unroll
    for (int i=0;i<4;++i)
        #pragma unroll
        for (int j=0;j<8;++j) acc[i][j]=0.f;
    for (int kc = 0; kc < 128; kc += 64){
        __syncthreads();
        #pragma unroll
        for (int l = 0; l < 16; ++l){
            int idx = tid + l*256;      // 4096 A elems
            int r = idx >> 6, c = idx & 63;
            hs[c][r] = A[(size_t)(m0+r)*128 + kc + c];
        }
        #pragma unroll
        for (int l = 0; l < 32; ++l){
            int idx = tid + l*256;      // 8192 W elems
            int r = idx >> 6, c = idx & 63;
            ws[c][r] = W[r*128 + kc + c];
        }
        __syncthreads();
        #pragma unroll 4
        for (int k = 0; k < 64; ++k){
            float4 hv = *(const float4*)&hs[k][tm*4];
            float4 w0 = *(const float4*)&ws[k][tn*8];
            float4 w1 = *(const float4*)&ws[k][tn*8+4];
            float hvv[4] = {hv.x,hv.y,hv.z,hv.w};
            float wvv[8] = {w0.x,w0.y,w0.z,w0.w,w1.x,w1.y,w1.z,w1.w};
            #pragma unroll
            for (int i=0;i<4;++i)
                #pragma unroll
                for (int j=0;j<8;++j)
                    acc[i][j] = fmaf(hvv[i], wvv[j], acc[i][j]);
        }
    }
    #pragma unroll
    for (int i=0;i<4;++i){
        size_t m = (size_t)m0 + tm*4 + i;
        float b0 = bias ? bias[tn*8+0] : 0.f;
        float b1 = bias ? bias[tn*8+1] : 0.f;
        float b2 = bias ? bias[tn*8+2] : 0.f;
        float b3 = bias ? bias[tn*8+3] : 0.f;
        float b4 = bias ? bias[tn*8+4] : 0.f;
        float b5 = bias ? bias[tn*8+5] : 0.f;
        float b6 = bias ? bias[tn*8+6] : 0.f;
        float b7 = bias ? bias[tn*8+7] : 0.f;
        float4 o0 = make_float4(acc[i][0]+b0, acc[i][1]+b1, acc[i][2]+b2, acc[i][3]+b3);
        float4 o1 = make_float4(acc[i][4]+b4, acc[i][5]+b5, acc[i][6]+b6, acc[i][7]+b7);
        *(float4*)&out[m*128 + tn*8]     = o0;
        *(float4*)&out[m*128 + tn*8 + 4] = o1;
    }
}

// ---------------- GCN aggregate + LN (+ReLU+residual), in-place on h ----------------
__global__ __launch_bounds__(256) void gcn_agg(float* __restrict__ h, const float* __restrict__ hw,
        const int* __restrict__ offs, const int* __restrict__ src, const float* __restrict__ ew,
        const float* __restrict__ dinv, const float* __restrict__ bias,
        const float* __restrict__ lnw, const float* __restrict__ lnb, int last){
    int node = blockIdx.x*4 + (threadIdx.x>>6);
    int lane = threadIdx.x & 63;
    const float2* hw2 = (const float2*)hw;
    float di = dinv[node];
    float sw = di*di;
    float2 acc = hw2[(size_t)node*64 + lane];
    acc.x *= sw; acc.y *= sw;
    int e0 = offs[node], e1 = offs[node+1];
    for (int e = e0; e < e1; ++e){
        float w = ew[e]; int s = src[e];
        float2 v = hw2[(size_t)s*64 + lane];
        acc.x += w*v.x; acc.y += w*v.y;
    }
    float2 b2 = ((const float2*)bias)[lane];
    acc.x += b2.x; acc.y += b2.y;
    // LayerNorm over 128 dims
    float s = acc.x + acc.y;
    for (int o=32;o>0;o>>=1) s += __shfl_xor(s,o);
    float mean = s * (1.f/128.f);
    float dx = acc.x-mean, dy = acc.y-mean;
    float var = dx*dx + dy*dy;
    for (int o=32;o>0;o>>=1) var += __shfl_xor(var,o);
    float rs = rsqrtf(var*(1.f/128.f) + 1e-5f);
    float2 w2 = ((const float2*)lnw)[lane], lb2 = ((const float2*)lnb)[lane];
    float yx = dx*rs*w2.x + lb2.x;
    float yy = dy*rs*w2.y + lb2.y;
    float2* h2 = (float2*)h;
    if (!last){
        float2 r = h2[(size_t)node*64+lane];
        yx = fmaxf(yx,0.f) + r.x;
        yy = fmaxf(yy,0.f) + r.y;
    }
    h2[(size_t)node*64+lane] = make_float2(yx,yy);
}

// ---------------- decoder small ops ----------------
__global__ __launch_bounds__(256) void bcast_cq(const float* __restrict__ cq, float* __restrict__ t){
    int idx = blockIdx.x*256 + threadIdx.x;  // < 1536*128
    int r = idx >> 7;
    t[idx] = cq[((r % 12)<<7) | (idx&127)];
}

__global__ __launch_bounds__(256) void ln_rows(const float* __restrict__ x, float* __restrict__ y,
        const float* __restrict__ w, const float* __restrict__ b){
    int r = blockIdx.x*4 + (threadIdx.x>>6);
    int lane = threadIdx.x & 63;
    const float2* x2 = (const float2*)(x + (size_t)r*128);
    float2 v = x2[lane];
    float s = v.x+v.y;
    for (int o=32;o>0;o>>=1) s += __shfl_xor(s,o);
    float mean = s*(1.f/128.f);
    float dx=v.x-mean, dy=v.y-mean;
    float var = dx*dx+dy*dy;
    for (int o=32;o>0;o>>=1) var += __shfl_xor(var,o);
    float rs = rsqrtf(var*(1.f/128.f) + 1e-5f);
    float2 w2=((const float2*)w)[lane], b2=((const float2*)b)[lane];
    ((float2*)(y + (size_t)r*128))[lane] = make_float2(dx*rs*w2.x+b2.x, dy*rs*w2.y+b2.y);
}

// flags: 1 = accumulate into out, 2 = relu
__global__ __launch_bounds__(256) void small_gemm(const float* __restrict__ x, const float* __restrict__ W,
        const float* __restrict__ bias, float* __restrict__ out, int R, int K, int NO, int flags){
    int idx = blockIdx.x*256 + threadIdx.x;
    if (idx >= R*NO) return;
    int r = idx / NO, n = idx - r*NO;
    const float4* xr = (const float4*)(x + (size_t)r*K);
    const float4* wr = (const float4*)(W + (size_t)n*K);
    float a = bias ? bias[n] : 0.0f;
    int K4 = K>>2;
    for (int k=0;k<K4;++k){
        float4 xv = xr[k], wv = wr[k];
        a += xv.x*wv.x + xv.y*wv.y + xv.z*wv.z + xv.w*wv.w;
    }
    if (flags & 2) a = fmaxf(a, 0.f);
    if (flags & 1) a += out[idx];
    out[idx] = a;
}

__global__ __launch_bounds__(64) void self_attn(const float* __restrict__ qkv, float* __restrict__ out){
    int b = blockIdx.x >> 2, hh = blockIdx.x & 3;
    int lane = threadIdx.x;
    __shared__ float q[12][32], k[12][32], v[12][32], sc[12][12];
    for (int idx = lane; idx < 12*32; idx += 64){
        int c = idx>>5, d = idx&31;
        size_t base = (size_t)(b*12+c)*384 + hh*32 + d;
        q[c][d] = qkv[base] * 0.17677669529663687f;
        k[c][d] = qkv[base+128];
        v[c][d] = qkv[base+256];
    }
    __syncthreads();
    for (int p = lane; p < 144; p += 64){
        int qi = p/12, ki = p%12;
        float a = 0;
        #pragma unroll
        for (int d=0; d<32; ++d) a += q[qi][d]*k[ki][d];
        sc[qi][ki] = a;
    }
    __syncthreads();
    if (lane < 12){
        float m = -1e30f;
        for (int j=0;j<12;++j) m = fmaxf(m, sc[lane][j]);
        float sum=0;
        for (int j=0;j<12;++j){ float e=__expf(sc[lane][j]-m); sc[lane][j]=e; sum+=e; }
        float inv=1.f/sum;
        for (int j=0;j<12;++j) sc[lane][j]*=inv;
    }
    __syncthreads();
    for (int p = lane; p < 384; p += 64){
        int c = p>>5, d = p&31;
        float a=0;
        #pragma unroll
        for (int j=0;j<12;++j) a += sc[c][j]*v[j][d];
        out[(size_t)(b*12+c)*128 + hh*32 + d] = a;
    }
}

__global__ __launch_bounds__(256) void cross_attn(const float* __restrict__ q,
        const float* __restrict__ K, const float* __restrict__ V, float* __restrict__ out){
    __shared__ float qs[12][32];
    __shared__ float s[12][1000];
    int b = blockIdx.x >> 2, hh = blockIdx.x & 3;
    int tid = threadIdx.x;
    // FIX: block has 256 threads but 384 (c,d) pairs — must stride, not guard.
    for (int p = tid; p < 384; p += 256){
        int c = p>>5, d = p&31;
        qs[c][d] = q[(size_t)(b*12+c)*128 + hh*32 + d] * 0.17677669529663687f;
    }
    __syncthreads();
    const float* Kb = K + (size_t)b*1000*128 + hh*32;
    for (int k = tid; k < 1000; k += 256){
        const float* kr = Kb + (size_t)k*128;
        float acc[12];
        #pragma unroll
        for (int c=0;c<12;++c) acc[c]=0.f;
        for (int d = 0; d < 32; ++d){
            float kv = kr[d];
            #pragma unroll
            for (int c = 0; c < 12; ++c) acc[c] += qs[c][d]*kv;
        }
        #pragma unroll
        for (int c = 0; c < 12; ++c) s[c][k] = acc[c];
    }
    __syncthreads();
    int w = tid>>6, lane = tid&63;
    for (int c = w; c < 12; c += 4){
        float m = -1e30f;
        for (int k = lane; k < 1000; k += 64) m = fmaxf(m, s[c][k]);
        for (int o=32;o>0;o>>=1) m = fmaxf(m, __shfl_xor(m,o));
        float sum = 0;
        for (int k = lane; k < 1000; k += 64){ float e = __expf(s[c][k]-m); s[c][k]=e; sum += e; }
        for (int o=32;o>0;o>>=1) sum += __shfl_xor(sum,o);
        float inv = 1.f/sum;
        for (int k = lane; k < 1000; k += 64) s[c][k] *= inv;
    }
    __syncthreads();
    const float* Vb = V + (size_t)b*1000*128 + hh*32;
    for (int p = tid; p < 384; p += 256){
        int c = p>>5, d = p&31;
        float acc = 0;
        for (int k = 0; k < 1000; ++k) acc += s[c][k]*Vb[(size_t)k*128+d];
        out[(size_t)(b*12+c)*128 + hh*32 + d] = acc;
    }
}

__global__ __launch_bounds__(256) void final_out(const float* __restrict__ t,
        const float* __restrict__ lw, const float* __restrict__ lb,
        const float* __restrict__ ow, const float* __restrict__ ob, float* __restrict__ out){
    int r = blockIdx.x*4 + (threadIdx.x>>6);
    int lane = threadIdx.x & 63;
    const float2* x2 = (const float2*)(t + (size_t)r*128);
    float2 v = x2[lane];
    float s = v.x+v.y;
    for (int o=32;o>0;o>>=1) s += __shfl_xor(s,o);
    float mean = s*(1.f/128.f);
    float dx=v.x-mean, dy=v.y-mean;
    float var = dx*dx+dy*dy;
    for (int o=32;o>0;o>>=1) var += __shfl_xor(var,o);
    float rs = rsqrtf(var*(1.f/128.f)+1e-5f);
    float2 w2=((const float2*)lw)[lane], b2=((const float2*)lb)[lane];
    float2 o2=((const float2*)ow)[lane];
    float d = (dx*rs*w2.x+b2.x)*o2.x + (dy*rs*w2.y+b2.y)*o2.y;
    for (int o=32;o>0;o>>=1) d += __shfl_xor(d,o);
    if (lane==0) out[r] = d + ob[0];
}

extern "C" void kernel_launch(void* const* d_in, const int* in_sizes, int n_in,
                              void* d_out, int out_size, void* d_ws, size_t ws_size,
                              hipStream_t stream){
    (void)in_sizes; (void)n_in; (void)out_size; (void)ws_size;
    const float* x        = (const float*)d_in[0];
    const int*   eidx     = (const int*)d_in[1];
    // d_in[2] (batch) unused: uniform 1000 nodes/graph by construction
    const float* in_w     = (const float*)d_in[3];
    const float* in_b     = (const float*)d_in[4];
    const float* gcn_w    = (const float*)d_in[5];
    const float* gcn_b    = (const float*)d_in[6];
    const float* ln_w     = (const float*)d_in[7];
    const float* ln_b     = (const float*)d_in[8];
    const float* cq       = (const float*)d_in[9];
    const float* sa_qkv_w = (const float*)d_in[10];
    const float* sa_qkv_b = (const float*)d_in[11];
    const float* sa_out_w = (const float*)d_in[12];
    const float* sa_out_b = (const float*)d_in[13];
    const float* ca_qkv_w = (const float*)d_in[14];
    const float* ca_qkv_b = (const float*)d_in[15];
    const float* ca_out_w = (const float*)d_in[16];
    const float* ca_out_b = (const float*)d_in[17];
    const float* n1w=(const float*)d_in[18]; const float* n1b=(const float*)d_in[19];
    const float* n2w=(const float*)d_in[20]; const float* n2b=(const float*)d_in[21];
    const float* n3w=(const float*)d_in[22]; const float* n3b=(const float*)d_in[23];
    const float* ff1w=(const float*)d_in[24]; const float* ff1b=(const float*)d_in[25];
    const float* ff2w=(const float*)d_in[26]; const float* ff2b=(const float*)d_in[27];
    const float* opln_w=(const float*)d_in[28]; const float* opln_b=(const float*)d_in[29];
    const float* opw=(const float*)d_in[30]; const float* opb=(const float*)d_in[31];
    float* out = (float*)d_out;

    char* base = (char*)d_ws;
    size_t off = 0;
    auto alloc = [&](size_t bytes)->void*{
        void* r = base + off; off += (bytes + 255) & ~(size_t)255; return r;
    };
    float* h    = (float*)alloc((size_t)NNODES*DD*4);
    float* hw   = (float*)alloc((size_t)NNODES*DD*4);
    float* vb   = (float*)alloc((size_t)NNODES*DD*4);
    float* dinv = (float*)alloc((size_t)NNODES*4);
    int*   cnt  = (int*)  alloc((size_t)NNODES*4);
    int*   offs = (int*)  alloc((size_t)(NNODES+1)*4);
    int*   bsum = (int*)  alloc(512*4);
    int*   csrc = (int*)  alloc((size_t)NEDGES*4);
    float* cw   = (float*)alloc((size_t)NEDGES*4);
    float* t    = (float*)alloc((size_t)NROWS*DD*4);
    float* tn   = (float*)alloc((size_t)NROWS*DD*4);
    float* sq   = (float*)alloc((size_t)NROWS*384*4);
    float* att  = (float*)alloc((size_t)NROWS*DD*4);
    float* ffh  = (float*)alloc((size_t)NROWS*512*4);

    const int* erow = eidx;
    const int* ecol = eidx + NEDGES;

    // CSR build (once, reused by all 3 GCN layers)
    hipMemsetAsync(cnt, 0, (size_t)NNODES*4, stream);
    count_edges<<<NEDGES/256, 256, 0, stream>>>(ecol, cnt);
    compute_dinv<<<NNODES/256, 256, 0, stream>>>(cnt, dinv);
    scan_a<<<NNODES/256, 256, 0, stream>>>(cnt, offs, bsum);
    scan_b<<<1, 512, 0, stream>>>(bsum, NNODES/256);
    scan_c<<<NNODES/256, 256, 0, stream>>>(offs, bsum);
    hipMemsetAsync(cnt, 0, (size_t)NNODES*4, stream);
    fill_csr<<<NEDGES/256, 256, 0, stream>>>(erow, ecol, offs, cnt, dinv, csrc, cw);

    // node pipeline
    in_proj<<<NNODES*DD/256, 256, 0, stream>>>(x, in_w, in_b, h);
    for (int i=0;i<3;++i){
        gemm128<<<NNODES/64, 256, 0, stream>>>(h, gcn_w + (size_t)i*DD*DD, nullptr, hw);
        gcn_agg<<<NNODES/4, 256, 0, stream>>>(h, hw, offs, csrc, cw, dinv,
                gcn_b + (size_t)i*DD, ln_w + (size_t)i*DD, ln_b + (size_t)i*DD, i==2);
    }
    // cross-attn K,V projections (memory == h reshaped [B,1000,D])
    gemm128<<<NNODES/64, 256, 0, stream>>>(h, ca_qkv_w + DD*DD,   ca_qkv_b + DD,   hw);  // K
    gemm128<<<NNODES/64, 256, 0, stream>>>(h, ca_qkv_w + 2*DD*DD, ca_qkv_b + 2*DD, vb);  // V

    // decoder layer (norm_first)
    bcast_cq<<<NROWS*DD/256, 256, 0, stream>>>(cq, t);
    ln_rows<<<NROWS/4, 256, 0, stream>>>(t, tn, n1w, n1b);
    small_gemm<<<NROWS*384/256, 256, 0, stream>>>(tn, sa_qkv_w, sa_qkv_b, sq, NROWS, 128, 384, 0);
    self_attn<<<BB*4, 64, 0, stream>>>(sq, att);
    small_gemm<<<NROWS*128/256, 256, 0, stream>>>(att, sa_out_w, sa_out_b, t, NROWS, 128, 128, 1);
    ln_rows<<<NROWS/4, 256, 0, stream>>>(t, tn, n2w, n2b);
    small_gemm<<<NROWS*128/256, 256, 0, stream>>>(tn, ca_qkv_w, ca_qkv_b, sq, NROWS, 128, 128, 0);
    cross_attn<<<BB*4, 256, 0, stream>>>(sq, hw, vb, att);
    small_gemm<<<NROWS*128/256, 256, 0, stream>>>(att, ca_out_w, ca_out_b, t, NROWS, 128, 128, 1);
    ln_rows<<<NROWS/4, 256, 0, stream>>>(t, tn, n3w, n3b);
    small_gemm<<<NROWS*512/256, 256, 0, stream>>>(tn, ff1w, ff1b, ffh, NROWS, 128, 512, 2);
    small_gemm<<<NROWS*128/256, 256, 0, stream>>>(ffh, ff2w, ff2b, t, NROWS, 512, 128, 1);
    final_out<<<NROWS/4, 256, 0, stream>>>(t, opln_w, opln_b, opw, opb, out);
}

// Round 3
// 1083.428 us; speedup vs baseline: 1.2897x; 1.2897x over previous
//
#include <hip/hip_runtime.h>

#define NNODES 128000
#define NEDGES 640000
#define BB 128
#define CC 12
#define DD 128
#define NROWS (BB*CC)   // 1536

typedef __attribute__((ext_vector_type(8))) short short8;
typedef __attribute__((ext_vector_type(4))) float f32x4;
typedef unsigned short ushort_t;

__device__ __forceinline__ ushort_t f2bf(float f){
    union { float f; unsigned u; } v; v.f = f;
    unsigned r = (v.u + 0x7FFF + ((v.u >> 16) & 1)) >> 16;  // RNE
    return (ushort_t)r;
}

// ---------------- CSR build ----------------
__global__ __launch_bounds__(256) void count_edges(const int* __restrict__ col, int* __restrict__ cnt){
    int e = blockIdx.x*256 + threadIdx.x;
    if (e < NEDGES) atomicAdd(&cnt[col[e]], 1);
}

__global__ __launch_bounds__(256) void compute_dinv(const int* __restrict__ cnt, float* __restrict__ dinv){
    int i = blockIdx.x*256 + threadIdx.x;
    if (i < NNODES) dinv[i] = rsqrtf((float)cnt[i] + 1.0f);
}

__global__ __launch_bounds__(256) void scan_a(const int* __restrict__ cnt, int* __restrict__ offs, int* __restrict__ bsum){
    __shared__ int tmp[256];
    int tid = threadIdx.x;
    int g = blockIdx.x*256 + tid;
    int v = cnt[g];
    tmp[tid] = v;
    __syncthreads();
    for (int o=1;o<256;o<<=1){
        int a = (tid>=o)? tmp[tid-o] : 0;
        __syncthreads();
        tmp[tid] += a;
        __syncthreads();
    }
    offs[g] = tmp[tid] - v;
    if (tid==255) bsum[blockIdx.x] = tmp[255];
}

__global__ __launch_bounds__(512) void scan_b(int* __restrict__ bsum, int NB){
    __shared__ int tmp[512];
    int tid = threadIdx.x;
    int v = (tid<NB)? bsum[tid] : 0;
    tmp[tid] = v;
    __syncthreads();
    for (int o=1;o<512;o<<=1){
        int a = (tid>=o)? tmp[tid-o] : 0;
        __syncthreads();
        tmp[tid] += a;
        __syncthreads();
    }
    if (tid<NB) bsum[tid] = tmp[tid] - v;
}

__global__ __launch_bounds__(256) void scan_c(int* __restrict__ offs, const int* __restrict__ bsum){
    int g = blockIdx.x*256 + threadIdx.x;
    offs[g] += bsum[g>>8];
    if (g==0) offs[NNODES] = NEDGES;
}

__global__ __launch_bounds__(256) void fill_csr(const int* __restrict__ row, const int* __restrict__ col,
        const int* __restrict__ offs, int* __restrict__ cur, const float* __restrict__ dinv,
        int* __restrict__ src, float* __restrict__ ew){
    int e = blockIdx.x*256 + threadIdx.x;
    if (e >= NEDGES) return;
    int c = col[e], r = row[e];
    int p = atomicAdd(&cur[c], 1);
    int idx = offs[c] + p;
    src[idx] = r;
    ew[idx] = dinv[r]*dinv[c];
}

// ---------------- weight f32 -> bf16 (5 x 128x128: gcn0..2, ca-K, ca-V) ----------------
__global__ __launch_bounds__(256) void conv_w(const float* __restrict__ gcn_w,
        const float* __restrict__ ca_qkv_w, ushort_t* __restrict__ Wb){
    int i = blockIdx.x*256 + threadIdx.x;   // < 5*16384
    int slot = i >> 14, off = i & 16383;
    float v = (slot < 3) ? gcn_w[slot*16384 + off]
                         : ca_qkv_w[16384 + (slot-3)*16384 + off];
    Wb[i] = f2bf(v);
}

// ---------------- input projection: h = x @ in_w.T + in_b (+ bf16 copy) ----------------
__global__ __launch_bounds__(256) void in_proj(const float* __restrict__ x, const float* __restrict__ W,
        const float* __restrict__ bias, float* __restrict__ h, ushort_t* __restrict__ hbf){
    __shared__ float ws[128*17];
    __shared__ float bs[128];
    int tid = threadIdx.x;
    for (int i=tid;i<2048;i+=256) ws[(i>>4)*17 + (i&15)] = W[i];
    if (tid<128) bs[tid] = bias[tid];
    __syncthreads();
    size_t idx = (size_t)blockIdx.x*256 + tid;
    int m = (int)(idx>>7), n = (int)(idx&127);
    const float4* xr = (const float4*)(x + (size_t)m*16);
    float4 x0=xr[0], x1=xr[1], x2=xr[2], x3=xr[3];
    const float* wr = ws + n*17;
    float a = bs[n];
    a += x0.x*wr[0]+x0.y*wr[1]+x0.z*wr[2]+x0.w*wr[3];
    a += x1.x*wr[4]+x1.y*wr[5]+x1.z*wr[6]+x1.w*wr[7];
    a += x2.x*wr[8]+x2.y*wr[9]+x2.z*wr[10]+x2.w*wr[11];
    a += x3.x*wr[12]+x3.y*wr[13]+x3.z*wr[14]+x3.w*wr[15];
    h[idx] = a;
    hbf[idx] = f2bf(a);
}

// ---------------- MFMA GEMM: out[m][n] = sum_k A_bf[m][k]*W_bf[n][k] (+bias) ----------------
// A: [128000][128] bf16, W: [128][128] bf16 row-major (n-major). 64 rows/block, wave->16 rows.
__global__ __launch_bounds__(256) void gemm_mfma(const ushort_t* __restrict__ A,
        const ushort_t* __restrict__ Wb, const float* __restrict__ bias, float* __restrict__ out){
    int lane = threadIdx.x & 63, wave = threadIdx.x >> 6;
    int m0 = blockIdx.x*64 + wave*16;
    int lr = lane & 15;            // row-within-16-tile (A row / W row=n)
    int lk = (lane >> 4) * 8;      // k offset (8 contiguous bf16)
    short8 bfrag[4][8];            // [kc][nt] -- whole W in registers (shared via L2/L1)
    #pragma unroll
    for (int nt=0; nt<8; ++nt)
        #pragma unroll
        for (int kc=0; kc<4; ++kc)
            bfrag[kc][nt] = *(const short8*)&Wb[(nt*16 + lr)*128 + kc*32 + lk];
    f32x4 acc[8];
    #pragma unroll
    for (int nt=0; nt<8; ++nt) acc[nt] = (f32x4){0.f,0.f,0.f,0.f};
    const ushort_t* arow = A + (size_t)(m0 + lr)*128 + lk;
    #pragma unroll
    for (int kc=0; kc<4; ++kc){
        short8 a = *(const short8*)(arow + kc*32);
        #pragma unroll
        for (int nt=0; nt<8; ++nt)
            acc[nt] = __builtin_amdgcn_mfma_f32_16x16x32_bf16(a, bfrag[kc][nt], acc[nt], 0, 0, 0);
    }
    // D: row = (lane>>4)*4 + reg, col = lane&15 (m89-verified)
    size_t orow = (size_t)m0 + (lane>>4)*4;
    #pragma unroll
    for (int nt=0; nt<8; ++nt){
        int col = nt*16 + lr;
        float bv = bias ? bias[col] : 0.f;
        #pragma unroll
        for (int r=0; r<4; ++r)
            out[(orow + r)*128 + col] = acc[nt][r] + bv;
    }
}

// ---------------- GCN aggregate + LN (+ReLU+residual), in-place on h, emits bf16 ----------------
__global__ __launch_bounds__(256) void gcn_agg(float* __restrict__ h, const float* __restrict__ hw,
        const int* __restrict__ offs, const int* __restrict__ src, const float* __restrict__ ew,
        const float* __restrict__ dinv, const float* __restrict__ bias,
        const float* __restrict__ lnw, const float* __restrict__ lnb,
        ushort_t* __restrict__ hbf, int last){
    int node = blockIdx.x*4 + (threadIdx.x>>6);
    int lane = threadIdx.x & 63;
    const float2* hw2 = (const float2*)hw;
    float di = dinv[node];
    float sw = di*di;
    float2 acc = hw2[(size_t)node*64 + lane];
    acc.x *= sw; acc.y *= sw;
    int e0 = offs[node], e1 = offs[node+1];
    for (int e = e0; e < e1; ++e){
        float w = ew[e]; int s = src[e];
        float2 v = hw2[(size_t)s*64 + lane];
        acc.x += w*v.x; acc.y += w*v.y;
    }
    float2 b2 = ((const float2*)bias)[lane];
    acc.x += b2.x; acc.y += b2.y;
    float s = acc.x + acc.y;
    for (int o=32;o>0;o>>=1) s += __shfl_xor(s,o);
    float mean = s * (1.f/128.f);
    float dx = acc.x-mean, dy = acc.y-mean;
    float var = dx*dx + dy*dy;
    for (int o=32;o>0;o>>=1) var += __shfl_xor(var,o);
    float rs = rsqrtf(var*(1.f/128.f) + 1e-5f);
    float2 w2 = ((const float2*)lnw)[lane], lb2 = ((const float2*)lnb)[lane];
    float yx = dx*rs*w2.x + lb2.x;
    float yy = dy*rs*w2.y + lb2.y;
    float2* h2 = (float2*)h;
    if (!last){
        float2 r = h2[(size_t)node*64+lane];
        yx = fmaxf(yx,0.f) + r.x;
        yy = fmaxf(yy,0.f) + r.y;
        h2[(size_t)node*64+lane] = make_float2(yx,yy);
    }
    unsigned pk = (unsigned)f2bf(yx) | ((unsigned)f2bf(yy) << 16);
    ((unsigned*)hbf)[(size_t)node*64 + lane] = pk;
}

// ---------------- decoder small ops ----------------
__global__ __launch_bounds__(256) void bcast_cq(const float* __restrict__ cq, float* __restrict__ t){
    int idx = blockIdx.x*256 + threadIdx.x;
    int r = idx >> 7;
    t[idx] = cq[((r % 12)<<7) | (idx&127)];
}

__global__ __launch_bounds__(256) void ln_rows(const float* __restrict__ x, float* __restrict__ y,
        const float* __restrict__ w, const float* __restrict__ b){
    int r = blockIdx.x*4 + (threadIdx.x>>6);
    int lane = threadIdx.x & 63;
    const float2* x2 = (const float2*)(x + (size_t)r*128);
    float2 v = x2[lane];
    float s = v.x+v.y;
    for (int o=32;o>0;o>>=1) s += __shfl_xor(s,o);
    float mean = s*(1.f/128.f);
    float dx=v.x-mean, dy=v.y-mean;
    float var = dx*dx+dy*dy;
    for (int o=32;o>0;o>>=1) var += __shfl_xor(var,o);
    float rs = rsqrtf(var*(1.f/128.f) + 1e-5f);
    float2 w2=((const float2*)w)[lane], b2=((const float2*)b)[lane];
    ((float2*)(y + (size_t)r*128))[lane] = make_float2(dx*rs*w2.x+b2.x, dy*rs*w2.y+b2.y);
}

// flags: 1 = accumulate into out, 2 = relu
__global__ __launch_bounds__(256) void small_gemm(const float* __restrict__ x, const float* __restrict__ W,
        const float* __restrict__ bias, float* __restrict__ out, int R, int K, int NO, int flags){
    int idx = blockIdx.x*256 + threadIdx.x;
    if (idx >= R*NO) return;
    int r = idx / NO, n = idx - r*NO;
    const float4* xr = (const float4*)(x + (size_t)r*K);
    const float4* wr = (const float4*)(W + (size_t)n*K);
    float a = bias ? bias[n] : 0.0f;
    int K4 = K>>2;
    for (int k=0;k<K4;++k){
        float4 xv = xr[k], wv = wr[k];
        a += xv.x*wv.x + xv.y*wv.y + xv.z*wv.z + xv.w*wv.w;
    }
    if (flags & 2) a = fmaxf(a, 0.f);
    if (flags & 1) a += out[idx];
    out[idx] = a;
}

__global__ __launch_bounds__(64) void self_attn(const float* __restrict__ qkv, float* __restrict__ out){
    int b = blockIdx.x >> 2, hh = blockIdx.x & 3;
    int lane = threadIdx.x;
    __shared__ float q[12][32], k[12][32], v[12][32], sc[12][12];
    for (int idx = lane; idx < 12*32; idx += 64){
        int c = idx>>5, d = idx&31;
        size_t base = (size_t)(b*12+c)*384 + hh*32 + d;
        q[c][d] = qkv[base] * 0.17677669529663687f;
        k[c][d] = qkv[base+128];
        v[c][d] = qkv[base+256];
    }
    __syncthreads();
    for (int p = lane; p < 144; p += 64){
        int qi = p/12, ki = p%12;
        float a = 0;
        #pragma unroll
        for (int d=0; d<32; ++d) a += q[qi][d]*k[ki][d];
        sc[qi][ki] = a;
    }
    __syncthreads();
    if (lane < 12){
        float m = -1e30f;
        for (int j=0;j<12;++j) m = fmaxf(m, sc[lane][j]);
        float sum=0;
        for (int j=0;j<12;++j){ float e=__expf(sc[lane][j]-m); sc[lane][j]=e; sum+=e; }
        float inv=1.f/sum;
        for (int j=0;j<12;++j) sc[lane][j]*=inv;
    }
    __syncthreads();
    for (int p = lane; p < 384; p += 64){
        int c = p>>5, d = p&31;
        float a=0;
        #pragma unroll
        for (int j=0;j<12;++j) a += sc[c][j]*v[j][d];
        out[(size_t)(b*12+c)*128 + hh*32 + d] = a;
    }
}

__global__ __launch_bounds__(256) void cross_attn(const float* __restrict__ q,
        const float* __restrict__ K, const float* __restrict__ V, float* __restrict__ out){
    __shared__ float qs[12][32];
    __shared__ float s[12][1000];
    int b = blockIdx.x >> 2, hh = blockIdx.x & 3;
    int tid = threadIdx.x;
    for (int p = tid; p < 384; p += 256){
        int c = p>>5, d = p&31;
        qs[c][d] = q[(size_t)(b*12+c)*128 + hh*32 + d] * 0.17677669529663687f;
    }
    __syncthreads();
    const float* Kb = K + (size_t)b*1000*128 + hh*32;
    for (int k = tid; k < 1000; k += 256){
        const float4* kr = (const float4*)(Kb + (size_t)k*128);
        float4 kv[8];
        #pragma unroll
        for (int j=0;j<8;++j) kv[j] = kr[j];
        #pragma unroll
        for (int c = 0; c < 12; ++c){
            const float4* qc = (const float4*)qs[c];
            float a = 0.f;
            #pragma unroll
            for (int j=0;j<8;++j){
                float4 qv = qc[j];
                a += kv[j].x*qv.x + kv[j].y*qv.y + kv[j].z*qv.z + kv[j].w*qv.w;
            }
            s[c][k] = a;
        }
    }
    __syncthreads();
    int w = tid>>6, lane = tid&63;
    for (int c = w; c < 12; c += 4){
        float m = -1e30f;
        for (int k = lane; k < 1000; k += 64) m = fmaxf(m, s[c][k]);
        for (int o=32;o>0;o>>=1) m = fmaxf(m, __shfl_xor(m,o));
        float sum = 0;
        for (int k = lane; k < 1000; k += 64){ float e = __expf(s[c][k]-m); s[c][k]=e; sum += e; }
        for (int o=32;o>0;o>>=1) sum += __shfl_xor(sum,o);
        float inv = 1.f/sum;
        for (int k = lane; k < 1000; k += 64) s[c][k] *= inv;
    }
    __syncthreads();
    const float* Vb = V + (size_t)b*1000*128 + hh*32;
    for (int p = tid; p < 384; p += 256){
        int c = p>>5, d = p&31;
        const float* vp = Vb + d;
        const float* sp = &s[c][0];
        float a0=0,a1=0,a2=0,a3=0,a4=0,a5=0,a6=0,a7=0;
        for (int k = 0; k < 1000; k += 8){   // 125 iters, 8 chains in flight
            a0 += sp[k+0]*vp[(size_t)(k+0)*128];
            a1 += sp[k+1]*vp[(size_t)(k+1)*128];
            a2 += sp[k+2]*vp[(size_t)(k+2)*128];
            a3 += sp[k+3]*vp[(size_t)(k+3)*128];
            a4 += sp[k+4]*vp[(size_t)(k+4)*128];
            a5 += sp[k+5]*vp[(size_t)(k+5)*128];
            a6 += sp[k+6]*vp[(size_t)(k+6)*128];
            a7 += sp[k+7]*vp[(size_t)(k+7)*128];
        }
        out[(size_t)(b*12+c)*128 + hh*32 + d] = ((a0+a1)+(a2+a3))+((a4+a5)+(a6+a7));
    }
}

__global__ __launch_bounds__(256) void final_out(const float* __restrict__ t,
        const float* __restrict__ lw, const float* __restrict__ lb,
        const float* __restrict__ ow, const float* __restrict__ ob, float* __restrict__ out){
    int r = blockIdx.x*4 + (threadIdx.x>>6);
    int lane = threadIdx.x & 63;
    const float2* x2 = (const float2*)(t + (size_t)r*128);
    float2 v = x2[lane];
    float s = v.x+v.y;
    for (int o=32;o>0;o>>=1) s += __shfl_xor(s,o);
    float mean = s*(1.f/128.f);
    float dx=v.x-mean, dy=v.y-mean;
    float var = dx*dx+dy*dy;
    for (int o=32;o>0;o>>=1) var += __shfl_xor(var,o);
    float rs = rsqrtf(var*(1.f/128.f)+1e-5f);
    float2 w2=((const float2*)lw)[lane], b2=((const float2*)lb)[lane];
    float2 o2=((const float2*)ow)[lane];
    float d = (dx*rs*w2.x+b2.x)*o2.x + (dy*rs*w2.y+b2.y)*o2.y;
    for (int o=32;o>0;o>>=1) d += __shfl_xor(d,o);
    if (lane==0) out[r] = d + ob[0];
}

extern "C" void kernel_launch(void* const* d_in, const int* in_sizes, int n_in,
                              void* d_out, int out_size, void* d_ws, size_t ws_size,
                              hipStream_t stream){
    (void)in_sizes; (void)n_in; (void)out_size; (void)ws_size;
    const float* x        = (const float*)d_in[0];
    const int*   eidx     = (const int*)d_in[1];
    const float* in_w     = (const float*)d_in[3];
    const float* in_b     = (const float*)d_in[4];
    const float* gcn_w    = (const float*)d_in[5];
    const float* gcn_b    = (const float*)d_in[6];
    const float* ln_w     = (const float*)d_in[7];
    const float* ln_b     = (const float*)d_in[8];
    const float* cq       = (const float*)d_in[9];
    const float* sa_qkv_w = (const float*)d_in[10];
    const float* sa_qkv_b = (const float*)d_in[11];
    const float* sa_out_w = (const float*)d_in[12];
    const float* sa_out_b = (const float*)d_in[13];
    const float* ca_qkv_w = (const float*)d_in[14];
    const float* ca_qkv_b = (const float*)d_in[15];
    const float* ca_out_w = (const float*)d_in[16];
    const float* ca_out_b = (const float*)d_in[17];
    const float* n1w=(const float*)d_in[18]; const float* n1b=(const float*)d_in[19];
    const float* n2w=(const float*)d_in[20]; const float* n2b=(const float*)d_in[21];
    const float* n3w=(const float*)d_in[22]; const float* n3b=(const float*)d_in[23];
    const float* ff1w=(const float*)d_in[24]; const float* ff1b=(const float*)d_in[25];
    const float* ff2w=(const float*)d_in[26]; const float* ff2b=(const float*)d_in[27];
    const float* opln_w=(const float*)d_in[28]; const float* opln_b=(const float*)d_in[29];
    const float* opw=(const float*)d_in[30]; const float* opb=(const float*)d_in[31];
    float* out = (float*)d_out;

    char* base = (char*)d_ws;
    size_t off = 0;
    auto alloc = [&](size_t bytes)->void*{
        void* r = base + off; off += (bytes + 255) & ~(size_t)255; return r;
    };
    float*    h    = (float*)alloc((size_t)NNODES*DD*4);   // aliased as vb after last agg
    float*    hw   = (float*)alloc((size_t)NNODES*DD*4);
    ushort_t* hbf  = (ushort_t*)alloc((size_t)NNODES*DD*2);
    ushort_t* Wb   = (ushort_t*)alloc((size_t)5*DD*DD*2);
    float*    dinv = (float*)alloc((size_t)NNODES*4);
    int*      cnt  = (int*)  alloc((size_t)NNODES*4);
    int*      offs = (int*)  alloc((size_t)(NNODES+1)*4);
    int*      bsum = (int*)  alloc(512*4);
    int*      csrc = (int*)  alloc((size_t)NEDGES*4);
    float*    cw   = (float*)alloc((size_t)NEDGES*4);
    float*    t    = (float*)alloc((size_t)NROWS*DD*4);
    float*    tn   = (float*)alloc((size_t)NROWS*DD*4);
    float*    sq   = (float*)alloc((size_t)NROWS*384*4);
    float*    att  = (float*)alloc((size_t)NROWS*DD*4);
    float*    ffh  = (float*)alloc((size_t)NROWS*512*4);
    float*    vb   = h;   // h is dead after last gcn_agg (K/V GEMMs read hbf)

    const int* erow = eidx;
    const int* ecol = eidx + NEDGES;

    // CSR build (once, reused by all 3 GCN layers)
    hipMemsetAsync(cnt, 0, (size_t)NNODES*4, stream);
    count_edges<<<NEDGES/256, 256, 0, stream>>>(ecol, cnt);
    compute_dinv<<<NNODES/256, 256, 0, stream>>>(cnt, dinv);
    scan_a<<<NNODES/256, 256, 0, stream>>>(cnt, offs, bsum);
    scan_b<<<1, 512, 0, stream>>>(bsum, NNODES/256);
    scan_c<<<NNODES/256, 256, 0, stream>>>(offs, bsum);
    hipMemsetAsync(cnt, 0, (size_t)NNODES*4, stream);
    fill_csr<<<NEDGES/256, 256, 0, stream>>>(erow, ecol, offs, cnt, dinv, csrc, cw);

    conv_w<<<5*DD*DD/256, 256, 0, stream>>>(gcn_w, ca_qkv_w, Wb);

    // node pipeline
    in_proj<<<NNODES*DD/256, 256, 0, stream>>>(x, in_w, in_b, h, hbf);
    for (int i=0;i<3;++i){
        gemm_mfma<<<NNODES/64, 256, 0, stream>>>(hbf, Wb + (size_t)i*DD*DD, nullptr, hw);
        gcn_agg<<<NNODES/4, 256, 0, stream>>>(h, hw, offs, csrc, cw, dinv,
                gcn_b + (size_t)i*DD, ln_w + (size_t)i*DD, ln_b + (size_t)i*DD, hbf, i==2);
    }
    // cross-attn K,V projections from hbf
    gemm_mfma<<<NNODES/64, 256, 0, stream>>>(hbf, Wb + (size_t)3*DD*DD, ca_qkv_b + DD,   hw);  // K
    gemm_mfma<<<NNODES/64, 256, 0, stream>>>(hbf, Wb + (size_t)4*DD*DD, ca_qkv_b + 2*DD, vb);  // V

    // decoder layer (norm_first)
    bcast_cq<<<NROWS*DD/256, 256, 0, stream>>>(cq, t);
    ln_rows<<<NROWS/4, 256, 0, stream>>>(t, tn, n1w, n1b);
    small_gemm<<<NROWS*384/256, 256, 0, stream>>>(tn, sa_qkv_w, sa_qkv_b, sq, NROWS, 128, 384, 0);
    self_attn<<<BB*4, 64, 0, stream>>>(sq, att);
    small_gemm<<<NROWS*128/256, 256, 0, stream>>>(att, sa_out_w, sa_out_b, t, NROWS, 128, 128, 1);
    ln_rows<<<NROWS/4, 256, 0, stream>>>(t, tn, n2w, n2b);
    small_gemm<<<NROWS*128/256, 256, 0, stream>>>(tn, ca_qkv_w, ca_qkv_b, sq, NROWS, 128, 128, 0);
    cross_attn<<<BB*4, 256, 0, stream>>>(sq, hw, vb, att);
    small_gemm<<<NROWS*128/256, 256, 0, stream>>>(att, ca_out_w, ca_out_b, t, NROWS, 128, 128, 1);
    ln_rows<<<NROWS/4, 256, 0, stream>>>(t, tn, n3w, n3b);
    small_gemm<<<NROWS*512/256, 256, 0, stream>>>(tn, ff1w, ff1b, ffh, NROWS, 128, 512, 2);
    small_gemm<<<NROWS*128/256, 256, 0, stream>>>(ffh, ff2w, ff2b, t, NROWS, 512, 128, 1);
    final_out<<<NROWS/4, 256, 0, stream>>>(t, opln_w, opln_b, opw, opb, out);
}

// Round 4
// 931.238 us; speedup vs baseline: 1.5005x; 1.1634x over previous
//
#include <hip/hip_runtime.h>

#define NNODES 128000
#define NEDGES 640000
#define BB 128
#define CC 12
#define DD 128
#define NROWS (BB*CC)   // 1536
#define NSPLIT 8
#define CHUNK 125

typedef __attribute__((ext_vector_type(8))) short short8;
typedef __attribute__((ext_vector_type(4))) float f32x4;
typedef unsigned short ushort_t;

__device__ __forceinline__ ushort_t f2bf(float f){
    union { float f; unsigned u; } v; v.f = f;
    unsigned r = (v.u + 0x7FFF + ((v.u >> 16) & 1)) >> 16;  // RNE
    return (ushort_t)r;
}
__device__ __forceinline__ float bfu_lo(unsigned u){
    union { unsigned u; float f; } v; v.u = u << 16; return v.f;
}
__device__ __forceinline__ float bfu_hi(unsigned u){
    union { unsigned u; float f; } v; v.u = u & 0xFFFF0000u; return v.f;
}

// ---------------- CSR build ----------------
__global__ __launch_bounds__(256) void count_edges(const int* __restrict__ col, int* __restrict__ cnt){
    int e = blockIdx.x*256 + threadIdx.x;
    if (e < NEDGES) atomicAdd(&cnt[col[e]], 1);
}

__global__ __launch_bounds__(256) void compute_dinv(const int* __restrict__ cnt, float* __restrict__ dinv){
    int i = blockIdx.x*256 + threadIdx.x;
    if (i < NNODES) dinv[i] = rsqrtf((float)cnt[i] + 1.0f);
}

__global__ __launch_bounds__(256) void scan_a(const int* __restrict__ cnt, int* __restrict__ offs, int* __restrict__ bsum){
    __shared__ int tmp[256];
    int tid = threadIdx.x;
    int g = blockIdx.x*256 + tid;
    int v = cnt[g];
    tmp[tid] = v;
    __syncthreads();
    for (int o=1;o<256;o<<=1){
        int a = (tid>=o)? tmp[tid-o] : 0;
        __syncthreads();
        tmp[tid] += a;
        __syncthreads();
    }
    offs[g] = tmp[tid] - v;
    if (tid==255) bsum[blockIdx.x] = tmp[255];
}

__global__ __launch_bounds__(512) void scan_b(int* __restrict__ bsum, int NB){
    __shared__ int tmp[512];
    int tid = threadIdx.x;
    int v = (tid<NB)? bsum[tid] : 0;
    tmp[tid] = v;
    __syncthreads();
    for (int o=1;o<512;o<<=1){
        int a = (tid>=o)? tmp[tid-o] : 0;
        __syncthreads();
        tmp[tid] += a;
        __syncthreads();
    }
    if (tid<NB) bsum[tid] = tmp[tid] - v;
}

__global__ __launch_bounds__(256) void scan_c(int* __restrict__ offs, const int* __restrict__ bsum){
    int g = blockIdx.x*256 + threadIdx.x;
    offs[g] += bsum[g>>8];
    if (g==0) offs[NNODES] = NEDGES;
}

__global__ __launch_bounds__(256) void fill_csr(const int* __restrict__ row, const int* __restrict__ col,
        const int* __restrict__ offs, int* __restrict__ cur, const float* __restrict__ dinv,
        int* __restrict__ src, float* __restrict__ ew){
    int e = blockIdx.x*256 + threadIdx.x;
    if (e >= NEDGES) return;
    int c = col[e], r = row[e];
    int p = atomicAdd(&cur[c], 1);
    int idx = offs[c] + p;
    src[idx] = r;
    ew[idx] = dinv[r]*dinv[c];
}

// ---------------- weight f32 -> bf16 (5 x 128x128: gcn0..2, ca-K, ca-V) ----------------
__global__ __launch_bounds__(256) void conv_w(const float* __restrict__ gcn_w,
        const float* __restrict__ ca_qkv_w, ushort_t* __restrict__ Wb){
    int i = blockIdx.x*256 + threadIdx.x;   // < 5*16384
    int slot = i >> 14, off = i & 16383;
    float v = (slot < 3) ? gcn_w[slot*16384 + off]
                         : ca_qkv_w[16384 + (slot-3)*16384 + off];
    Wb[i] = f2bf(v);
}

// ---------------- input projection: h = x @ in_w.T + in_b (+ bf16 copy) ----------------
__global__ __launch_bounds__(256) void in_proj(const float* __restrict__ x, const float* __restrict__ W,
        const float* __restrict__ bias, float* __restrict__ h, ushort_t* __restrict__ hbf){
    __shared__ float ws[128*17];
    __shared__ float bs[128];
    int tid = threadIdx.x;
    for (int i=tid;i<2048;i+=256) ws[(i>>4)*17 + (i&15)] = W[i];
    if (tid<128) bs[tid] = bias[tid];
    __syncthreads();
    size_t idx = (size_t)blockIdx.x*256 + tid;
    int m = (int)(idx>>7), n = (int)(idx&127);
    const float4* xr = (const float4*)(x + (size_t)m*16);
    float4 x0=xr[0], x1=xr[1], x2=xr[2], x3=xr[3];
    const float* wr = ws + n*17;
    float a = bs[n];
    a += x0.x*wr[0]+x0.y*wr[1]+x0.z*wr[2]+x0.w*wr[3];
    a += x1.x*wr[4]+x1.y*wr[5]+x1.z*wr[6]+x1.w*wr[7];
    a += x2.x*wr[8]+x2.y*wr[9]+x2.z*wr[10]+x2.w*wr[11];
    a += x3.x*wr[12]+x3.y*wr[13]+x3.z*wr[14]+x3.w*wr[15];
    h[idx] = a;
    hbf[idx] = f2bf(a);
}

// ---------------- MFMA GEMM: out_bf[m][n] = bf16( sum_k A_bf[m][k]*W_bf[n][k] (+bias) ) ----
__global__ __launch_bounds__(256) void gemm_mfma(const ushort_t* __restrict__ A,
        const ushort_t* __restrict__ Wb, const float* __restrict__ bias, ushort_t* __restrict__ out){
    int lane = threadIdx.x & 63, wave = threadIdx.x >> 6;
    int m0 = blockIdx.x*64 + wave*16;
    int lr = lane & 15;            // row-within-16-tile (A row / W row=n)
    int lk = (lane >> 4) * 8;      // k offset (8 contiguous bf16)
    short8 bfrag[4][8];
    #pragma unroll
    for (int nt=0; nt<8; ++nt)
        #pragma unroll
        for (int kc=0; kc<4; ++kc)
            bfrag[kc][nt] = *(const short8*)&Wb[(nt*16 + lr)*128 + kc*32 + lk];
    f32x4 acc[8];
    #pragma unroll
    for (int nt=0; nt<8; ++nt) acc[nt] = (f32x4){0.f,0.f,0.f,0.f};
    const ushort_t* arow = A + (size_t)(m0 + lr)*128 + lk;
    #pragma unroll
    for (int kc=0; kc<4; ++kc){
        short8 a = *(const short8*)(arow + kc*32);
        #pragma unroll
        for (int nt=0; nt<8; ++nt)
            acc[nt] = __builtin_amdgcn_mfma_f32_16x16x32_bf16(a, bfrag[kc][nt], acc[nt], 0, 0, 0);
    }
    size_t orow = (size_t)m0 + (lane>>4)*4;
    #pragma unroll
    for (int nt=0; nt<8; ++nt){
        int col = nt*16 + lr;
        float bv = bias ? bias[col] : 0.f;
        #pragma unroll
        for (int r=0; r<4; ++r)
            out[(orow + r)*128 + col] = f2bf(acc[nt][r] + bv);
    }
}

// ---------------- GCN aggregate (bf16 gather) + LN (+ReLU+residual) ----------------
__global__ __launch_bounds__(256) void gcn_agg(float* __restrict__ h, const ushort_t* __restrict__ hwbf,
        const int* __restrict__ offs, const int* __restrict__ src, const float* __restrict__ ew,
        const float* __restrict__ dinv, const float* __restrict__ bias,
        const float* __restrict__ lnw, const float* __restrict__ lnb,
        ushort_t* __restrict__ hbf, int last){
    int node = blockIdx.x*4 + (threadIdx.x>>6);
    int lane = threadIdx.x & 63;
    const unsigned* hwu = (const unsigned*)hwbf;
    float di = dinv[node];
    float sw = di*di;
    unsigned su = hwu[(size_t)node*64 + lane];
    float ax = sw*bfu_lo(su), ay = sw*bfu_hi(su);
    int e0 = offs[node], e1 = offs[node+1];
    for (int e = e0; e < e1; ++e){
        float w = ew[e]; int sidx = src[e];
        unsigned u = hwu[(size_t)sidx*64 + lane];
        ax += w*bfu_lo(u); ay += w*bfu_hi(u);
    }
    float2 b2 = ((const float2*)bias)[lane];
    ax += b2.x; ay += b2.y;
    float s = ax + ay;
    for (int o=32;o>0;o>>=1) s += __shfl_xor(s,o);
    float mean = s * (1.f/128.f);
    float dx = ax-mean, dy = ay-mean;
    float var = dx*dx + dy*dy;
    for (int o=32;o>0;o>>=1) var += __shfl_xor(var,o);
    float rs = rsqrtf(var*(1.f/128.f) + 1e-5f);
    float2 w2 = ((const float2*)lnw)[lane], lb2 = ((const float2*)lnb)[lane];
    float yx = dx*rs*w2.x + lb2.x;
    float yy = dy*rs*w2.y + lb2.y;
    float2* h2 = (float2*)h;
    if (!last){
        float2 r = h2[(size_t)node*64+lane];
        yx = fmaxf(yx,0.f) + r.x;
        yy = fmaxf(yy,0.f) + r.y;
        h2[(size_t)node*64+lane] = make_float2(yx,yy);
    }
    unsigned pk = (unsigned)f2bf(yx) | ((unsigned)f2bf(yy) << 16);
    ((unsigned*)hbf)[(size_t)node*64 + lane] = pk;
}

// ---------------- decoder small ops ----------------
__global__ __launch_bounds__(256) void bcast_cq(const float* __restrict__ cq, float* __restrict__ t){
    int idx = blockIdx.x*256 + threadIdx.x;
    int r = idx >> 7;
    t[idx] = cq[((r % 12)<<7) | (idx&127)];
}

__global__ __launch_bounds__(256) void ln_rows(const float* __restrict__ x, float* __restrict__ y,
        const float* __restrict__ w, const float* __restrict__ b){
    int r = blockIdx.x*4 + (threadIdx.x>>6);
    int lane = threadIdx.x & 63;
    const float2* x2 = (const float2*)(x + (size_t)r*128);
    float2 v = x2[lane];
    float s = v.x+v.y;
    for (int o=32;o>0;o>>=1) s += __shfl_xor(s,o);
    float mean = s*(1.f/128.f);
    float dx=v.x-mean, dy=v.y-mean;
    float var = dx*dx+dy*dy;
    for (int o=32;o>0;o>>=1) var += __shfl_xor(var,o);
    float rs = rsqrtf(var*(1.f/128.f) + 1e-5f);
    float2 w2=((const float2*)w)[lane], b2=((const float2*)b)[lane];
    ((float2*)(y + (size_t)r*128))[lane] = make_float2(dx*rs*w2.x+b2.x, dy*rs*w2.y+b2.y);
}

// flags: 1 = accumulate into out, 2 = relu
__global__ __launch_bounds__(256) void small_gemm(const float* __restrict__ x, const float* __restrict__ W,
        const float* __restrict__ bias, float* __restrict__ out, int R, int K, int NO, int flags){
    int idx = blockIdx.x*256 + threadIdx.x;
    if (idx >= R*NO) return;
    int r = idx / NO, n = idx - r*NO;
    const float4* xr = (const float4*)(x + (size_t)r*K);
    const float4* wr = (const float4*)(W + (size_t)n*K);
    float a = bias ? bias[n] : 0.0f;
    int K4 = K>>2;
    for (int k=0;k<K4;++k){
        float4 xv = xr[k], wv = wr[k];
        a += xv.x*wv.x + xv.y*wv.y + xv.z*wv.z + xv.w*wv.w;
    }
    if (flags & 2) a = fmaxf(a, 0.f);
    if (flags & 1) a += out[idx];
    out[idx] = a;
}

__global__ __launch_bounds__(64) void self_attn(const float* __restrict__ qkv, float* __restrict__ out){
    int b = blockIdx.x >> 2, hh = blockIdx.x & 3;
    int lane = threadIdx.x;
    __shared__ float q[12][32], k[12][32], v[12][32], sc[12][12];
    for (int idx = lane; idx < 12*32; idx += 64){
        int c = idx>>5, d = idx&31;
        size_t base = (size_t)(b*12+c)*384 + hh*32 + d;
        q[c][d] = qkv[base] * 0.17677669529663687f;
        k[c][d] = qkv[base+128];
        v[c][d] = qkv[base+256];
    }
    __syncthreads();
    for (int p = lane; p < 144; p += 64){
        int qi = p/12, ki = p%12;
        float a = 0;
        #pragma unroll
        for (int d=0; d<32; ++d) a += q[qi][d]*k[ki][d];
        sc[qi][ki] = a;
    }
    __syncthreads();
    if (lane < 12){
        float m = -1e30f;
        for (int j=0;j<12;++j) m = fmaxf(m, sc[lane][j]);
        float sum=0;
        for (int j=0;j<12;++j){ float e=__expf(sc[lane][j]-m); sc[lane][j]=e; sum+=e; }
        float inv=1.f/sum;
        for (int j=0;j<12;++j) sc[lane][j]*=inv;
    }
    __syncthreads();
    for (int p = lane; p < 384; p += 64){
        int c = p>>5, d = p&31;
        float a=0;
        #pragma unroll
        for (int j=0;j<12;++j) a += sc[c][j]*v[j][d];
        out[(size_t)(b*12+c)*128 + hh*32 + d] = a;
    }
}

// ---------------- flash cross-attention, k-split, MFMA for QK^T and PV ----------------
// grid = BB*NSPLIT, block 512. K,V bf16 [node][128]. q fp32 [1536][128].
__global__ __launch_bounds__(512) void cross_attn_part(const float* __restrict__ q,
        const ushort_t* __restrict__ K, const ushort_t* __restrict__ V,
        float* __restrict__ opart, float2* __restrict__ mlpart){
    __shared__ __align__(16) ushort_t qs[16*136];        // Q bf16, rows 12-15 zero
    __shared__ __align__(16) unsigned char uni[128*136*2]; // s32[48][130] then vt[128][136]
    __shared__ __align__(16) ushort_t pbf[4*16*136];     // P bf16 [h][16q][136kk], zero-padded
    __shared__ float2 ml[48];
    float* s32 = (float*)uni;
    ushort_t* vt = (ushort_t*)uni;

    int tid = threadIdx.x;
    int b = blockIdx.x / NSPLIT, sp = blockIdx.x % NSPLIT;
    int k0 = sp * CHUNK;
    int lane = tid & 63, w = tid >> 6;
    int lr = lane & 15, hi8 = (lane >> 4) * 8;

    // phase 0: issue V chunk loads into registers (write to LDS later), stage Q, zero pbf
    const unsigned* Vu = (const unsigned*)V + ((size_t)b*1000 + k0)*64;
    unsigned vreg[16];
    #pragma unroll
    for (int j=0;j<15;++j) vreg[j] = Vu[tid + j*512];
    if (tid < 320) vreg[15] = Vu[tid + 7680];

    for (int i = tid; i < 16*128; i += 512){
        int r = i >> 7, c = i & 127;
        ushort_t v = 0;
        if (r < 12) v = f2bf(q[((size_t)b*12 + r)*128 + c] * 0.17677669529663687f);
        qs[r*136 + c] = v;
    }
    for (int i = tid; i < 4352; i += 512) ((unsigned*)pbf)[i] = 0;
    __syncthreads();

    // phase 1: scores. wave w owns kk-tile w (16 keys). one MFMA per head (K=32=head_dim).
    {
        int krow = k0 + w*16 + lr; if (krow > k0 + 124) krow = k0 + 124;
        const ushort_t* Krow = K + ((size_t)b*1000 + krow)*128 + hi8;
        #pragma unroll
        for (int h=0; h<4; ++h){
            short8 kf = *(const short8*)(Krow + h*32);
            short8 qf = *(const short8*)&qs[lr*136 + h*32 + hi8];
            f32x4 d = __builtin_amdgcn_mfma_f32_16x16x32_bf16(qf, kf, (f32x4){0,0,0,0}, 0, 0, 0);
            int qbase = (lane>>4)*4;
            #pragma unroll
            for (int r=0; r<4; ++r){
                int qq = qbase + r;
                if (qq < 12) s32[(h*12+qq)*130 + w*16 + lr] = d[r];
            }
        }
    }
    __syncthreads();

    // phase 2: per-(h,q) max & sum(exp), write P (bf16) in place; 4 lanes per (h,q)
    if (tid < 192){
        int hq = tid >> 2, sub = tid & 3;
        int h = hq / 12, qq = hq - h*12;
        float m = -1e30f;
        for (int kk = sub; kk < CHUNK; kk += 4) m = fmaxf(m, s32[hq*130 + kk]);
        m = fmaxf(m, __shfl_xor(m, 1));
        m = fmaxf(m, __shfl_xor(m, 2));
        float l = 0.f;
        for (int kk = sub; kk < CHUNK; kk += 4){
            float e = __expf(s32[hq*130 + kk] - m);
            l += e;
            pbf[(h*16+qq)*136 + kk] = f2bf(e);
        }
        l += __shfl_xor(l, 1);
        l += __shfl_xor(l, 2);
        if (sub == 0) ml[hq] = make_float2(m, l);
    }
    __syncthreads();   // s32 dead

    // phase 3: write V chunk transposed into LDS (vt[dp][kk]); zero kk=125..127
    #pragma unroll
    for (int j=0;j<15;++j){
        int i = tid + j*512;
        int kk = i >> 6, dp = (i & 63)*2;
        unsigned u = vreg[j];
        vt[dp*136 + kk]     = (ushort_t)(u & 0xFFFF);
        vt[(dp+1)*136 + kk] = (ushort_t)(u >> 16);
    }
    if (tid < 320){
        int i = tid + 7680;
        int kk = i >> 6, dp = (i & 63)*2;
        unsigned u = vreg[15];
        vt[dp*136 + kk]     = (ushort_t)(u & 0xFFFF);
        vt[(dp+1)*136 + kk] = (ushort_t)(u >> 16);
    }
    if (tid < 384){
        int dp = tid / 3, kk = 125 + tid % 3;
        vt[dp*136 + kk] = 0;
    }
    __syncthreads();

    // phase 4: PV. wave w owns dp-tile w (16 dims), head h = w>>1. 4 MFMA over kk=0..127.
    {
        int h = w >> 1;
        f32x4 acc = (f32x4){0,0,0,0};
        #pragma unroll
        for (int kc=0; kc<4; ++kc){
            short8 pf = *(const short8*)&pbf[(h*16+lr)*136 + kc*32 + hi8];
            short8 vf = *(const short8*)&vt[(w*16+lr)*136 + kc*32 + hi8];
            acc = __builtin_amdgcn_mfma_f32_16x16x32_bf16(pf, vf, acc, 0, 0, 0);
        }
        int qbase = (lane>>4)*4;
        float* ob = opart + ((size_t)(b*NSPLIT+sp)*12)*128;
        #pragma unroll
        for (int r=0; r<4; ++r){
            int qq = qbase + r;
            if (qq < 12) ob[(size_t)qq*128 + w*16 + lr] = acc[r];
        }
    }
    if (tid < 48) mlpart[(size_t)(b*NSPLIT+sp)*48 + tid] = ml[tid];
}

__global__ __launch_bounds__(256) void cross_attn_comb(const float* __restrict__ opart,
        const float* __restrict__ mlpart, float* __restrict__ att){
    int b = blockIdx.x, tid = threadIdx.x;
    __shared__ float mls[NSPLIT*48*2];
    for (int i = tid; i < NSPLIT*48*2; i += 256) mls[i] = mlpart[(size_t)b*NSPLIT*96 + i];
    __syncthreads();
    for (int p = tid; p < 1536; p += 256){
        int qq = p >> 7, dp = p & 127, h = dp >> 5, hq = h*12 + qq;
        float M = -1e30f;
        #pragma unroll
        for (int sp=0; sp<NSPLIT; ++sp) M = fmaxf(M, mls[sp*96 + hq*2]);
        float L = 0.f, O = 0.f;
        #pragma unroll
        for (int sp=0; sp<NSPLIT; ++sp){
            float wgt = __expf(mls[sp*96 + hq*2] - M);
            L += wgt * mls[sp*96 + hq*2 + 1];
            O += wgt * opart[((size_t)(b*NSPLIT+sp)*12 + qq)*128 + dp];
        }
        att[((size_t)b*12 + qq)*128 + dp] = O / L;
    }
}

__global__ __launch_bounds__(256) void final_out(const float* __restrict__ t,
        const float* __restrict__ lw, const float* __restrict__ lb,
        const float* __restrict__ ow, const float* __restrict__ ob, float* __restrict__ out){
    int r = blockIdx.x*4 + (threadIdx.x>>6);
    int lane = threadIdx.x & 63;
    const float2* x2 = (const float2*)(t + (size_t)r*128);
    float2 v = x2[lane];
    float s = v.x+v.y;
    for (int o=32;o>0;o>>=1) s += __shfl_xor(s,o);
    float mean = s*(1.f/128.f);
    float dx=v.x-mean, dy=v.y-mean;
    float var = dx*dx+dy*dy;
    for (int o=32;o>0;o>>=1) var += __shfl_xor(var,o);
    float rs = rsqrtf(var*(1.f/128.f)+1e-5f);
    float2 w2=((const float2*)lw)[lane], b2=((const float2*)lb)[lane];
    float2 o2=((const float2*)ow)[lane];
    float d = (dx*rs*w2.x+b2.x)*o2.x + (dy*rs*w2.y+b2.y)*o2.y;
    for (int o=32;o>0;o>>=1) d += __shfl_xor(d,o);
    if (lane==0) out[r] = d + ob[0];
}

extern "C" void kernel_launch(void* const* d_in, const int* in_sizes, int n_in,
                              void* d_out, int out_size, void* d_ws, size_t ws_size,
                              hipStream_t stream){
    (void)in_sizes; (void)n_in; (void)out_size; (void)ws_size;
    const float* x        = (const float*)d_in[0];
    const int*   eidx     = (const int*)d_in[1];
    const float* in_w     = (const float*)d_in[3];
    const float* in_b     = (const float*)d_in[4];
    const float* gcn_w    = (const float*)d_in[5];
    const float* gcn_b    = (const float*)d_in[6];
    const float* ln_w     = (const float*)d_in[7];
    const float* ln_b     = (const float*)d_in[8];
    const float* cq       = (const float*)d_in[9];
    const float* sa_qkv_w = (const float*)d_in[10];
    const float* sa_qkv_b = (const float*)d_in[11];
    const float* sa_out_w = (const float*)d_in[12];
    const float* sa_out_b = (const float*)d_in[13];
    const float* ca_qkv_w = (const float*)d_in[14];
    const float* ca_qkv_b = (const float*)d_in[15];
    const float* ca_out_w = (const float*)d_in[16];
    const float* ca_out_b = (const float*)d_in[17];
    const float* n1w=(const float*)d_in[18]; const float* n1b=(const float*)d_in[19];
    const float* n2w=(const float*)d_in[20]; const float* n2b=(const float*)d_in[21];
    const float* n3w=(const float*)d_in[22]; const float* n3b=(const float*)d_in[23];
    const float* ff1w=(const float*)d_in[24]; const float* ff1b=(const float*)d_in[25];
    const float* ff2w=(const float*)d_in[26]; const float* ff2b=(const float*)d_in[27];
    const float* opln_w=(const float*)d_in[28]; const float* opln_b=(const float*)d_in[29];
    const float* opw=(const float*)d_in[30]; const float* opb=(const float*)d_in[31];
    float* out = (float*)d_out;

    char* base = (char*)d_ws;
    size_t off = 0;
    auto alloc = [&](size_t bytes)->void*{
        void* r = base + off; off += (bytes + 255) & ~(size_t)255; return r;
    };
    float*    h     = (float*)alloc((size_t)NNODES*DD*4);
    ushort_t* hbf   = (ushort_t*)alloc((size_t)NNODES*DD*2);
    ushort_t* kbf   = (ushort_t*)alloc((size_t)NNODES*DD*2);  // also hwbf during GCN loop
    ushort_t* vbf   = (ushort_t*)alloc((size_t)NNODES*DD*2);
    ushort_t* Wb    = (ushort_t*)alloc((size_t)5*DD*DD*2);
    float*    dinv  = (float*)alloc((size_t)NNODES*4);
    int*      cnt   = (int*)  alloc((size_t)NNODES*4);
    int*      offs  = (int*)  alloc((size_t)(NNODES+1)*4);
    int*      bsum  = (int*)  alloc(512*4);
    int*      csrc  = (int*)  alloc((size_t)NEDGES*4);
    float*    cw    = (float*)alloc((size_t)NEDGES*4);
    float*    t     = (float*)alloc((size_t)NROWS*DD*4);
    float*    tn    = (float*)alloc((size_t)NROWS*DD*4);
    float*    sq    = (float*)alloc((size_t)NROWS*384*4);
    float*    att   = (float*)alloc((size_t)NROWS*DD*4);
    float*    ffh   = (float*)alloc((size_t)NROWS*512*4);
    float*    opart = (float*)alloc((size_t)BB*NSPLIT*12*128*4);
    float2*   mlprt = (float2*)alloc((size_t)BB*NSPLIT*48*8);
    ushort_t* hwbf  = kbf;

    const int* erow = eidx;
    const int* ecol = eidx + NEDGES;

    // CSR build (once, reused by all 3 GCN layers)
    hipMemsetAsync(cnt, 0, (size_t)NNODES*4, stream);
    count_edges<<<NEDGES/256, 256, 0, stream>>>(ecol, cnt);
    compute_dinv<<<NNODES/256, 256, 0, stream>>>(cnt, dinv);
    scan_a<<<NNODES/256, 256, 0, stream>>>(cnt, offs, bsum);
    scan_b<<<1, 512, 0, stream>>>(bsum, NNODES/256);
    scan_c<<<NNODES/256, 256, 0, stream>>>(offs, bsum);
    hipMemsetAsync(cnt, 0, (size_t)NNODES*4, stream);
    fill_csr<<<NEDGES/256, 256, 0, stream>>>(erow, ecol, offs, cnt, dinv, csrc, cw);

    conv_w<<<5*DD*DD/256, 256, 0, stream>>>(gcn_w, ca_qkv_w, Wb);

    // node pipeline
    in_proj<<<NNODES*DD/256, 256, 0, stream>>>(x, in_w, in_b, h, hbf);
    for (int i=0;i<3;++i){
        gemm_mfma<<<NNODES/64, 256, 0, stream>>>(hbf, Wb + (size_t)i*DD*DD, nullptr, hwbf);
        gcn_agg<<<NNODES/4, 256, 0, stream>>>(h, hwbf, offs, csrc, cw, dinv,
                gcn_b + (size_t)i*DD, ln_w + (size_t)i*DD, ln_b + (size_t)i*DD, hbf, i==2);
    }
    // cross-attn K,V projections (bf16 out)
    gemm_mfma<<<NNODES/64, 256, 0, stream>>>(hbf, Wb + (size_t)3*DD*DD, ca_qkv_b + DD,   kbf);
    gemm_mfma<<<NNODES/64, 256, 0, stream>>>(hbf, Wb + (size_t)4*DD*DD, ca_qkv_b + 2*DD, vbf);

    // decoder layer (norm_first)
    bcast_cq<<<NROWS*DD/256, 256, 0, stream>>>(cq, t);
    ln_rows<<<NROWS/4, 256, 0, stream>>>(t, tn, n1w, n1b);
    small_gemm<<<NROWS*384/256, 256, 0, stream>>>(tn, sa_qkv_w, sa_qkv_b, sq, NROWS, 128, 384, 0);
    self_attn<<<BB*4, 64, 0, stream>>>(sq, att);
    small_gemm<<<NROWS*128/256, 256, 0, stream>>>(att, sa_out_w, sa_out_b, t, NROWS, 128, 128, 1);
    ln_rows<<<NROWS/4, 256, 0, stream>>>(t, tn, n2w, n2b);
    small_gemm<<<NROWS*128/256, 256, 0, stream>>>(tn, ca_qkv_w, ca_qkv_b, sq, NROWS, 128, 128, 0);
    cross_attn_part<<<BB*NSPLIT, 512, 0, stream>>>(sq, kbf, vbf, opart, mlprt);
    cross_attn_comb<<<BB, 256, 0, stream>>>(opart, (const float*)mlprt, att);
    small_gemm<<<NROWS*128/256, 256, 0, stream>>>(att, ca_out_w, ca_out_b, t, NROWS, 128, 128, 1);
    ln_rows<<<NROWS/4, 256, 0, stream>>>(t, tn, n3w, n3b);
    small_gemm<<<NROWS*512/256, 256, 0, stream>>>(tn, ff1w, ff1b, ffh, NROWS, 128, 512, 2);
    small_gemm<<<NROWS*128/256, 256, 0, stream>>>(ffh, ff2w, ff2b, t, NROWS, 512, 128, 1);
    final_out<<<NROWS/4, 256, 0, stream>>>(t, opln_w, opln_b, opw, opb, out);
}

// Round 5
// 790.725 us; speedup vs baseline: 1.7671x; 1.1777x over previous
//
#include <hip/hip_runtime.h>

#define NNODES 128000
#define NEDGES 640000
#define BB 128
#define CC 12
#define DD 128
#define NROWS (BB*CC)   // 1536
#define NSPLIT 8
#define CHUNK 125

typedef __attribute__((ext_vector_type(8))) short short8;
typedef __attribute__((ext_vector_type(4))) float f32x4;
typedef unsigned short ushort_t;

__device__ __forceinline__ ushort_t f2bf(float f){
    union { float f; unsigned u; } v; v.f = f;
    unsigned r = (v.u + 0x7FFF + ((v.u >> 16) & 1)) >> 16;  // RNE
    return (ushort_t)r;
}
__device__ __forceinline__ float bfu_lo(unsigned u){
    union { unsigned u; float f; } v; v.u = u << 16; return v.f;
}
__device__ __forceinline__ float bfu_hi(unsigned u){
    union { unsigned u; float f; } v; v.u = u & 0xFFFF0000u; return v.f;
}

// ---------------- CSR build ----------------
__global__ __launch_bounds__(256) void count_edges(const int* __restrict__ col, int* __restrict__ cnt){
    int e = blockIdx.x*256 + threadIdx.x;
    if (e < NEDGES) atomicAdd(&cnt[col[e]], 1);
}

__global__ __launch_bounds__(256) void compute_dinv(const int* __restrict__ cnt, float* __restrict__ dinv){
    int i = blockIdx.x*256 + threadIdx.x;
    if (i < NNODES) dinv[i] = rsqrtf((float)cnt[i] + 1.0f);
}

__global__ __launch_bounds__(256) void scan_a(const int* __restrict__ cnt, int* __restrict__ offs, int* __restrict__ bsum){
    __shared__ int tmp[256];
    int tid = threadIdx.x;
    int g = blockIdx.x*256 + tid;
    int v = cnt[g];
    tmp[tid] = v;
    __syncthreads();
    for (int o=1;o<256;o<<=1){
        int a = (tid>=o)? tmp[tid-o] : 0;
        __syncthreads();
        tmp[tid] += a;
        __syncthreads();
    }
    offs[g] = tmp[tid] - v;
    if (tid==255) bsum[blockIdx.x] = tmp[255];
}

__global__ __launch_bounds__(512) void scan_b(int* __restrict__ bsum, int NB){
    __shared__ int tmp[512];
    int tid = threadIdx.x;
    int v = (tid<NB)? bsum[tid] : 0;
    tmp[tid] = v;
    __syncthreads();
    for (int o=1;o<512;o<<=1){
        int a = (tid>=o)? tmp[tid-o] : 0;
        __syncthreads();
        tmp[tid] += a;
        __syncthreads();
    }
    if (tid<NB) bsum[tid] = tmp[tid] - v;
}

__global__ __launch_bounds__(256) void scan_c(int* __restrict__ offs, const int* __restrict__ bsum){
    int g = blockIdx.x*256 + threadIdx.x;
    offs[g] += bsum[g>>8];
    if (g==0) offs[NNODES] = NEDGES;
}

__global__ __launch_bounds__(256) void fill_csr(const int* __restrict__ row, const int* __restrict__ col,
        const int* __restrict__ offs, int* __restrict__ cur, const float* __restrict__ dinv,
        int2* __restrict__ ee){
    int e = blockIdx.x*256 + threadIdx.x;
    if (e >= NEDGES) return;
    int c = col[e], r = row[e];
    int p = atomicAdd(&cur[c], 1);
    int idx = offs[c] + p;
    float w = dinv[r]*dinv[c];
    ee[idx] = make_int2(r, __float_as_int(w));
}

// ---------------- weight f32 -> bf16 (5 x 128x128: gcn0..2, ca-K, ca-V) ----------------
__global__ __launch_bounds__(256) void conv_w(const float* __restrict__ gcn_w,
        const float* __restrict__ ca_qkv_w, ushort_t* __restrict__ Wb){
    int i = blockIdx.x*256 + threadIdx.x;   // < 5*16384
    int slot = i >> 14, off = i & 16383;
    float v = (slot < 3) ? gcn_w[slot*16384 + off]
                         : ca_qkv_w[16384 + (slot-3)*16384 + off];
    Wb[i] = f2bf(v);
}

// in_w [128][16] -> bf16 padded [128][32] (zeros k>=16)
__global__ __launch_bounds__(256) void conv_wpad(const float* __restrict__ in_w, ushort_t* __restrict__ Wpad){
    int i = blockIdx.x*256 + threadIdx.x;   // < 4096
    int n = i >> 5, k = i & 31;
    Wpad[i] = (k < 16) ? f2bf(in_w[n*16 + k]) : (ushort_t)0;
}

// ---------------- input projection via MFMA: h = x @ in_w.T + in_b ----------------
// 64 rows/block, x staged bf16-padded in LDS, K=32 (half zeros).
__global__ __launch_bounds__(256) void in_proj_mfma(const float* __restrict__ x,
        const ushort_t* __restrict__ Wpad, const float* __restrict__ bias,
        float* __restrict__ h, ushort_t* __restrict__ hbf){
    __shared__ __align__(16) ushort_t xs[64*32];
    int tid = threadIdx.x;
    int m0 = blockIdx.x*64;
    if (tid < 128){
        short8 z = {0,0,0,0,0,0,0,0};
        *(short8*)&xs[(tid>>1)*32 + 16 + (tid&1)*8] = z;
    }
    float4 xv = *(const float4*)(x + (size_t)m0*16 + tid*4);
    uint2 pk2;
    pk2.x = (unsigned)f2bf(xv.x) | ((unsigned)f2bf(xv.y) << 16);
    pk2.y = (unsigned)f2bf(xv.z) | ((unsigned)f2bf(xv.w) << 16);
    *(uint2*)&xs[(tid>>2)*32 + (tid&3)*4] = pk2;
    __syncthreads();
    int lane = tid & 63, w = tid >> 6;
    int lr = lane & 15, lk = (lane>>4)*8;
    short8 bfrag[8];
    #pragma unroll
    for (int nt=0; nt<8; ++nt)
        bfrag[nt] = *(const short8*)&Wpad[(nt*16 + lr)*32 + lk];
    short8 a = *(const short8*)&xs[(w*16 + lr)*32 + lk];
    f32x4 acc[8];
    #pragma unroll
    for (int nt=0; nt<8; ++nt)
        acc[nt] = __builtin_amdgcn_mfma_f32_16x16x32_bf16(a, bfrag[nt], (f32x4){0,0,0,0}, 0, 0, 0);
    size_t orow = (size_t)m0 + w*16 + (lane>>4)*4;
    #pragma unroll
    for (int nt=0; nt<8; ++nt){
        int col = nt*16 + lr;
        float bv = bias[col];
        #pragma unroll
        for (int r=0; r<4; ++r){
            float val = acc[nt][r] + bv;
            h[(orow + r)*128 + col] = val;
            hbf[(orow + r)*128 + col] = f2bf(val);
        }
    }
}

// ---------------- MFMA GEMM: out_bf[m][n] = bf16( sum_k A_bf[m][k]*W_bf[n][k] (+bias) ) ----
__global__ __launch_bounds__(256) void gemm_mfma(const ushort_t* __restrict__ A,
        const ushort_t* __restrict__ Wb, const float* __restrict__ bias, ushort_t* __restrict__ out){
    int lane = threadIdx.x & 63, wave = threadIdx.x >> 6;
    int m0 = blockIdx.x*64 + wave*16;
    int lr = lane & 15;
    int lk = (lane >> 4) * 8;
    short8 bfrag[4][8];
    #pragma unroll
    for (int nt=0; nt<8; ++nt)
        #pragma unroll
        for (int kc=0; kc<4; ++kc)
            bfrag[kc][nt] = *(const short8*)&Wb[(nt*16 + lr)*128 + kc*32 + lk];
    f32x4 acc[8];
    #pragma unroll
    for (int nt=0; nt<8; ++nt) acc[nt] = (f32x4){0.f,0.f,0.f,0.f};
    const ushort_t* arow = A + (size_t)(m0 + lr)*128 + lk;
    #pragma unroll
    for (int kc=0; kc<4; ++kc){
        short8 a = *(const short8*)(arow + kc*32);
        #pragma unroll
        for (int nt=0; nt<8; ++nt)
            acc[nt] = __builtin_amdgcn_mfma_f32_16x16x32_bf16(a, bfrag[kc][nt], acc[nt], 0, 0, 0);
    }
    size_t orow = (size_t)m0 + (lane>>4)*4;
    #pragma unroll
    for (int nt=0; nt<8; ++nt){
        int col = nt*16 + lr;
        float bv = bias ? bias[col] : 0.f;
        #pragma unroll
        for (int r=0; r<4; ++r)
            out[(orow + r)*128 + col] = f2bf(acc[nt][r] + bv);
    }
}

// ---------------- GCN aggregate: wide gather (16 lanes/row, 4 edges in flight) + LN ----------
__global__ __launch_bounds__(256) void gcn_agg(float* __restrict__ h, const ushort_t* __restrict__ hwbf,
        const int* __restrict__ offs, const int2* __restrict__ ee,
        const float* __restrict__ dinv, const float* __restrict__ bias,
        const float* __restrict__ lnw, const float* __restrict__ lnb,
        ushort_t* __restrict__ hbf, int last){
    int node = blockIdx.x*4 + (threadIdx.x>>6);
    int lane = threadIdx.x & 63;
    int g = lane >> 4, l = lane & 15;
    const uint4* hw4 = (const uint4*)hwbf;   // 16 B units; one row = 16 uint4
    float p[8];
    // self term (group 0 only; others contribute 0 and get summed in)
    {
        uint4 sv = hw4[(size_t)node*16 + l];
        float di = dinv[node];
        float sw = di*di*((g==0)?1.f:0.f);
        p[0]=sw*bfu_lo(sv.x); p[1]=sw*bfu_hi(sv.x);
        p[2]=sw*bfu_lo(sv.y); p[3]=sw*bfu_hi(sv.y);
        p[4]=sw*bfu_lo(sv.z); p[5]=sw*bfu_hi(sv.z);
        p[6]=sw*bfu_lo(sv.w); p[7]=sw*bfu_hi(sv.w);
    }
    int e0 = offs[node], e1 = offs[node+1];
    int nit = (e1 - e0 + 3) >> 2;
    for (int it = 0; it < nit; ++it){
        int e = e0 + it*4 + g;
        int2 pr = (e < e1) ? ee[e] : make_int2(node, 0);
        float w = __int_as_float(pr.y);
        uint4 v = hw4[(size_t)pr.x*16 + l];
        p[0] += w*bfu_lo(v.x); p[1] += w*bfu_hi(v.x);
        p[2] += w*bfu_lo(v.y); p[3] += w*bfu_hi(v.y);
        p[4] += w*bfu_lo(v.z); p[5] += w*bfu_hi(v.z);
        p[6] += w*bfu_lo(v.w); p[7] += w*bfu_hi(v.w);
    }
    // cross-group reduce: sum over the 4 groups (lanes l, l+16, l+32, l+48)
    #pragma unroll
    for (int j=0;j<8;++j){
        p[j] += __shfl_xor(p[j], 16);
        p[j] += __shfl_xor(p[j], 32);
    }
    // bias
    {
        const float4* b4 = (const float4*)bias;
        float4 b0 = b4[l*2], b1 = b4[l*2+1];
        p[0]+=b0.x; p[1]+=b0.y; p[2]+=b0.z; p[3]+=b0.w;
        p[4]+=b1.x; p[5]+=b1.y; p[6]+=b1.z; p[7]+=b1.w;
    }
    // LN over 128 dims (16 lanes x 8 dims, replicated across groups)
    float s = ((p[0]+p[1])+(p[2]+p[3]))+((p[4]+p[5])+(p[6]+p[7]));
    s += __shfl_xor(s,1); s += __shfl_xor(s,2); s += __shfl_xor(s,4); s += __shfl_xor(s,8);
    float mean = s*(1.f/128.f);
    float var = 0.f;
    #pragma unroll
    for (int j=0;j<8;++j){ p[j] -= mean; var += p[j]*p[j]; }
    var += __shfl_xor(var,1); var += __shfl_xor(var,2); var += __shfl_xor(var,4); var += __shfl_xor(var,8);
    float rs = rsqrtf(var*(1.f/128.f) + 1e-5f);
    float4 w0 = ((const float4*)lnw)[l*2], w1 = ((const float4*)lnw)[l*2+1];
    float4 lb0 = ((const float4*)lnb)[l*2], lb1 = ((const float4*)lnb)[l*2+1];
    float y[8];
    y[0]=p[0]*rs*w0.x+lb0.x; y[1]=p[1]*rs*w0.y+lb0.y; y[2]=p[2]*rs*w0.z+lb0.z; y[3]=p[3]*rs*w0.w+lb0.w;
    y[4]=p[4]*rs*w1.x+lb1.x; y[5]=p[5]*rs*w1.y+lb1.y; y[6]=p[6]*rs*w1.z+lb1.z; y[7]=p[7]*rs*w1.w+lb1.w;
    if (!last){
        float4* hr = (float4*)(h + (size_t)node*128);
        float4 r0 = hr[l*2], r1 = hr[l*2+1];
        y[0]=fmaxf(y[0],0.f)+r0.x; y[1]=fmaxf(y[1],0.f)+r0.y;
        y[2]=fmaxf(y[2],0.f)+r0.z; y[3]=fmaxf(y[3],0.f)+r0.w;
        y[4]=fmaxf(y[4],0.f)+r1.x; y[5]=fmaxf(y[5],0.f)+r1.y;
        y[6]=fmaxf(y[6],0.f)+r1.z; y[7]=fmaxf(y[7],0.f)+r1.w;
        if (g==0){
            hr[l*2]   = make_float4(y[0],y[1],y[2],y[3]);
            hr[l*2+1] = make_float4(y[4],y[5],y[6],y[7]);
        }
    }
    if (g==0){
        uint4 pk;
        pk.x = (unsigned)f2bf(y[0]) | ((unsigned)f2bf(y[1])<<16);
        pk.y = (unsigned)f2bf(y[2]) | ((unsigned)f2bf(y[3])<<16);
        pk.z = (unsigned)f2bf(y[4]) | ((unsigned)f2bf(y[5])<<16);
        pk.w = (unsigned)f2bf(y[6]) | ((unsigned)f2bf(y[7])<<16);
        ((uint4*)hbf)[(size_t)node*16 + l] = pk;
    }
}

// ---------------- decoder small ops ----------------
__global__ __launch_bounds__(256) void bcast_cq(const float* __restrict__ cq, float* __restrict__ t){
    int idx = blockIdx.x*256 + threadIdx.x;
    int r = idx >> 7;
    t[idx] = cq[((r % 12)<<7) | (idx&127)];
}

__global__ __launch_bounds__(256) void ln_rows(const float* __restrict__ x, float* __restrict__ y,
        const float* __restrict__ w, const float* __restrict__ b){
    int r = blockIdx.x*4 + (threadIdx.x>>6);
    int lane = threadIdx.x & 63;
    const float2* x2 = (const float2*)(x + (size_t)r*128);
    float2 v = x2[lane];
    float s = v.x+v.y;
    for (int o=32;o>0;o>>=1) s += __shfl_xor(s,o);
    float mean = s*(1.f/128.f);
    float dx=v.x-mean, dy=v.y-mean;
    float var = dx*dx+dy*dy;
    for (int o=32;o>0;o>>=1) var += __shfl_xor(var,o);
    float rs = rsqrtf(var*(1.f/128.f) + 1e-5f);
    float2 w2=((const float2*)w)[lane], b2=((const float2*)b)[lane];
    ((float2*)(y + (size_t)r*128))[lane] = make_float2(dx*rs*w2.x+b2.x, dy*rs*w2.y+b2.y);
}

// flags: 1 = accumulate into out, 2 = relu
__global__ __launch_bounds__(256) void small_gemm(const float* __restrict__ x, const float* __restrict__ W,
        const float* __restrict__ bias, float* __restrict__ out, int R, int K, int NO, int flags){
    int idx = blockIdx.x*256 + threadIdx.x;
    if (idx >= R*NO) return;
    int r = idx / NO, n = idx - r*NO;
    const float4* xr = (const float4*)(x + (size_t)r*K);
    const float4* wr = (const float4*)(W + (size_t)n*K);
    float a = bias ? bias[n] : 0.0f;
    int K4 = K>>2;
    for (int k=0;k<K4;++k){
        float4 xv = xr[k], wv = wr[k];
        a += xv.x*wv.x + xv.y*wv.y + xv.z*wv.z + xv.w*wv.w;
    }
    if (flags & 2) a = fmaxf(a, 0.f);
    if (flags & 1) a += out[idx];
    out[idx] = a;
}

__global__ __launch_bounds__(64) void self_attn(const float* __restrict__ qkv, float* __restrict__ out){
    int b = blockIdx.x >> 2, hh = blockIdx.x & 3;
    int lane = threadIdx.x;
    __shared__ float q[12][32], k[12][32], v[12][32], sc[12][12];
    for (int idx = lane; idx < 12*32; idx += 64){
        int c = idx>>5, d = idx&31;
        size_t base = (size_t)(b*12+c)*384 + hh*32 + d;
        q[c][d] = qkv[base] * 0.17677669529663687f;
        k[c][d] = qkv[base+128];
        v[c][d] = qkv[base+256];
    }
    __syncthreads();
    for (int p = lane; p < 144; p += 64){
        int qi = p/12, ki = p%12;
        float a = 0;
        #pragma unroll
        for (int d=0; d<32; ++d) a += q[qi][d]*k[ki][d];
        sc[qi][ki] = a;
    }
    __syncthreads();
    if (lane < 12){
        float m = -1e30f;
        for (int j=0;j<12;++j) m = fmaxf(m, sc[lane][j]);
        float sum=0;
        for (int j=0;j<12;++j){ float e=__expf(sc[lane][j]-m); sc[lane][j]=e; sum+=e; }
        float inv=1.f/sum;
        for (int j=0;j<12;++j) sc[lane][j]*=inv;
    }
    __syncthreads();
    for (int p = lane; p < 384; p += 64){
        int c = p>>5, d = p&31;
        float a=0;
        #pragma unroll
        for (int j=0;j<12;++j) a += sc[c][j]*v[j][d];
        out[(size_t)(b*12+c)*128 + hh*32 + d] = a;
    }
}

// ---------------- flash cross-attention, k-split, MFMA for QK^T and PV ----------------
__global__ __launch_bounds__(512) void cross_attn_part(const float* __restrict__ q,
        const ushort_t* __restrict__ K, const ushort_t* __restrict__ V,
        float* __restrict__ opart, float2* __restrict__ mlpart){
    __shared__ __align__(16) ushort_t qs[16*136];
    __shared__ __align__(16) unsigned char uni[128*136*2];
    __shared__ __align__(16) ushort_t pbf[4*16*136];
    __shared__ float2 ml[48];
    float* s32 = (float*)uni;
    ushort_t* vt = (ushort_t*)uni;

    int tid = threadIdx.x;
    int b = blockIdx.x / NSPLIT, sp = blockIdx.x % NSPLIT;
    int k0 = sp * CHUNK;
    int lane = tid & 63, w = tid >> 6;
    int lr = lane & 15, hi8 = (lane >> 4) * 8;

    const unsigned* Vu = (const unsigned*)V + ((size_t)b*1000 + k0)*64;
    unsigned vreg[16];
    #pragma unroll
    for (int j=0;j<15;++j) vreg[j] = Vu[tid + j*512];
    if (tid < 320) vreg[15] = Vu[tid + 7680];

    for (int i = tid; i < 16*128; i += 512){
        int r = i >> 7, c = i & 127;
        ushort_t v = 0;
        if (r < 12) v = f2bf(q[((size_t)b*12 + r)*128 + c] * 0.17677669529663687f);
        qs[r*136 + c] = v;
    }
    for (int i = tid; i < 4352; i += 512) ((unsigned*)pbf)[i] = 0;
    __syncthreads();

    {
        int krow = k0 + w*16 + lr; if (krow > k0 + 124) krow = k0 + 124;
        const ushort_t* Krow = K + ((size_t)b*1000 + krow)*128 + hi8;
        #pragma unroll
        for (int h=0; h<4; ++h){
            short8 kf = *(const short8*)(Krow + h*32);
            short8 qf = *(const short8*)&qs[lr*136 + h*32 + hi8];
            f32x4 d = __builtin_amdgcn_mfma_f32_16x16x32_bf16(qf, kf, (f32x4){0,0,0,0}, 0, 0, 0);
            int qbase = (lane>>4)*4;
            #pragma unroll
            for (int r=0; r<4; ++r){
                int qq = qbase + r;
                if (qq < 12) s32[(h*12+qq)*130 + w*16 + lr] = d[r];
            }
        }
    }
    __syncthreads();

    if (tid < 192){
        int hq = tid >> 2, sub = tid & 3;
        int h = hq / 12, qq = hq - h*12;
        float m = -1e30f;
        for (int kk = sub; kk < CHUNK; kk += 4) m = fmaxf(m, s32[hq*130 + kk]);
        m = fmaxf(m, __shfl_xor(m, 1));
        m = fmaxf(m, __shfl_xor(m, 2));
        float l = 0.f;
        for (int kk = sub; kk < CHUNK; kk += 4){
            float e = __expf(s32[hq*130 + kk] - m);
            l += e;
            pbf[(h*16+qq)*136 + kk] = f2bf(e);
        }
        l += __shfl_xor(l, 1);
        l += __shfl_xor(l, 2);
        if (sub == 0) ml[hq] = make_float2(m, l);
    }
    __syncthreads();

    #pragma unroll
    for (int j=0;j<15;++j){
        int i = tid + j*512;
        int kk = i >> 6, dp = (i & 63)*2;
        unsigned u = vreg[j];
        vt[dp*136 + kk]     = (ushort_t)(u & 0xFFFF);
        vt[(dp+1)*136 + kk] = (ushort_t)(u >> 16);
    }
    if (tid < 320){
        int i = tid + 7680;
        int kk = i >> 6, dp = (i & 63)*2;
        unsigned u = vreg[15];
        vt[dp*136 + kk]     = (ushort_t)(u & 0xFFFF);
        vt[(dp+1)*136 + kk] = (ushort_t)(u >> 16);
    }
    if (tid < 384){
        int dp = tid / 3, kk = 125 + tid % 3;
        vt[dp*136 + kk] = 0;
    }
    __syncthreads();

    {
        int h = w >> 1;
        f32x4 acc = (f32x4){0,0,0,0};
        #pragma unroll
        for (int kc=0; kc<4; ++kc){
            short8 pf = *(const short8*)&pbf[(h*16+lr)*136 + kc*32 + hi8];
            short8 vf = *(const short8*)&vt[(w*16+lr)*136 + kc*32 + hi8];
            acc = __builtin_amdgcn_mfma_f32_16x16x32_bf16(pf, vf, acc, 0, 0, 0);
        }
        int qbase = (lane>>4)*4;
        float* ob = opart + ((size_t)(b*NSPLIT+sp)*12)*128;
        #pragma unroll
        for (int r=0; r<4; ++r){
            int qq = qbase + r;
            if (qq < 12) ob[(size_t)qq*128 + w*16 + lr] = acc[r];
        }
    }
    if (tid < 48) mlpart[(size_t)(b*NSPLIT+sp)*48 + tid] = ml[tid];
}

__global__ __launch_bounds__(256) void cross_attn_comb(const float* __restrict__ opart,
        const float* __restrict__ mlpart, float* __restrict__ att){
    int b = blockIdx.x, tid = threadIdx.x;
    __shared__ float mls[NSPLIT*48*2];
    for (int i = tid; i < NSPLIT*48*2; i += 256) mls[i] = mlpart[(size_t)b*NSPLIT*96 + i];
    __syncthreads();
    for (int p = tid; p < 1536; p += 256){
        int qq = p >> 7, dp = p & 127, h = dp >> 5, hq = h*12 + qq;
        float M = -1e30f;
        #pragma unroll
        for (int sp=0; sp<NSPLIT; ++sp) M = fmaxf(M, mls[sp*96 + hq*2]);
        float L = 0.f, O = 0.f;
        #pragma unroll
        for (int sp=0; sp<NSPLIT; ++sp){
            float wgt = __expf(mls[sp*96 + hq*2] - M);
            L += wgt * mls[sp*96 + hq*2 + 1];
            O += wgt * opart[((size_t)(b*NSPLIT+sp)*12 + qq)*128 + dp];
        }
        att[((size_t)b*12 + qq)*128 + dp] = O / L;
    }
}

__global__ __launch_bounds__(256) void final_out(const float* __restrict__ t,
        const float* __restrict__ lw, const float* __restrict__ lb,
        const float* __restrict__ ow, const float* __restrict__ ob, float* __restrict__ out){
    int r = blockIdx.x*4 + (threadIdx.x>>6);
    int lane = threadIdx.x & 63;
    const float2* x2 = (const float2*)(t + (size_t)r*128);
    float2 v = x2[lane];
    float s = v.x+v.y;
    for (int o=32;o>0;o>>=1) s += __shfl_xor(s,o);
    float mean = s*(1.f/128.f);
    float dx=v.x-mean, dy=v.y-mean;
    float var = dx*dx+dy*dy;
    for (int o=32;o>0;o>>=1) var += __shfl_xor(var,o);
    float rs = rsqrtf(var*(1.f/128.f)+1e-5f);
    float2 w2=((const float2*)lw)[lane], b2=((const float2*)lb)[lane];
    float2 o2=((const float2*)ow)[lane];
    float d = (dx*rs*w2.x+b2.x)*o2.x + (dy*rs*w2.y+b2.y)*o2.y;
    for (int o=32;o>0;o>>=1) d += __shfl_xor(d,o);
    if (lane==0) out[r] = d + ob[0];
}

extern "C" void kernel_launch(void* const* d_in, const int* in_sizes, int n_in,
                              void* d_out, int out_size, void* d_ws, size_t ws_size,
                              hipStream_t stream){
    (void)in_sizes; (void)n_in; (void)out_size; (void)ws_size;
    const float* x        = (const float*)d_in[0];
    const int*   eidx     = (const int*)d_in[1];
    const float* in_w     = (const float*)d_in[3];
    const float* in_b     = (const float*)d_in[4];
    const float* gcn_w    = (const float*)d_in[5];
    const float* gcn_b    = (const float*)d_in[6];
    const float* ln_w     = (const float*)d_in[7];
    const float* ln_b     = (const float*)d_in[8];
    const float* cq       = (const float*)d_in[9];
    const float* sa_qkv_w = (const float*)d_in[10];
    const float* sa_qkv_b = (const float*)d_in[11];
    const float* sa_out_w = (const float*)d_in[12];
    const float* sa_out_b = (const float*)d_in[13];
    const float* ca_qkv_w = (const float*)d_in[14];
    const float* ca_qkv_b = (const float*)d_in[15];
    const float* ca_out_w = (const float*)d_in[16];
    const float* ca_out_b = (const float*)d_in[17];
    const float* n1w=(const float*)d_in[18]; const float* n1b=(const float*)d_in[19];
    const float* n2w=(const float*)d_in[20]; const float* n2b=(const float*)d_in[21];
    const float* n3w=(const float*)d_in[22]; const float* n3b=(const float*)d_in[23];
    const float* ff1w=(const float*)d_in[24]; const float* ff1b=(const float*)d_in[25];
    const float* ff2w=(const float*)d_in[26]; const float* ff2b=(const float*)d_in[27];
    const float* opln_w=(const float*)d_in[28]; const float* opln_b=(const float*)d_in[29];
    const float* opw=(const float*)d_in[30]; const float* opb=(const float*)d_in[31];
    float* out = (float*)d_out;

    char* base = (char*)d_ws;
    size_t off = 0;
    auto alloc = [&](size_t bytes)->void*{
        void* r = base + off; off += (bytes + 255) & ~(size_t)255; return r;
    };
    float*    h     = (float*)alloc((size_t)NNODES*DD*4);
    ushort_t* hbf   = (ushort_t*)alloc((size_t)NNODES*DD*2);
    ushort_t* kbf   = (ushort_t*)alloc((size_t)NNODES*DD*2);  // also hwbf during GCN loop
    ushort_t* vbf   = (ushort_t*)alloc((size_t)NNODES*DD*2);
    ushort_t* Wb    = (ushort_t*)alloc((size_t)5*DD*DD*2);
    ushort_t* Wpad  = (ushort_t*)alloc((size_t)DD*32*2);
    float*    dinv  = (float*)alloc((size_t)NNODES*4);
    int*      cnt   = (int*)  alloc((size_t)NNODES*4);
    int*      offs  = (int*)  alloc((size_t)(NNODES+1)*4);
    int*      bsum  = (int*)  alloc(512*4);
    int2*     ee    = (int2*) alloc((size_t)NEDGES*8);
    float*    t     = (float*)alloc((size_t)NROWS*DD*4);
    float*    tn    = (float*)alloc((size_t)NROWS*DD*4);
    float*    sq    = (float*)alloc((size_t)NROWS*384*4);
    float*    att   = (float*)alloc((size_t)NROWS*DD*4);
    float*    ffh   = (float*)alloc((size_t)NROWS*512*4);
    float*    opart = (float*)alloc((size_t)BB*NSPLIT*12*128*4);
    float2*   mlprt = (float2*)alloc((size_t)BB*NSPLIT*48*8);
    ushort_t* hwbf  = kbf;

    const int* erow = eidx;
    const int* ecol = eidx + NEDGES;

    // CSR build (once, reused by all 3 GCN layers)
    hipMemsetAsync(cnt, 0, (size_t)NNODES*4, stream);
    count_edges<<<NEDGES/256, 256, 0, stream>>>(ecol, cnt);
    compute_dinv<<<NNODES/256, 256, 0, stream>>>(cnt, dinv);
    scan_a<<<NNODES/256, 256, 0, stream>>>(cnt, offs, bsum);
    scan_b<<<1, 512, 0, stream>>>(bsum, NNODES/256);
    scan_c<<<NNODES/256, 256, 0, stream>>>(offs, bsum);
    hipMemsetAsync(cnt, 0, (size_t)NNODES*4, stream);
    fill_csr<<<NEDGES/256, 256, 0, stream>>>(erow, ecol, offs, cnt, dinv, ee);

    conv_w<<<5*DD*DD/256, 256, 0, stream>>>(gcn_w, ca_qkv_w, Wb);
    conv_wpad<<<DD*32/256, 256, 0, stream>>>(in_w, Wpad);

    // node pipeline
    in_proj_mfma<<<NNODES/64, 256, 0, stream>>>(x, Wpad, in_b, h, hbf);
    for (int i=0;i<3;++i){
        gemm_mfma<<<NNODES/64, 256, 0, stream>>>(hbf, Wb + (size_t)i*DD*DD, nullptr, hwbf);
        gcn_agg<<<NNODES/4, 256, 0, stream>>>(h, hwbf, offs, ee, dinv,
                gcn_b + (size_t)i*DD, ln_w + (size_t)i*DD, ln_b + (size_t)i*DD, hbf, i==2);
    }
    // cross-attn K,V projections (bf16 out)
    gemm_mfma<<<NNODES/64, 256, 0, stream>>>(hbf, Wb + (size_t)3*DD*DD, ca_qkv_b + DD,   kbf);
    gemm_mfma<<<NNODES/64, 256, 0, stream>>>(hbf, Wb + (size_t)4*DD*DD, ca_qkv_b + 2*DD, vbf);

    // decoder layer (norm_first)
    bcast_cq<<<NROWS*DD/256, 256, 0, stream>>>(cq, t);
    ln_rows<<<NROWS/4, 256, 0, stream>>>(t, tn, n1w, n1b);
    small_gemm<<<NROWS*384/256, 256, 0, stream>>>(tn, sa_qkv_w, sa_qkv_b, sq, NROWS, 128, 384, 0);
    self_attn<<<BB*4, 64, 0, stream>>>(sq, att);
    small_gemm<<<NROWS*128/256, 256, 0, stream>>>(att, sa_out_w, sa_out_b, t, NROWS, 128, 128, 1);
    ln_rows<<<NROWS/4, 256, 0, stream>>>(t, tn, n2w, n2b);
    small_gemm<<<NROWS*128/256, 256, 0, stream>>>(tn, ca_qkv_w, ca_qkv_b, sq, NROWS, 128, 128, 0);
    cross_attn_part<<<BB*NSPLIT, 512, 0, stream>>>(sq, kbf, vbf, opart, mlprt);
    cross_attn_comb<<<BB, 256, 0, stream>>>(opart, (const float*)mlprt, att);
    small_gemm<<<NROWS*128/256, 256, 0, stream>>>(att, ca_out_w, ca_out_b, t, NROWS, 128, 128, 1);
    ln_rows<<<NROWS/4, 256, 0, stream>>>(t, tn, n3w, n3b);
    small_gemm<<<NROWS*512/256, 256, 0, stream>>>(tn, ff1w, ff1b, ffh, NROWS, 128, 512, 2);
    small_gemm<<<NROWS*128/256, 256, 0, stream>>>(ffh, ff2w, ff2b, t, NROWS, 512, 128, 1);
    final_out<<<NROWS/4, 256, 0, stream>>>(t, opln_w, opln_b, opw, opb, out);
}

// Round 6
// 617.540 us; speedup vs baseline: 2.2627x; 1.2804x over previous
//
#include <hip/hip_runtime.h>

#define NNODES 128000
#define NEDGES 640000
#define BB 128
#define CC 12
#define DD 128
#define NROWS (BB*CC)   // 1536
#define NSPLIT 8
#define CHUNK 125

typedef __attribute__((ext_vector_type(8))) short short8;
typedef __attribute__((ext_vector_type(4))) float f32x4;
typedef unsigned short ushort_t;

__device__ __forceinline__ ushort_t f2bf(float f){
    union { float f; unsigned u; } v; v.f = f;
    unsigned r = (v.u + 0x7FFF + ((v.u >> 16) & 1)) >> 16;  // RNE
    return (ushort_t)r;
}
__device__ __forceinline__ float bfu_lo(unsigned u){
    union { unsigned u; float f; } v; v.u = u << 16; return v.f;
}
__device__ __forceinline__ float bfu_hi(unsigned u){
    union { unsigned u; float f; } v; v.u = u & 0xFFFF0000u; return v.f;
}

// ---------------- CSR build ----------------
__global__ __launch_bounds__(256) void count_edges(const int* __restrict__ col, int* __restrict__ cnt){
    int e = blockIdx.x*256 + threadIdx.x;
    if (e < NEDGES) atomicAdd(&cnt[col[e]], 1);
}

__global__ __launch_bounds__(256) void compute_dinv(const int* __restrict__ cnt, float* __restrict__ dinv){
    int i = blockIdx.x*256 + threadIdx.x;
    if (i < NNODES) dinv[i] = rsqrtf((float)cnt[i] + 1.0f);
}

__global__ __launch_bounds__(256) void scan_a(const int* __restrict__ cnt, int* __restrict__ offs, int* __restrict__ bsum){
    __shared__ int tmp[256];
    int tid = threadIdx.x;
    int g = blockIdx.x*256 + tid;
    int v = cnt[g];
    tmp[tid] = v;
    __syncthreads();
    for (int o=1;o<256;o<<=1){
        int a = (tid>=o)? tmp[tid-o] : 0;
        __syncthreads();
        tmp[tid] += a;
        __syncthreads();
    }
    offs[g] = tmp[tid] - v;
    if (tid==255) bsum[blockIdx.x] = tmp[255];
}

__global__ __launch_bounds__(512) void scan_b(int* __restrict__ bsum, int NB){
    __shared__ int tmp[512];
    int tid = threadIdx.x;
    int v = (tid<NB)? bsum[tid] : 0;
    tmp[tid] = v;
    __syncthreads();
    for (int o=1;o<512;o<<=1){
        int a = (tid>=o)? tmp[tid-o] : 0;
        __syncthreads();
        tmp[tid] += a;
        __syncthreads();
    }
    if (tid<NB) bsum[tid] = tmp[tid] - v;
}

__global__ __launch_bounds__(256) void scan_c(int* __restrict__ offs, const int* __restrict__ bsum){
    int g = blockIdx.x*256 + threadIdx.x;
    offs[g] += bsum[g>>8];
    if (g==0) offs[NNODES] = NEDGES;
}

__global__ __launch_bounds__(256) void fill_csr(const int* __restrict__ row, const int* __restrict__ col,
        const int* __restrict__ offs, int* __restrict__ cur, const float* __restrict__ dinv,
        int2* __restrict__ ee){
    int e = blockIdx.x*256 + threadIdx.x;
    if (e >= NEDGES) return;
    int c = col[e], r = row[e];
    int p = atomicAdd(&cur[c], 1);
    int idx = offs[c] + p;
    float w = dinv[r]*dinv[c];
    ee[idx] = make_int2(r, __float_as_int(w));
}

// ---------------- weight conversions ----------------
__global__ __launch_bounds__(256) void conv_w(const float* __restrict__ gcn_w,
        const float* __restrict__ ca_qkv_w, ushort_t* __restrict__ Wb){
    int i = blockIdx.x*256 + threadIdx.x;   // < 5*16384
    int slot = i >> 14, off = i & 16383;
    float v = (slot < 3) ? gcn_w[slot*16384 + off]
                         : ca_qkv_w[16384 + (slot-3)*16384 + off];
    Wb[i] = f2bf(v);
}

// in_w [128][16] -> bf16 padded [128][32] (zeros k>=16)
__global__ __launch_bounds__(256) void conv_wpad(const float* __restrict__ in_w, ushort_t* __restrict__ Wpad){
    int i = blockIdx.x*256 + threadIdx.x;   // < 4096
    int n = i >> 5, k = i & 31;
    Wpad[i] = (k < 16) ? f2bf(in_w[n*16 + k]) : (ushort_t)0;
}

// decoder weights: ca_out (128x128) | ff1 (512x128) | ff2 (128x512)
__global__ __launch_bounds__(256) void conv_wdec(const float* __restrict__ caout,
        const float* __restrict__ ff1, const float* __restrict__ ff2, ushort_t* __restrict__ Wd){
    int i = blockIdx.x*256 + threadIdx.x;   // < 147456
    float v;
    if (i < 16384) v = caout[i];
    else if (i < 81920) v = ff1[i - 16384];
    else v = ff2[i - 81920];
    Wd[i] = f2bf(v);
}

// ---------------- input projection via MFMA ----------------
__global__ __launch_bounds__(256) void in_proj_mfma(const float* __restrict__ x,
        const ushort_t* __restrict__ Wpad, const float* __restrict__ bias,
        float* __restrict__ h, ushort_t* __restrict__ hbf){
    __shared__ __align__(16) ushort_t xs[64*32];
    int tid = threadIdx.x;
    int m0 = blockIdx.x*64;
    if (tid < 128){
        short8 z = {0,0,0,0,0,0,0,0};
        *(short8*)&xs[(tid>>1)*32 + 16 + (tid&1)*8] = z;
    }
    float4 xv = *(const float4*)(x + (size_t)m0*16 + tid*4);
    uint2 pk2;
    pk2.x = (unsigned)f2bf(xv.x) | ((unsigned)f2bf(xv.y) << 16);
    pk2.y = (unsigned)f2bf(xv.z) | ((unsigned)f2bf(xv.w) << 16);
    *(uint2*)&xs[(tid>>2)*32 + (tid&3)*4] = pk2;
    __syncthreads();
    int lane = tid & 63, w = tid >> 6;
    int lr = lane & 15, lk = (lane>>4)*8;
    short8 bfrag[8];
    #pragma unroll
    for (int nt=0; nt<8; ++nt)
        bfrag[nt] = *(const short8*)&Wpad[(nt*16 + lr)*32 + lk];
    short8 a = *(const short8*)&xs[(w*16 + lr)*32 + lk];
    f32x4 acc[8];
    #pragma unroll
    for (int nt=0; nt<8; ++nt)
        acc[nt] = __builtin_amdgcn_mfma_f32_16x16x32_bf16(a, bfrag[nt], (f32x4){0,0,0,0}, 0, 0, 0);
    size_t orow = (size_t)m0 + w*16 + (lane>>4)*4;
    #pragma unroll
    for (int nt=0; nt<8; ++nt){
        int col = nt*16 + lr;
        float bv = bias[col];
        #pragma unroll
        for (int r=0; r<4; ++r){
            float val = acc[nt][r] + bv;
            h[(orow + r)*128 + col] = val;
            hbf[(orow + r)*128 + col] = f2bf(val);
        }
    }
}

// ---------------- MFMA GEMM (node pipeline, K=N=128, bf16 out) ----------------
__global__ __launch_bounds__(256) void gemm_mfma(const ushort_t* __restrict__ A,
        const ushort_t* __restrict__ Wb, const float* __restrict__ bias, ushort_t* __restrict__ out){
    int lane = threadIdx.x & 63, wave = threadIdx.x >> 6;
    int m0 = blockIdx.x*64 + wave*16;
    int lr = lane & 15;
    int lk = (lane >> 4) * 8;
    short8 bfrag[4][8];
    #pragma unroll
    for (int nt=0; nt<8; ++nt)
        #pragma unroll
        for (int kc=0; kc<4; ++kc)
            bfrag[kc][nt] = *(const short8*)&Wb[(nt*16 + lr)*128 + kc*32 + lk];
    f32x4 acc[8];
    #pragma unroll
    for (int nt=0; nt<8; ++nt) acc[nt] = (f32x4){0.f,0.f,0.f,0.f};
    const ushort_t* arow = A + (size_t)(m0 + lr)*128 + lk;
    #pragma unroll
    for (int kc=0; kc<4; ++kc){
        short8 a = *(const short8*)(arow + kc*32);
        #pragma unroll
        for (int nt=0; nt<8; ++nt)
            acc[nt] = __builtin_amdgcn_mfma_f32_16x16x32_bf16(a, bfrag[kc][nt], acc[nt], 0, 0, 0);
    }
    size_t orow = (size_t)m0 + (lane>>4)*4;
    #pragma unroll
    for (int nt=0; nt<8; ++nt){
        int col = nt*16 + lr;
        float bv = bias ? bias[col] : 0.f;
        #pragma unroll
        for (int r=0; r<4; ++r)
            out[(orow + r)*128 + col] = f2bf(acc[nt][r] + bv);
    }
}

// ---------------- decoder MFMA GEMM: flexible K (mult of 128), NO via grid.y ----------------
// flags: 1=accumulate into out(fp32), 2=relu, 4=write outbf, 8=write out fp32
__global__ __launch_bounds__(256) void dec_gemm(const ushort_t* __restrict__ A,
        const ushort_t* __restrict__ Wb, const float* __restrict__ bias,
        float* __restrict__ out, ushort_t* __restrict__ outbf,
        int K, int NO, int flags){
    int lane = threadIdx.x & 63, wave = threadIdx.x >> 6;
    int m0 = blockIdx.x*64 + wave*16;
    int n0 = blockIdx.y*128;
    int lr = lane & 15, lk = (lane>>4)*8;
    f32x4 acc[8];
    #pragma unroll
    for (int nt=0; nt<8; ++nt) acc[nt] = (f32x4){0.f,0.f,0.f,0.f};
    for (int ko = 0; ko < K; ko += 128){
        short8 bfrag[4][8];
        #pragma unroll
        for (int nt=0; nt<8; ++nt)
            #pragma unroll
            for (int kc=0; kc<4; ++kc)
                bfrag[kc][nt] = *(const short8*)&Wb[(size_t)(n0 + nt*16 + lr)*K + ko + kc*32 + lk];
        const ushort_t* arow = A + (size_t)(m0 + lr)*K + ko + lk;
        #pragma unroll
        for (int kc=0; kc<4; ++kc){
            short8 a = *(const short8*)(arow + kc*32);
            #pragma unroll
            for (int nt=0; nt<8; ++nt)
                acc[nt] = __builtin_amdgcn_mfma_f32_16x16x32_bf16(a, bfrag[kc][nt], acc[nt], 0, 0, 0);
        }
    }
    int orow0 = m0 + (lane>>4)*4;
    #pragma unroll
    for (int nt=0; nt<8; ++nt){
        int col = n0 + nt*16 + lr;
        float bv = bias[col];
        #pragma unroll
        for (int r=0; r<4; ++r){
            size_t idx = (size_t)(orow0 + r)*NO + col;
            float val = acc[nt][r] + bv;
            if (flags & 2) val = fmaxf(val, 0.f);
            if (flags & 1) val += out[idx];
            if (flags & 8) out[idx] = val;
            if (flags & 4) outbf[idx] = f2bf(val);
        }
    }
}

// ---------------- GCN aggregate: wide gather + LN ----------------
__global__ __launch_bounds__(256) void gcn_agg(float* __restrict__ h, const ushort_t* __restrict__ hwbf,
        const int* __restrict__ offs, const int2* __restrict__ ee,
        const float* __restrict__ dinv, const float* __restrict__ bias,
        const float* __restrict__ lnw, const float* __restrict__ lnb,
        ushort_t* __restrict__ hbf, int last){
    int node = blockIdx.x*4 + (threadIdx.x>>6);
    int lane = threadIdx.x & 63;
    int g = lane >> 4, l = lane & 15;
    const uint4* hw4 = (const uint4*)hwbf;
    float p[8];
    {
        uint4 sv = hw4[(size_t)node*16 + l];
        float di = dinv[node];
        float sw = di*di*((g==0)?1.f:0.f);
        p[0]=sw*bfu_lo(sv.x); p[1]=sw*bfu_hi(sv.x);
        p[2]=sw*bfu_lo(sv.y); p[3]=sw*bfu_hi(sv.y);
        p[4]=sw*bfu_lo(sv.z); p[5]=sw*bfu_hi(sv.z);
        p[6]=sw*bfu_lo(sv.w); p[7]=sw*bfu_hi(sv.w);
    }
    int e0 = offs[node], e1 = offs[node+1];
    int nit = (e1 - e0 + 3) >> 2;
    for (int it = 0; it < nit; ++it){
        int e = e0 + it*4 + g;
        int2 pr = (e < e1) ? ee[e] : make_int2(node, 0);
        float w = __int_as_float(pr.y);
        uint4 v = hw4[(size_t)pr.x*16 + l];
        p[0] += w*bfu_lo(v.x); p[1] += w*bfu_hi(v.x);
        p[2] += w*bfu_lo(v.y); p[3] += w*bfu_hi(v.y);
        p[4] += w*bfu_lo(v.z); p[5] += w*bfu_hi(v.z);
        p[6] += w*bfu_lo(v.w); p[7] += w*bfu_hi(v.w);
    }
    #pragma unroll
    for (int j=0;j<8;++j){
        p[j] += __shfl_xor(p[j], 16);
        p[j] += __shfl_xor(p[j], 32);
    }
    {
        const float4* b4 = (const float4*)bias;
        float4 b0 = b4[l*2], b1 = b4[l*2+1];
        p[0]+=b0.x; p[1]+=b0.y; p[2]+=b0.z; p[3]+=b0.w;
        p[4]+=b1.x; p[5]+=b1.y; p[6]+=b1.z; p[7]+=b1.w;
    }
    float s = ((p[0]+p[1])+(p[2]+p[3]))+((p[4]+p[5])+(p[6]+p[7]));
    s += __shfl_xor(s,1); s += __shfl_xor(s,2); s += __shfl_xor(s,4); s += __shfl_xor(s,8);
    float mean = s*(1.f/128.f);
    float var = 0.f;
    #pragma unroll
    for (int j=0;j<8;++j){ p[j] -= mean; var += p[j]*p[j]; }
    var += __shfl_xor(var,1); var += __shfl_xor(var,2); var += __shfl_xor(var,4); var += __shfl_xor(var,8);
    float rs = rsqrtf(var*(1.f/128.f) + 1e-5f);
    float4 w0 = ((const float4*)lnw)[l*2], w1 = ((const float4*)lnw)[l*2+1];
    float4 lb0 = ((const float4*)lnb)[l*2], lb1 = ((const float4*)lnb)[l*2+1];
    float y[8];
    y[0]=p[0]*rs*w0.x+lb0.x; y[1]=p[1]*rs*w0.y+lb0.y; y[2]=p[2]*rs*w0.z+lb0.z; y[3]=p[3]*rs*w0.w+lb0.w;
    y[4]=p[4]*rs*w1.x+lb1.x; y[5]=p[5]*rs*w1.y+lb1.y; y[6]=p[6]*rs*w1.z+lb1.z; y[7]=p[7]*rs*w1.w+lb1.w;
    if (!last){
        float4* hr = (float4*)(h + (size_t)node*128);
        float4 r0 = hr[l*2], r1 = hr[l*2+1];
        y[0]=fmaxf(y[0],0.f)+r0.x; y[1]=fmaxf(y[1],0.f)+r0.y;
        y[2]=fmaxf(y[2],0.f)+r0.z; y[3]=fmaxf(y[3],0.f)+r0.w;
        y[4]=fmaxf(y[4],0.f)+r1.x; y[5]=fmaxf(y[5],0.f)+r1.y;
        y[6]=fmaxf(y[6],0.f)+r1.z; y[7]=fmaxf(y[7],0.f)+r1.w;
        if (g==0){
            hr[l*2]   = make_float4(y[0],y[1],y[2],y[3]);
            hr[l*2+1] = make_float4(y[4],y[5],y[6],y[7]);
        }
    }
    if (g==0){
        uint4 pk;
        pk.x = (unsigned)f2bf(y[0]) | ((unsigned)f2bf(y[1])<<16);
        pk.y = (unsigned)f2bf(y[2]) | ((unsigned)f2bf(y[3])<<16);
        pk.z = (unsigned)f2bf(y[4]) | ((unsigned)f2bf(y[5])<<16);
        pk.w = (unsigned)f2bf(y[6]) | ((unsigned)f2bf(y[7])<<16);
        ((uint4*)hbf)[(size_t)node*16 + l] = pk;
    }
}

// ---------------- decoder small ops ----------------
// LN over rows (fp32 out) - used for 12-row batch-invariant prefix
__global__ __launch_bounds__(256) void ln_rows(const float* __restrict__ x, float* __restrict__ y,
        const float* __restrict__ w, const float* __restrict__ b){
    int r = blockIdx.x*4 + (threadIdx.x>>6);
    int lane = threadIdx.x & 63;
    const float2* x2 = (const float2*)(x + (size_t)r*128);
    float2 v = x2[lane];
    float s = v.x+v.y;
    for (int o=32;o>0;o>>=1) s += __shfl_xor(s,o);
    float mean = s*(1.f/128.f);
    float dx=v.x-mean, dy=v.y-mean;
    float var = dx*dx+dy*dy;
    for (int o=32;o>0;o>>=1) var += __shfl_xor(var,o);
    float rs = rsqrtf(var*(1.f/128.f) + 1e-5f);
    float2 w2=((const float2*)w)[lane], b2=((const float2*)b)[lane];
    ((float2*)(y + (size_t)r*128))[lane] = make_float2(dx*rs*w2.x+b2.x, dy*rs*w2.y+b2.y);
}

// LN over rows (bf16 out) - full 1536 rows before FF
__global__ __launch_bounds__(256) void ln_rows_bf(const float* __restrict__ x, ushort_t* __restrict__ y,
        const float* __restrict__ w, const float* __restrict__ b){
    int r = blockIdx.x*4 + (threadIdx.x>>6);
    int lane = threadIdx.x & 63;
    const float2* x2 = (const float2*)(x + (size_t)r*128);
    float2 v = x2[lane];
    float s = v.x+v.y;
    for (int o=32;o>0;o>>=1) s += __shfl_xor(s,o);
    float mean = s*(1.f/128.f);
    float dx=v.x-mean, dy=v.y-mean;
    float var = dx*dx+dy*dy;
    for (int o=32;o>0;o>>=1) var += __shfl_xor(var,o);
    float rs = rsqrtf(var*(1.f/128.f) + 1e-5f);
    float2 w2=((const float2*)w)[lane], b2=((const float2*)b)[lane];
    float yx = dx*rs*w2.x+b2.x, yy = dy*rs*w2.y+b2.y;
    ((unsigned*)y)[(size_t)r*64 + lane] = (unsigned)f2bf(yx) | ((unsigned)f2bf(yy)<<16);
}

// naive fp32 gemm for 12-row prefix. flags: 1=acc, 2=relu
__global__ __launch_bounds__(256) void small_gemm(const float* __restrict__ x, const float* __restrict__ W,
        const float* __restrict__ bias, float* __restrict__ out, int R, int K, int NO, int flags){
    int idx = blockIdx.x*256 + threadIdx.x;
    if (idx >= R*NO) return;
    int r = idx / NO, n = idx - r*NO;
    const float4* xr = (const float4*)(x + (size_t)r*K);
    const float4* wr = (const float4*)(W + (size_t)n*K);
    float a = bias ? bias[n] : 0.0f;
    int K4 = K>>2;
    for (int k=0;k<K4;++k){
        float4 xv = xr[k], wv = wr[k];
        a += xv.x*wv.x + xv.y*wv.y + xv.z*wv.z + xv.w*wv.w;
    }
    if (flags & 2) a = fmaxf(a, 0.f);
    if (flags & 1) a += out[idx];
    out[idx] = a;
}

__global__ __launch_bounds__(256) void copy12(const float* __restrict__ cq, float* __restrict__ t12){
    int i = blockIdx.x*256 + threadIdx.x;   // < 1536
    t12[i] = cq[i];
}

// t_full[r][:] = t12[r%12][:]
__global__ __launch_bounds__(256) void bcast_t(const float* __restrict__ t12, float* __restrict__ t_full){
    int idx = blockIdx.x*256 + threadIdx.x;  // < 1536*128
    int r = idx >> 7;
    t_full[idx] = t12[(r % 12)*128 + (idx & 127)];
}

// self-attention on the 12 batch-invariant rows; grid = 4 heads
__global__ __launch_bounds__(64) void self_attn12(const float* __restrict__ qkv, float* __restrict__ out){
    int hh = blockIdx.x;
    int lane = threadIdx.x;
    __shared__ float q[12][32], k[12][32], v[12][32], sc[12][12];
    for (int idx = lane; idx < 12*32; idx += 64){
        int c = idx>>5, d = idx&31;
        size_t base = (size_t)c*384 + hh*32 + d;
        q[c][d] = qkv[base] * 0.17677669529663687f;
        k[c][d] = qkv[base+128];
        v[c][d] = qkv[base+256];
    }
    __syncthreads();
    for (int p = lane; p < 144; p += 64){
        int qi = p/12, ki = p%12;
        float a = 0;
        #pragma unroll
        for (int d=0; d<32; ++d) a += q[qi][d]*k[ki][d];
        sc[qi][ki] = a;
    }
    __syncthreads();
    if (lane < 12){
        float m = -1e30f;
        for (int j=0;j<12;++j) m = fmaxf(m, sc[lane][j]);
        float sum=0;
        for (int j=0;j<12;++j){ float e=__expf(sc[lane][j]-m); sc[lane][j]=e; sum+=e; }
        float inv=1.f/sum;
        for (int j=0;j<12;++j) sc[lane][j]*=inv;
    }
    __syncthreads();
    for (int p = lane; p < 384; p += 64){
        int c = p>>5, d = p&31;
        float a=0;
        #pragma unroll
        for (int j=0;j<12;++j) a += sc[c][j]*v[j][d];
        out[(size_t)c*128 + hh*32 + d] = a;
    }
}

// ---------------- flash cross-attention, k-split, MFMA; shared q12 ----------------
__global__ __launch_bounds__(512) void cross_attn_part(const float* __restrict__ q12,
        const ushort_t* __restrict__ K, const ushort_t* __restrict__ V,
        float* __restrict__ opart, float2* __restrict__ mlpart){
    __shared__ __align__(16) ushort_t qs[16*136];
    __shared__ __align__(16) unsigned char uni[128*136*2];
    __shared__ __align__(16) ushort_t pbf[4*16*136];
    __shared__ float2 ml[48];
    float* s32 = (float*)uni;
    ushort_t* vt = (ushort_t*)uni;

    int tid = threadIdx.x;
    int b = blockIdx.x / NSPLIT, sp = blockIdx.x % NSPLIT;
    int k0 = sp * CHUNK;
    int lane = tid & 63, w = tid >> 6;
    int lr = lane & 15, hi8 = (lane >> 4) * 8;

    const unsigned* Vu = (const unsigned*)V + ((size_t)b*1000 + k0)*64;
    unsigned vreg[16];
    #pragma unroll
    for (int j=0;j<15;++j) vreg[j] = Vu[tid + j*512];
    if (tid < 320) vreg[15] = Vu[tid + 7680];

    for (int i = tid; i < 16*128; i += 512){
        int r = i >> 7, c = i & 127;
        ushort_t v = 0;
        if (r < 12) v = f2bf(q12[r*128 + c] * 0.17677669529663687f);
        qs[r*136 + c] = v;
    }
    for (int i = tid; i < 4352; i += 512) ((unsigned*)pbf)[i] = 0;
    __syncthreads();

    {
        int krow = k0 + w*16 + lr; if (krow > k0 + 124) krow = k0 + 124;
        const ushort_t* Krow = K + ((size_t)b*1000 + krow)*128 + hi8;
        #pragma unroll
        for (int h=0; h<4; ++h){
            short8 kf = *(const short8*)(Krow + h*32);
            short8 qf = *(const short8*)&qs[lr*136 + h*32 + hi8];
            f32x4 d = __builtin_amdgcn_mfma_f32_16x16x32_bf16(qf, kf, (f32x4){0,0,0,0}, 0, 0, 0);
            int qbase = (lane>>4)*4;
            #pragma unroll
            for (int r=0; r<4; ++r){
                int qq = qbase + r;
                if (qq < 12) s32[(h*12+qq)*130 + w*16 + lr] = d[r];
            }
        }
    }
    __syncthreads();

    if (tid < 192){
        int hq = tid >> 2, sub = tid & 3;
        int h = hq / 12, qq = hq - h*12;
        float m = -1e30f;
        for (int kk = sub; kk < CHUNK; kk += 4) m = fmaxf(m, s32[hq*130 + kk]);
        m = fmaxf(m, __shfl_xor(m, 1));
        m = fmaxf(m, __shfl_xor(m, 2));
        float l = 0.f;
        for (int kk = sub; kk < CHUNK; kk += 4){
            float e = __expf(s32[hq*130 + kk] - m);
            l += e;
            pbf[(h*16+qq)*136 + kk] = f2bf(e);
        }
        l += __shfl_xor(l, 1);
        l += __shfl_xor(l, 2);
        if (sub == 0) ml[hq] = make_float2(m, l);
    }
    __syncthreads();

    #pragma unroll
    for (int j=0;j<15;++j){
        int i = tid + j*512;
        int kk = i >> 6, dp = (i & 63)*2;
        unsigned u = vreg[j];
        vt[dp*136 + kk]     = (ushort_t)(u & 0xFFFF);
        vt[(dp+1)*136 + kk] = (ushort_t)(u >> 16);
    }
    if (tid < 320){
        int i = tid + 7680;
        int kk = i >> 6, dp = (i & 63)*2;
        unsigned u = vreg[15];
        vt[dp*136 + kk]     = (ushort_t)(u & 0xFFFF);
        vt[(dp+1)*136 + kk] = (ushort_t)(u >> 16);
    }
    if (tid < 384){
        int dp = tid / 3, kk = 125 + tid % 3;
        vt[dp*136 + kk] = 0;
    }
    __syncthreads();

    {
        int h = w >> 1;
        f32x4 acc = (f32x4){0,0,0,0};
        #pragma unroll
        for (int kc=0; kc<4; ++kc){
            short8 pf = *(const short8*)&pbf[(h*16+lr)*136 + kc*32 + hi8];
            short8 vf = *(const short8*)&vt[(w*16+lr)*136 + kc*32 + hi8];
            acc = __builtin_amdgcn_mfma_f32_16x16x32_bf16(pf, vf, acc, 0, 0, 0);
        }
        int qbase = (lane>>4)*4;
        float* ob = opart + ((size_t)(b*NSPLIT+sp)*12)*128;
        #pragma unroll
        for (int r=0; r<4; ++r){
            int qq = qbase + r;
            if (qq < 12) ob[(size_t)qq*128 + w*16 + lr] = acc[r];
        }
    }
    if (tid < 48) mlpart[(size_t)(b*NSPLIT+sp)*48 + tid] = ml[tid];
}

__global__ __launch_bounds__(256) void cross_attn_comb(const float* __restrict__ opart,
        const float* __restrict__ mlpart, ushort_t* __restrict__ attbf){
    int b = blockIdx.x, tid = threadIdx.x;
    __shared__ float mls[NSPLIT*48*2];
    for (int i = tid; i < NSPLIT*48*2; i += 256) mls[i] = mlpart[(size_t)b*NSPLIT*96 + i];
    __syncthreads();
    for (int p = tid; p < 1536; p += 256){
        int qq = p >> 7, dp = p & 127, h = dp >> 5, hq = h*12 + qq;
        float M = -1e30f;
        #pragma unroll
        for (int sp=0; sp<NSPLIT; ++sp) M = fmaxf(M, mls[sp*96 + hq*2]);
        float L = 0.f, O = 0.f;
        #pragma unroll
        for (int sp=0; sp<NSPLIT; ++sp){
            float wgt = __expf(mls[sp*96 + hq*2] - M);
            L += wgt * mls[sp*96 + hq*2 + 1];
            O += wgt * opart[((size_t)(b*NSPLIT+sp)*12 + qq)*128 + dp];
        }
        attbf[((size_t)b*12 + qq)*128 + dp] = f2bf(O / L);
    }
}

__global__ __launch_bounds__(256) void final_out(const float* __restrict__ t,
        const float* __restrict__ lw, const float* __restrict__ lb,
        const float* __restrict__ ow, const float* __restrict__ ob, float* __restrict__ out){
    int r = blockIdx.x*4 + (threadIdx.x>>6);
    int lane = threadIdx.x & 63;
    const float2* x2 = (const float2*)(t + (size_t)r*128);
    float2 v = x2[lane];
    float s = v.x+v.y;
    for (int o=32;o>0;o>>=1) s += __shfl_xor(s,o);
    float mean = s*(1.f/128.f);
    float dx=v.x-mean, dy=v.y-mean;
    float var = dx*dx+dy*dy;
    for (int o=32;o>0;o>>=1) var += __shfl_xor(var,o);
    float rs = rsqrtf(var*(1.f/128.f)+1e-5f);
    float2 w2=((const float2*)lw)[lane], b2=((const float2*)lb)[lane];
    float2 o2=((const float2*)ow)[lane];
    float d = (dx*rs*w2.x+b2.x)*o2.x + (dy*rs*w2.y+b2.y)*o2.y;
    for (int o=32;o>0;o>>=1) d += __shfl_xor(d,o);
    if (lane==0) out[r] = d + ob[0];
}

extern "C" void kernel_launch(void* const* d_in, const int* in_sizes, int n_in,
                              void* d_out, int out_size, void* d_ws, size_t ws_size,
                              hipStream_t stream){
    (void)in_sizes; (void)n_in; (void)out_size; (void)ws_size;
    const float* x        = (const float*)d_in[0];
    const int*   eidx     = (const int*)d_in[1];
    const float* in_w     = (const float*)d_in[3];
    const float* in_b     = (const float*)d_in[4];
    const float* gcn_w    = (const float*)d_in[5];
    const float* gcn_b    = (const float*)d_in[6];
    const float* ln_w     = (const float*)d_in[7];
    const float* ln_b     = (const float*)d_in[8];
    const float* cq       = (const float*)d_in[9];
    const float* sa_qkv_w = (const float*)d_in[10];
    const float* sa_qkv_b = (const float*)d_in[11];
    const float* sa_out_w = (const float*)d_in[12];
    const float* sa_out_b = (const float*)d_in[13];
    const float* ca_qkv_w = (const float*)d_in[14];
    const float* ca_qkv_b = (const float*)d_in[15];
    const float* ca_out_w = (const float*)d_in[16];
    const float* ca_out_b = (const float*)d_in[17];
    const float* n1w=(const float*)d_in[18]; const float* n1b=(const float*)d_in[19];
    const float* n2w=(const float*)d_in[20]; const float* n2b=(const float*)d_in[21];
    const float* n3w=(const float*)d_in[22]; const float* n3b=(const float*)d_in[23];
    const float* ff1w=(const float*)d_in[24]; const float* ff1b=(const float*)d_in[25];
    const float* ff2w=(const float*)d_in[26]; const float* ff2b=(const float*)d_in[27];
    const float* opln_w=(const float*)d_in[28]; const float* opln_b=(const float*)d_in[29];
    const float* opw=(const float*)d_in[30]; const float* opb=(const float*)d_in[31];
    float* out = (float*)d_out;

    char* base = (char*)d_ws;
    size_t off = 0;
    auto alloc = [&](size_t bytes)->void*{
        void* r = base + off; off += (bytes + 255) & ~(size_t)255; return r;
    };
    float*    h     = (float*)alloc((size_t)NNODES*DD*4);
    ushort_t* hbf   = (ushort_t*)alloc((size_t)NNODES*DD*2);
    ushort_t* kbf   = (ushort_t*)alloc((size_t)NNODES*DD*2);  // also hwbf during GCN loop
    ushort_t* vbf   = (ushort_t*)alloc((size_t)NNODES*DD*2);
    ushort_t* Wb    = (ushort_t*)alloc((size_t)5*DD*DD*2);
    ushort_t* Wpad  = (ushort_t*)alloc((size_t)DD*32*2);
    ushort_t* Wdec  = (ushort_t*)alloc((size_t)147456*2);
    float*    dinv  = (float*)alloc((size_t)NNODES*4);
    int*      cnt   = (int*)  alloc((size_t)NNODES*4);
    int*      offs  = (int*)  alloc((size_t)(NNODES+1)*4);
    int*      bsum  = (int*)  alloc(512*4);
    int2*     ee    = (int2*) alloc((size_t)NEDGES*8);
    float*    t12   = (float*)alloc((size_t)12*DD*4);
    float*    tn12  = (float*)alloc((size_t)12*DD*4);
    float*    sq12  = (float*)alloc((size_t)12*384*4);
    float*    att12 = (float*)alloc((size_t)12*DD*4);
    float*    q12   = (float*)alloc((size_t)12*DD*4);
    float*    tfull = (float*)alloc((size_t)NROWS*DD*4);
    ushort_t* tnbf  = (ushort_t*)alloc((size_t)NROWS*DD*2);
    ushort_t* attbf = (ushort_t*)alloc((size_t)NROWS*DD*2);
    ushort_t* ffhbf = (ushort_t*)alloc((size_t)NROWS*512*2);
    float*    opart = (float*)alloc((size_t)BB*NSPLIT*12*128*4);
    float2*   mlprt = (float2*)alloc((size_t)BB*NSPLIT*48*8);
    ushort_t* hwbf  = kbf;

    const int* erow = eidx;
    const int* ecol = eidx + NEDGES;

    // CSR build (once, reused by all 3 GCN layers)
    hipMemsetAsync(cnt, 0, (size_t)NNODES*4, stream);
    count_edges<<<NEDGES/256, 256, 0, stream>>>(ecol, cnt);
    compute_dinv<<<NNODES/256, 256, 0, stream>>>(cnt, dinv);
    scan_a<<<NNODES/256, 256, 0, stream>>>(cnt, offs, bsum);
    scan_b<<<1, 512, 0, stream>>>(bsum, NNODES/256);
    scan_c<<<NNODES/256, 256, 0, stream>>>(offs, bsum);
    hipMemsetAsync(cnt, 0, (size_t)NNODES*4, stream);
    fill_csr<<<NEDGES/256, 256, 0, stream>>>(erow, ecol, offs, cnt, dinv, ee);

    conv_w<<<5*DD*DD/256, 256, 0, stream>>>(gcn_w, ca_qkv_w, Wb);
    conv_wpad<<<DD*32/256, 256, 0, stream>>>(in_w, Wpad);
    conv_wdec<<<576, 256, 0, stream>>>(ca_out_w, ff1w, ff2w, Wdec);

    // node pipeline
    in_proj_mfma<<<NNODES/64, 256, 0, stream>>>(x, Wpad, in_b, h, hbf);
    for (int i=0;i<3;++i){
        gemm_mfma<<<NNODES/64, 256, 0, stream>>>(hbf, Wb + (size_t)i*DD*DD, nullptr, hwbf);
        gcn_agg<<<NNODES/4, 256, 0, stream>>>(h, hwbf, offs, ee, dinv,
                gcn_b + (size_t)i*DD, ln_w + (size_t)i*DD, ln_b + (size_t)i*DD, hbf, i==2);
    }
    // cross-attn K,V projections (bf16 out)
    gemm_mfma<<<NNODES/64, 256, 0, stream>>>(hbf, Wb + (size_t)3*DD*DD, ca_qkv_b + DD,   kbf);
    gemm_mfma<<<NNODES/64, 256, 0, stream>>>(hbf, Wb + (size_t)4*DD*DD, ca_qkv_b + 2*DD, vbf);

    // ---- decoder: batch-invariant 12-row prefix (fp32, exact) ----
    ln_rows<<<3, 256, 0, stream>>>(cq, tn12, n1w, n1b);
    small_gemm<<<18, 256, 0, stream>>>(tn12, sa_qkv_w, sa_qkv_b, sq12, 12, 128, 384, 0);
    self_attn12<<<4, 64, 0, stream>>>(sq12, att12);
    copy12<<<6, 256, 0, stream>>>(cq, t12);
    small_gemm<<<6, 256, 0, stream>>>(att12, sa_out_w, sa_out_b, t12, 12, 128, 128, 1);
    ln_rows<<<3, 256, 0, stream>>>(t12, tn12, n2w, n2b);
    small_gemm<<<6, 256, 0, stream>>>(tn12, ca_qkv_w, ca_qkv_b, q12, 12, 128, 128, 0);

    // ---- per-batch: cross-attention + FF (bf16 MFMA) ----
    cross_attn_part<<<BB*NSPLIT, 512, 0, stream>>>(q12, kbf, vbf, opart, mlprt);
    cross_attn_comb<<<BB, 256, 0, stream>>>(opart, (const float*)mlprt, attbf);
    bcast_t<<<NROWS*DD/256, 256, 0, stream>>>(t12, tfull);
    dim3 g24_1(24,1), g24_4(24,4);
    dec_gemm<<<g24_1, 256, 0, stream>>>(attbf, Wdec, ca_out_b, tfull, nullptr, 128, 128, 1|8);
    ln_rows_bf<<<NROWS/4, 256, 0, stream>>>(tfull, tnbf, n3w, n3b);
    dec_gemm<<<g24_4, 256, 0, stream>>>(tnbf, Wdec + 16384, ff1b, nullptr, ffhbf, 128, 512, 2|4);
    dec_gemm<<<g24_1, 256, 0, stream>>>(ffhbf, Wdec + 81920, ff2b, tfull, nullptr, 512, 128, 1|8);
    final_out<<<NROWS/4, 256, 0, stream>>>(tfull, opln_w, opln_b, opw, opb, out);
}

// Round 7
// 562.670 us; speedup vs baseline: 2.4834x; 1.0975x over previous
//
#include <hip/hip_runtime.h>

#define NNODES 128000
#define NEDGES 640000
#define BB 128
#define CC 12
#define DD 128
#define NROWS (BB*CC)   // 1536
#define NSPLIT 8
#define CHUNK 125

typedef __attribute__((ext_vector_type(8))) short short8;
typedef __attribute__((ext_vector_type(4))) float f32x4;
typedef unsigned short ushort_t;

__device__ __forceinline__ ushort_t f2bf(float f){
    union { float f; unsigned u; } v; v.f = f;
    unsigned r = (v.u + 0x7FFF + ((v.u >> 16) & 1)) >> 16;  // RNE
    return (ushort_t)r;
}
__device__ __forceinline__ float bfu_lo(unsigned u){
    union { unsigned u; float f; } v; v.u = u << 16; return v.f;
}
__device__ __forceinline__ float bfu_hi(unsigned u){
    union { unsigned u; float f; } v; v.u = u & 0xFFFF0000u; return v.f;
}

// ---------------- CSR build ----------------
__global__ __launch_bounds__(256) void count_edges(const int* __restrict__ col, int* __restrict__ cnt){
    int e = blockIdx.x*256 + threadIdx.x;
    if (e < NEDGES) atomicAdd(&cnt[col[e]], 1);
}

__global__ __launch_bounds__(256) void compute_dinv(const int* __restrict__ cnt, float* __restrict__ dinv){
    int i = blockIdx.x*256 + threadIdx.x;
    if (i < NNODES) dinv[i] = rsqrtf((float)cnt[i] + 1.0f);
}

__global__ __launch_bounds__(256) void scan_a(const int* __restrict__ cnt, int* __restrict__ offs, int* __restrict__ bsum){
    __shared__ int tmp[256];
    int tid = threadIdx.x;
    int g = blockIdx.x*256 + tid;
    int v = cnt[g];
    tmp[tid] = v;
    __syncthreads();
    for (int o=1;o<256;o<<=1){
        int a = (tid>=o)? tmp[tid-o] : 0;
        __syncthreads();
        tmp[tid] += a;
        __syncthreads();
    }
    offs[g] = tmp[tid] - v;
    if (tid==255) bsum[blockIdx.x] = tmp[255];
}

__global__ __launch_bounds__(512) void scan_b(int* __restrict__ bsum, int NB){
    __shared__ int tmp[512];
    int tid = threadIdx.x;
    int v = (tid<NB)? bsum[tid] : 0;
    tmp[tid] = v;
    __syncthreads();
    for (int o=1;o<512;o<<=1){
        int a = (tid>=o)? tmp[tid-o] : 0;
        __syncthreads();
        tmp[tid] += a;
        __syncthreads();
    }
    if (tid<NB) bsum[tid] = tmp[tid] - v;
}

__global__ __launch_bounds__(256) void scan_c(int* __restrict__ offs, const int* __restrict__ bsum){
    int g = blockIdx.x*256 + threadIdx.x;
    offs[g] += bsum[g>>8];
    if (g==0) offs[NNODES] = NEDGES;
}

__global__ __launch_bounds__(256) void fill_csr(const int* __restrict__ row, const int* __restrict__ col,
        const int* __restrict__ offs, int* __restrict__ cur, const float* __restrict__ dinv,
        int2* __restrict__ ee){
    int e = blockIdx.x*256 + threadIdx.x;
    if (e >= NEDGES) return;
    int c = col[e], r = row[e];
    int p = atomicAdd(&cur[c], 1);
    int idx = offs[c] + p;
    float w = dinv[r]*dinv[c];
    ee[idx] = make_int2(r, __float_as_int(w));
}

// ---------------- weight conversions ----------------
__global__ __launch_bounds__(256) void conv_w(const float* __restrict__ gcn_w,
        const float* __restrict__ ca_qkv_w, ushort_t* __restrict__ Wb){
    int i = blockIdx.x*256 + threadIdx.x;   // < 5*16384
    int slot = i >> 14, off = i & 16383;
    float v = (slot < 3) ? gcn_w[slot*16384 + off]
                         : ca_qkv_w[16384 + (slot-3)*16384 + off];
    Wb[i] = f2bf(v);
}

// in_w [128][16] -> bf16 padded [128][32] (zeros k>=16)
__global__ __launch_bounds__(256) void conv_wpad(const float* __restrict__ in_w, ushort_t* __restrict__ Wpad){
    int i = blockIdx.x*256 + threadIdx.x;   // < 4096
    int n = i >> 5, k = i & 31;
    Wpad[i] = (k < 16) ? f2bf(in_w[n*16 + k]) : (ushort_t)0;
}

// decoder weights: ca_out (128x128) | ff1 (512x128) | ff2 (128x512)
__global__ __launch_bounds__(256) void conv_wdec(const float* __restrict__ caout,
        const float* __restrict__ ff1, const float* __restrict__ ff2, ushort_t* __restrict__ Wd){
    int i = blockIdx.x*256 + threadIdx.x;   // < 147456
    float v;
    if (i < 16384) v = caout[i];
    else if (i < 81920) v = ff1[i - 16384];
    else v = ff2[i - 81920];
    Wd[i] = f2bf(v);
}

// ---------------- input projection via MFMA (bf16 out only) ----------------
__global__ __launch_bounds__(256) void in_proj_mfma(const float* __restrict__ x,
        const ushort_t* __restrict__ Wpad, const float* __restrict__ bias,
        ushort_t* __restrict__ hbf){
    __shared__ __align__(16) ushort_t xs[64*32];
    int tid = threadIdx.x;
    int m0 = blockIdx.x*64;
    if (tid < 128){
        short8 z = {0,0,0,0,0,0,0,0};
        *(short8*)&xs[(tid>>1)*32 + 16 + (tid&1)*8] = z;
    }
    float4 xv = *(const float4*)(x + (size_t)m0*16 + tid*4);
    uint2 pk2;
    pk2.x = (unsigned)f2bf(xv.x) | ((unsigned)f2bf(xv.y) << 16);
    pk2.y = (unsigned)f2bf(xv.z) | ((unsigned)f2bf(xv.w) << 16);
    *(uint2*)&xs[(tid>>2)*32 + (tid&3)*4] = pk2;
    __syncthreads();
    int lane = tid & 63, w = tid >> 6;
    int lr = lane & 15, lk = (lane>>4)*8;
    short8 bfrag[8];
    #pragma unroll
    for (int nt=0; nt<8; ++nt)
        bfrag[nt] = *(const short8*)&Wpad[(nt*16 + lr)*32 + lk];
    short8 a = *(const short8*)&xs[(w*16 + lr)*32 + lk];
    f32x4 acc[8];
    #pragma unroll
    for (int nt=0; nt<8; ++nt)
        acc[nt] = __builtin_amdgcn_mfma_f32_16x16x32_bf16(a, bfrag[nt], (f32x4){0,0,0,0}, 0, 0, 0);
    size_t orow = (size_t)m0 + w*16 + (lane>>4)*4;
    #pragma unroll
    for (int nt=0; nt<8; ++nt){
        int col = nt*16 + lr;
        float bv = bias[col];
        #pragma unroll
        for (int r=0; r<4; ++r)
            hbf[(orow + r)*128 + col] = f2bf(acc[nt][r] + bv);
    }
}

// ---------------- MFMA GEMM (node pipeline, K=N=128, bf16 out): 32 rows/wave ----------------
__global__ __launch_bounds__(256) void gemm_mfma(const ushort_t* __restrict__ A,
        const ushort_t* __restrict__ Wb, const float* __restrict__ bias, ushort_t* __restrict__ out){
    int lane = threadIdx.x & 63, wave = threadIdx.x >> 6;
    int m0 = blockIdx.x*128 + wave*32;
    int lr = lane & 15;
    int lk = (lane >> 4) * 8;
    short8 bfrag[4][8];
    #pragma unroll
    for (int nt=0; nt<8; ++nt)
        #pragma unroll
        for (int kc=0; kc<4; ++kc)
            bfrag[kc][nt] = *(const short8*)&Wb[(nt*16 + lr)*128 + kc*32 + lk];
    f32x4 acc[2][8];
    #pragma unroll
    for (int t=0; t<2; ++t)
        #pragma unroll
        for (int nt=0; nt<8; ++nt) acc[t][nt] = (f32x4){0.f,0.f,0.f,0.f};
    const ushort_t* arow0 = A + (size_t)(m0 + lr)*128 + lk;
    const ushort_t* arow1 = arow0 + 16*128;
    #pragma unroll
    for (int kc=0; kc<4; ++kc){
        short8 a0 = *(const short8*)(arow0 + kc*32);
        short8 a1 = *(const short8*)(arow1 + kc*32);
        #pragma unroll
        for (int nt=0; nt<8; ++nt){
            acc[0][nt] = __builtin_amdgcn_mfma_f32_16x16x32_bf16(a0, bfrag[kc][nt], acc[0][nt], 0, 0, 0);
            acc[1][nt] = __builtin_amdgcn_mfma_f32_16x16x32_bf16(a1, bfrag[kc][nt], acc[1][nt], 0, 0, 0);
        }
    }
    #pragma unroll
    for (int t=0; t<2; ++t){
        size_t orow = (size_t)m0 + t*16 + (lane>>4)*4;
        #pragma unroll
        for (int nt=0; nt<8; ++nt){
            int col = nt*16 + lr;
            float bv = bias ? bias[col] : 0.f;
            #pragma unroll
            for (int r=0; r<4; ++r)
                out[(orow + r)*128 + col] = f2bf(acc[t][nt][r] + bv);
        }
    }
}

// ---------------- GCN aggregate: wide gather + LN, bf16 residual in-place on hbf ----------
__global__ __launch_bounds__(256) void gcn_agg(ushort_t* __restrict__ hbf, const ushort_t* __restrict__ hwbf,
        const int* __restrict__ offs, const int2* __restrict__ ee,
        const float* __restrict__ dinv, const float* __restrict__ bias,
        const float* __restrict__ lnw, const float* __restrict__ lnb, int last){
    int node = blockIdx.x*4 + (threadIdx.x>>6);
    int lane = threadIdx.x & 63;
    int g = lane >> 4, l = lane & 15;
    const uint4* hw4 = (const uint4*)hwbf;
    uint4* hb4 = (uint4*)hbf;
    float p[8];
    {
        uint4 sv = hw4[(size_t)node*16 + l];
        float di = dinv[node];
        float sw = di*di*((g==0)?1.f:0.f);
        p[0]=sw*bfu_lo(sv.x); p[1]=sw*bfu_hi(sv.x);
        p[2]=sw*bfu_lo(sv.y); p[3]=sw*bfu_hi(sv.y);
        p[4]=sw*bfu_lo(sv.z); p[5]=sw*bfu_hi(sv.z);
        p[6]=sw*bfu_lo(sv.w); p[7]=sw*bfu_hi(sv.w);
    }
    uint4 rv = make_uint4(0,0,0,0);
    if (!last) rv = hb4[(size_t)node*16 + l];   // bf16 residual (issued early)
    int e0 = offs[node], e1 = offs[node+1];
    int nit = (e1 - e0 + 3) >> 2;
    for (int it = 0; it < nit; ++it){
        int e = e0 + it*4 + g;
        int2 pr = (e < e1) ? ee[e] : make_int2(node, 0);
        float w = __int_as_float(pr.y);
        uint4 v = hw4[(size_t)pr.x*16 + l];
        p[0] += w*bfu_lo(v.x); p[1] += w*bfu_hi(v.x);
        p[2] += w*bfu_lo(v.y); p[3] += w*bfu_hi(v.y);
        p[4] += w*bfu_lo(v.z); p[5] += w*bfu_hi(v.z);
        p[6] += w*bfu_lo(v.w); p[7] += w*bfu_hi(v.w);
    }
    #pragma unroll
    for (int j=0;j<8;++j){
        p[j] += __shfl_xor(p[j], 16);
        p[j] += __shfl_xor(p[j], 32);
    }
    {
        const float4* b4 = (const float4*)bias;
        float4 b0 = b4[l*2], b1 = b4[l*2+1];
        p[0]+=b0.x; p[1]+=b0.y; p[2]+=b0.z; p[3]+=b0.w;
        p[4]+=b1.x; p[5]+=b1.y; p[6]+=b1.z; p[7]+=b1.w;
    }
    float s = ((p[0]+p[1])+(p[2]+p[3]))+((p[4]+p[5])+(p[6]+p[7]));
    s += __shfl_xor(s,1); s += __shfl_xor(s,2); s += __shfl_xor(s,4); s += __shfl_xor(s,8);
    float mean = s*(1.f/128.f);
    float var = 0.f;
    #pragma unroll
    for (int j=0;j<8;++j){ p[j] -= mean; var += p[j]*p[j]; }
    var += __shfl_xor(var,1); var += __shfl_xor(var,2); var += __shfl_xor(var,4); var += __shfl_xor(var,8);
    float rs = rsqrtf(var*(1.f/128.f) + 1e-5f);
    float4 w0 = ((const float4*)lnw)[l*2], w1 = ((const float4*)lnw)[l*2+1];
    float4 lb0 = ((const float4*)lnb)[l*2], lb1 = ((const float4*)lnb)[l*2+1];
    float y[8];
    y[0]=p[0]*rs*w0.x+lb0.x; y[1]=p[1]*rs*w0.y+lb0.y; y[2]=p[2]*rs*w0.z+lb0.z; y[3]=p[3]*rs*w0.w+lb0.w;
    y[4]=p[4]*rs*w1.x+lb1.x; y[5]=p[5]*rs*w1.y+lb1.y; y[6]=p[6]*rs*w1.z+lb1.z; y[7]=p[7]*rs*w1.w+lb1.w;
    if (!last){
        y[0]=fmaxf(y[0],0.f)+bfu_lo(rv.x); y[1]=fmaxf(y[1],0.f)+bfu_hi(rv.x);
        y[2]=fmaxf(y[2],0.f)+bfu_lo(rv.y); y[3]=fmaxf(y[3],0.f)+bfu_hi(rv.y);
        y[4]=fmaxf(y[4],0.f)+bfu_lo(rv.z); y[5]=fmaxf(y[5],0.f)+bfu_hi(rv.z);
        y[6]=fmaxf(y[6],0.f)+bfu_lo(rv.w); y[7]=fmaxf(y[7],0.f)+bfu_hi(rv.w);
    }
    if (g==0){
        uint4 pk;
        pk.x = (unsigned)f2bf(y[0]) | ((unsigned)f2bf(y[1])<<16);
        pk.y = (unsigned)f2bf(y[2]) | ((unsigned)f2bf(y[3])<<16);
        pk.z = (unsigned)f2bf(y[4]) | ((unsigned)f2bf(y[5])<<16);
        pk.w = (unsigned)f2bf(y[6]) | ((unsigned)f2bf(y[7])<<16);
        hb4[(size_t)node*16 + l] = pk;
    }
}

// ---------------- decoder MFMA GEMM: flexible K (mult of 128), NO via grid.y ----------------
// flags: 1=accumulate into out(fp32), 2=relu, 4=write outbf, 8=write out fp32
__global__ __launch_bounds__(256) void dec_gemm(const ushort_t* __restrict__ A,
        const ushort_t* __restrict__ Wb, const float* __restrict__ bias,
        float* __restrict__ out, ushort_t* __restrict__ outbf,
        int K, int NO, int flags){
    int lane = threadIdx.x & 63, wave = threadIdx.x >> 6;
    int m0 = blockIdx.x*64 + wave*16;
    int n0 = blockIdx.y*128;
    int lr = lane & 15, lk = (lane>>4)*8;
    f32x4 acc[8];
    #pragma unroll
    for (int nt=0; nt<8; ++nt) acc[nt] = (f32x4){0.f,0.f,0.f,0.f};
    for (int ko = 0; ko < K; ko += 128){
        short8 bfrag[4][8];
        #pragma unroll
        for (int nt=0; nt<8; ++nt)
            #pragma unroll
            for (int kc=0; kc<4; ++kc)
                bfrag[kc][nt] = *(const short8*)&Wb[(size_t)(n0 + nt*16 + lr)*K + ko + kc*32 + lk];
        const ushort_t* arow = A + (size_t)(m0 + lr)*K + ko + lk;
        #pragma unroll
        for (int kc=0; kc<4; ++kc){
            short8 a = *(const short8*)(arow + kc*32);
            #pragma unroll
            for (int nt=0; nt<8; ++nt)
                acc[nt] = __builtin_amdgcn_mfma_f32_16x16x32_bf16(a, bfrag[kc][nt], acc[nt], 0, 0, 0);
        }
    }
    int orow0 = m0 + (lane>>4)*4;
    #pragma unroll
    for (int nt=0; nt<8; ++nt){
        int col = n0 + nt*16 + lr;
        float bv = bias[col];
        #pragma unroll
        for (int r=0; r<4; ++r){
            size_t idx = (size_t)(orow0 + r)*NO + col;
            float val = acc[nt][r] + bv;
            if (flags & 2) val = fmaxf(val, 0.f);
            if (flags & 1) val += out[idx];
            if (flags & 8) out[idx] = val;
            if (flags & 4) outbf[idx] = f2bf(val);
        }
    }
}

// ---------------- decoder small ops ----------------
__global__ __launch_bounds__(256) void ln_rows(const float* __restrict__ x, float* __restrict__ y,
        const float* __restrict__ w, const float* __restrict__ b){
    int r = blockIdx.x*4 + (threadIdx.x>>6);
    int lane = threadIdx.x & 63;
    const float2* x2 = (const float2*)(x + (size_t)r*128);
    float2 v = x2[lane];
    float s = v.x+v.y;
    for (int o=32;o>0;o>>=1) s += __shfl_xor(s,o);
    float mean = s*(1.f/128.f);
    float dx=v.x-mean, dy=v.y-mean;
    float var = dx*dx+dy*dy;
    for (int o=32;o>0;o>>=1) var += __shfl_xor(var,o);
    float rs = rsqrtf(var*(1.f/128.f) + 1e-5f);
    float2 w2=((const float2*)w)[lane], b2=((const float2*)b)[lane];
    ((float2*)(y + (size_t)r*128))[lane] = make_float2(dx*rs*w2.x+b2.x, dy*rs*w2.y+b2.y);
}

__global__ __launch_bounds__(256) void ln_rows_bf(const float* __restrict__ x, ushort_t* __restrict__ y,
        const float* __restrict__ w, const float* __restrict__ b){
    int r = blockIdx.x*4 + (threadIdx.x>>6);
    int lane = threadIdx.x & 63;
    const float2* x2 = (const float2*)(x + (size_t)r*128);
    float2 v = x2[lane];
    float s = v.x+v.y;
    for (int o=32;o>0;o>>=1) s += __shfl_xor(s,o);
    float mean = s*(1.f/128.f);
    float dx=v.x-mean, dy=v.y-mean;
    float var = dx*dx+dy*dy;
    for (int o=32;o>0;o>>=1) var += __shfl_xor(var,o);
    float rs = rsqrtf(var*(1.f/128.f) + 1e-5f);
    float2 w2=((const float2*)w)[lane], b2=((const float2*)b)[lane];
    float yx = dx*rs*w2.x+b2.x, yy = dy*rs*w2.y+b2.y;
    ((unsigned*)y)[(size_t)r*64 + lane] = (unsigned)f2bf(yx) | ((unsigned)f2bf(yy)<<16);
}

// naive fp32 gemm for 12-row prefix. flags: 1=acc, 2=relu
__global__ __launch_bounds__(256) void small_gemm(const float* __restrict__ x, const float* __restrict__ W,
        const float* __restrict__ bias, float* __restrict__ out, int R, int K, int NO, int flags){
    int idx = blockIdx.x*256 + threadIdx.x;
    if (idx >= R*NO) return;
    int r = idx / NO, n = idx - r*NO;
    const float4* xr = (const float4*)(x + (size_t)r*K);
    const float4* wr = (const float4*)(W + (size_t)n*K);
    float a = bias ? bias[n] : 0.0f;
    int K4 = K>>2;
    for (int k=0;k<K4;++k){
        float4 xv = xr[k], wv = wr[k];
        a += xv.x*wv.x + xv.y*wv.y + xv.z*wv.z + xv.w*wv.w;
    }
    if (flags & 2) a = fmaxf(a, 0.f);
    if (flags & 1) a += out[idx];
    out[idx] = a;
}

__global__ __launch_bounds__(256) void copy12(const float* __restrict__ cq, float* __restrict__ t12){
    int i = blockIdx.x*256 + threadIdx.x;   // < 1536
    t12[i] = cq[i];
}

__global__ __launch_bounds__(256) void bcast_t(const float* __restrict__ t12, float* __restrict__ t_full){
    int idx = blockIdx.x*256 + threadIdx.x;  // < 1536*128
    int r = idx >> 7;
    t_full[idx] = t12[(r % 12)*128 + (idx & 127)];
}

__global__ __launch_bounds__(64) void self_attn12(const float* __restrict__ qkv, float* __restrict__ out){
    int hh = blockIdx.x;
    int lane = threadIdx.x;
    __shared__ float q[12][32], k[12][32], v[12][32], sc[12][12];
    for (int idx = lane; idx < 12*32; idx += 64){
        int c = idx>>5, d = idx&31;
        size_t base = (size_t)c*384 + hh*32 + d;
        q[c][d] = qkv[base] * 0.17677669529663687f;
        k[c][d] = qkv[base+128];
        v[c][d] = qkv[base+256];
    }
    __syncthreads();
    for (int p = lane; p < 144; p += 64){
        int qi = p/12, ki = p%12;
        float a = 0;
        #pragma unroll
        for (int d=0; d<32; ++d) a += q[qi][d]*k[ki][d];
        sc[qi][ki] = a;
    }
    __syncthreads();
    if (lane < 12){
        float m = -1e30f;
        for (int j=0;j<12;++j) m = fmaxf(m, sc[lane][j]);
        float sum=0;
        for (int j=0;j<12;++j){ float e=__expf(sc[lane][j]-m); sc[lane][j]=e; sum+=e; }
        float inv=1.f/sum;
        for (int j=0;j<12;++j) sc[lane][j]*=inv;
    }
    __syncthreads();
    for (int p = lane; p < 384; p += 64){
        int c = p>>5, d = p&31;
        float a=0;
        #pragma unroll
        for (int j=0;j<12;++j) a += sc[c][j]*v[j][d];
        out[(size_t)c*128 + hh*32 + d] = a;
    }
}

// ---------------- flash cross-attention, k-split, MFMA; shared q12 ----------------
__global__ __launch_bounds__(512) void cross_attn_part(const float* __restrict__ q12,
        const ushort_t* __restrict__ K, const ushort_t* __restrict__ V,
        float* __restrict__ opart, float2* __restrict__ mlpart){
    __shared__ __align__(16) ushort_t qs[16*136];
    __shared__ __align__(16) unsigned char uni[128*136*2];
    __shared__ __align__(16) ushort_t pbf[4*16*136];
    __shared__ float2 ml[48];
    float* s32 = (float*)uni;
    ushort_t* vt = (ushort_t*)uni;

    int tid = threadIdx.x;
    int b = blockIdx.x / NSPLIT, sp = blockIdx.x % NSPLIT;
    int k0 = sp * CHUNK;
    int lane = tid & 63, w = tid >> 6;
    int lr = lane & 15, hi8 = (lane >> 4) * 8;

    const unsigned* Vu = (const unsigned*)V + ((size_t)b*1000 + k0)*64;
    unsigned vreg[16];
    #pragma unroll
    for (int j=0;j<15;++j) vreg[j] = Vu[tid + j*512];
    if (tid < 320) vreg[15] = Vu[tid + 7680];

    for (int i = tid; i < 16*128; i += 512){
        int r = i >> 7, c = i & 127;
        ushort_t v = 0;
        if (r < 12) v = f2bf(q12[r*128 + c] * 0.17677669529663687f);
        qs[r*136 + c] = v;
    }
    for (int i = tid; i < 4352; i += 512) ((unsigned*)pbf)[i] = 0;
    __syncthreads();

    {
        int krow = k0 + w*16 + lr; if (krow > k0 + 124) krow = k0 + 124;
        const ushort_t* Krow = K + ((size_t)b*1000 + krow)*128 + hi8;
        #pragma unroll
        for (int h=0; h<4; ++h){
            short8 kf = *(const short8*)(Krow + h*32);
            short8 qf = *(const short8*)&qs[lr*136 + h*32 + hi8];
            f32x4 d = __builtin_amdgcn_mfma_f32_16x16x32_bf16(qf, kf, (f32x4){0,0,0,0}, 0, 0, 0);
            int qbase = (lane>>4)*4;
            #pragma unroll
            for (int r=0; r<4; ++r){
                int qq = qbase + r;
                if (qq < 12) s32[(h*12+qq)*130 + w*16 + lr] = d[r];
            }
        }
    }
    __syncthreads();

    if (tid < 192){
        int hq = tid >> 2, sub = tid & 3;
        int h = hq / 12, qq = hq - h*12;
        float m = -1e30f;
        for (int kk = sub; kk < CHUNK; kk += 4) m = fmaxf(m, s32[hq*130 + kk]);
        m = fmaxf(m, __shfl_xor(m, 1));
        m = fmaxf(m, __shfl_xor(m, 2));
        float l = 0.f;
        for (int kk = sub; kk < CHUNK; kk += 4){
            float e = __expf(s32[hq*130 + kk] - m);
            l += e;
            pbf[(h*16+qq)*136 + kk] = f2bf(e);
        }
        l += __shfl_xor(l, 1);
        l += __shfl_xor(l, 2);
        if (sub == 0) ml[hq] = make_float2(m, l);
    }
    __syncthreads();

    #pragma unroll
    for (int j=0;j<15;++j){
        int i = tid + j*512;
        int kk = i >> 6, dp = (i & 63)*2;
        unsigned u = vreg[j];
        vt[dp*136 + kk]     = (ushort_t)(u & 0xFFFF);
        vt[(dp+1)*136 + kk] = (ushort_t)(u >> 16);
    }
    if (tid < 320){
        int i = tid + 7680;
        int kk = i >> 6, dp = (i & 63)*2;
        unsigned u = vreg[15];
        vt[dp*136 + kk]     = (ushort_t)(u & 0xFFFF);
        vt[(dp+1)*136 + kk] = (ushort_t)(u >> 16);
    }
    if (tid < 384){
        int dp = tid / 3, kk = 125 + tid % 3;
        vt[dp*136 + kk] = 0;
    }
    __syncthreads();

    {
        int h = w >> 1;
        f32x4 acc = (f32x4){0,0,0,0};
        #pragma unroll
        for (int kc=0; kc<4; ++kc){
            short8 pf = *(const short8*)&pbf[(h*16+lr)*136 + kc*32 + hi8];
            short8 vf = *(const short8*)&vt[(w*16+lr)*136 + kc*32 + hi8];
            acc = __builtin_amdgcn_mfma_f32_16x16x32_bf16(pf, vf, acc, 0, 0, 0);
        }
        int qbase = (lane>>4)*4;
        float* ob = opart + ((size_t)(b*NSPLIT+sp)*12)*128;
        #pragma unroll
        for (int r=0; r<4; ++r){
            int qq = qbase + r;
            if (qq < 12) ob[(size_t)qq*128 + w*16 + lr] = acc[r];
        }
    }
    if (tid < 48) mlpart[(size_t)(b*NSPLIT+sp)*48 + tid] = ml[tid];
}

__global__ __launch_bounds__(256) void cross_attn_comb(const float* __restrict__ opart,
        const float* __restrict__ mlpart, ushort_t* __restrict__ attbf){
    int b = blockIdx.x, tid = threadIdx.x;
    __shared__ float mls[NSPLIT*48*2];
    for (int i = tid; i < NSPLIT*48*2; i += 256) mls[i] = mlpart[(size_t)b*NSPLIT*96 + i];
    __syncthreads();
    for (int p = tid; p < 1536; p += 256){
        int qq = p >> 7, dp = p & 127, h = dp >> 5, hq = h*12 + qq;
        float M = -1e30f;
        #pragma unroll
        for (int sp=0; sp<NSPLIT; ++sp) M = fmaxf(M, mls[sp*96 + hq*2]);
        float L = 0.f, O = 0.f;
        #pragma unroll
        for (int sp=0; sp<NSPLIT; ++sp){
            float wgt = __expf(mls[sp*96 + hq*2] - M);
            L += wgt * mls[sp*96 + hq*2 + 1];
            O += wgt * opart[((size_t)(b*NSPLIT+sp)*12 + qq)*128 + dp];
        }
        attbf[((size_t)b*12 + qq)*128 + dp] = f2bf(O / L);
    }
}

__global__ __launch_bounds__(256) void final_out(const float* __restrict__ t,
        const float* __restrict__ lw, const float* __restrict__ lb,
        const float* __restrict__ ow, const float* __restrict__ ob, float* __restrict__ out){
    int r = blockIdx.x*4 + (threadIdx.x>>6);
    int lane = threadIdx.x & 63;
    const float2* x2 = (const float2*)(t + (size_t)r*128);
    float2 v = x2[lane];
    float s = v.x+v.y;
    for (int o=32;o>0;o>>=1) s += __shfl_xor(s,o);
    float mean = s*(1.f/128.f);
    float dx=v.x-mean, dy=v.y-mean;
    float var = dx*dx+dy*dy;
    for (int o=32;o>0;o>>=1) var += __shfl_xor(var,o);
    float rs = rsqrtf(var*(1.f/128.f)+1e-5f);
    float2 w2=((const float2*)lw)[lane], b2=((const float2*)lb)[lane];
    float2 o2=((const float2*)ow)[lane];
    float d = (dx*rs*w2.x+b2.x)*o2.x + (dy*rs*w2.y+b2.y)*o2.y;
    for (int o=32;o>0;o>>=1) d += __shfl_xor(d,o);
    if (lane==0) out[r] = d + ob[0];
}

extern "C" void kernel_launch(void* const* d_in, const int* in_sizes, int n_in,
                              void* d_out, int out_size, void* d_ws, size_t ws_size,
                              hipStream_t stream){
    (void)in_sizes; (void)n_in; (void)out_size; (void)ws_size;
    const float* x        = (const float*)d_in[0];
    const int*   eidx     = (const int*)d_in[1];
    const float* in_w     = (const float*)d_in[3];
    const float* in_b     = (const float*)d_in[4];
    const float* gcn_w    = (const float*)d_in[5];
    const float* gcn_b    = (const float*)d_in[6];
    const float* ln_w     = (const float*)d_in[7];
    const float* ln_b     = (const float*)d_in[8];
    const float* cq       = (const float*)d_in[9];
    const float* sa_qkv_w = (const float*)d_in[10];
    const float* sa_qkv_b = (const float*)d_in[11];
    const float* sa_out_w = (const float*)d_in[12];
    const float* sa_out_b = (const float*)d_in[13];
    const float* ca_qkv_w = (const float*)d_in[14];
    const float* ca_qkv_b = (const float*)d_in[15];
    const float* ca_out_w = (const float*)d_in[16];
    const float* ca_out_b = (const float*)d_in[17];
    const float* n1w=(const float*)d_in[18]; const float* n1b=(const float*)d_in[19];
    const float* n2w=(const float*)d_in[20]; const float* n2b=(const float*)d_in[21];
    const float* n3w=(const float*)d_in[22]; const float* n3b=(const float*)d_in[23];
    const float* ff1w=(const float*)d_in[24]; const float* ff1b=(const float*)d_in[25];
    const float* ff2w=(const float*)d_in[26]; const float* ff2b=(const float*)d_in[27];
    const float* opln_w=(const float*)d_in[28]; const float* opln_b=(const float*)d_in[29];
    const float* opw=(const float*)d_in[30]; const float* opb=(const float*)d_in[31];
    float* out = (float*)d_out;

    char* base = (char*)d_ws;
    size_t off = 0;
    auto alloc = [&](size_t bytes)->void*{
        void* r = base + off; off += (bytes + 255) & ~(size_t)255; return r;
    };
    ushort_t* hbf   = (ushort_t*)alloc((size_t)NNODES*DD*2);
    ushort_t* kbf   = (ushort_t*)alloc((size_t)NNODES*DD*2);  // also hwbf during GCN loop
    ushort_t* vbf   = (ushort_t*)alloc((size_t)NNODES*DD*2);
    ushort_t* Wb    = (ushort_t*)alloc((size_t)5*DD*DD*2);
    ushort_t* Wpad  = (ushort_t*)alloc((size_t)DD*32*2);
    ushort_t* Wdec  = (ushort_t*)alloc((size_t)147456*2);
    float*    dinv  = (float*)alloc((size_t)NNODES*4);
    int*      cnt   = (int*)  alloc((size_t)NNODES*4);
    int*      offs  = (int*)  alloc((size_t)(NNODES+1)*4);
    int*      bsum  = (int*)  alloc(512*4);
    int2*     ee    = (int2*) alloc((size_t)NEDGES*8);
    float*    t12   = (float*)alloc((size_t)12*DD*4);
    float*    tn12  = (float*)alloc((size_t)12*DD*4);
    float*    sq12  = (float*)alloc((size_t)12*384*4);
    float*    att12 = (float*)alloc((size_t)12*DD*4);
    float*    q12   = (float*)alloc((size_t)12*DD*4);
    float*    tfull = (float*)alloc((size_t)NROWS*DD*4);
    ushort_t* tnbf  = (ushort_t*)alloc((size_t)NROWS*DD*2);
    ushort_t* attbf = (ushort_t*)alloc((size_t)NROWS*DD*2);
    ushort_t* ffhbf = (ushort_t*)alloc((size_t)NROWS*512*2);
    float*    opart = (float*)alloc((size_t)BB*NSPLIT*12*128*4);
    float2*   mlprt = (float2*)alloc((size_t)BB*NSPLIT*48*8);
    ushort_t* hwbf  = kbf;

    const int* erow = eidx;
    const int* ecol = eidx + NEDGES;

    // CSR build (once, reused by all 3 GCN layers)
    hipMemsetAsync(cnt, 0, (size_t)NNODES*4, stream);
    count_edges<<<NEDGES/256, 256, 0, stream>>>(ecol, cnt);
    compute_dinv<<<NNODES/256, 256, 0, stream>>>(cnt, dinv);
    scan_a<<<NNODES/256, 256, 0, stream>>>(cnt, offs, bsum);
    scan_b<<<1, 512, 0, stream>>>(bsum, NNODES/256);
    scan_c<<<NNODES/256, 256, 0, stream>>>(offs, bsum);
    hipMemsetAsync(cnt, 0, (size_t)NNODES*4, stream);
    fill_csr<<<NEDGES/256, 256, 0, stream>>>(erow, ecol, offs, cnt, dinv, ee);

    conv_w<<<5*DD*DD/256, 256, 0, stream>>>(gcn_w, ca_qkv_w, Wb);
    conv_wpad<<<DD*32/256, 256, 0, stream>>>(in_w, Wpad);
    conv_wdec<<<576, 256, 0, stream>>>(ca_out_w, ff1w, ff2w, Wdec);

    // node pipeline (residual lives in hbf as bf16)
    in_proj_mfma<<<NNODES/64, 256, 0, stream>>>(x, Wpad, in_b, hbf);
    for (int i=0;i<3;++i){
        gemm_mfma<<<NNODES/128, 256, 0, stream>>>(hbf, Wb + (size_t)i*DD*DD, nullptr, hwbf);
        gcn_agg<<<NNODES/4, 256, 0, stream>>>(hbf, hwbf, offs, ee, dinv,
                gcn_b + (size_t)i*DD, ln_w + (size_t)i*DD, ln_b + (size_t)i*DD, i==2);
    }
    // cross-attn K,V projections (bf16 out)
    gemm_mfma<<<NNODES/128, 256, 0, stream>>>(hbf, Wb + (size_t)3*DD*DD, ca_qkv_b + DD,   kbf);
    gemm_mfma<<<NNODES/128, 256, 0, stream>>>(hbf, Wb + (size_t)4*DD*DD, ca_qkv_b + 2*DD, vbf);

    // ---- decoder: batch-invariant 12-row prefix (fp32, exact) ----
    ln_rows<<<3, 256, 0, stream>>>(cq, tn12, n1w, n1b);
    small_gemm<<<18, 256, 0, stream>>>(tn12, sa_qkv_w, sa_qkv_b, sq12, 12, 128, 384, 0);
    self_attn12<<<4, 64, 0, stream>>>(sq12, att12);
    copy12<<<6, 256, 0, stream>>>(cq, t12);
    small_gemm<<<6, 256, 0, stream>>>(att12, sa_out_w, sa_out_b, t12, 12, 128, 128, 1);
    ln_rows<<<3, 256, 0, stream>>>(t12, tn12, n2w, n2b);
    small_gemm<<<6, 256, 0, stream>>>(tn12, ca_qkv_w, ca_qkv_b, q12, 12, 128, 128, 0);

    // ---- per-batch: cross-attention + FF (bf16 MFMA) ----
    cross_attn_part<<<BB*NSPLIT, 512, 0, stream>>>(q12, kbf, vbf, opart, mlprt);
    cross_attn_comb<<<BB, 256, 0, stream>>>(opart, (const float*)mlprt, attbf);
    bcast_t<<<NROWS*DD/256, 256, 0, stream>>>(t12, tfull);
    dim3 g24_1(24,1), g24_4(24,4);
    dec_gemm<<<g24_1, 256, 0, stream>>>(attbf, Wdec, ca_out_b, tfull, nullptr, 128, 128, 1|8);
    ln_rows_bf<<<NROWS/4, 256, 0, stream>>>(tfull, tnbf, n3w, n3b);
    dec_gemm<<<g24_4, 256, 0, stream>>>(tnbf, Wdec + 16384, ff1b, nullptr, ffhbf, 128, 512, 2|4);
    dec_gemm<<<g24_1, 256, 0, stream>>>(ffhbf, Wdec + 81920, ff2b, tfull, nullptr, 512, 128, 1|8);
    final_out<<<NROWS/4, 256, 0, stream>>>(tfull, opln_w, opln_b, opw, opb, out);
}

// Round 8
// 502.390 us; speedup vs baseline: 2.7813x; 1.1200x over previous
//
#include <hip/hip_runtime.h>

#define NNODES 128000
#define NEDGES 640000
#define BB 128
#define CC 12
#define DD 128
#define NROWS (BB*CC)   // 1536
#define NSPLIT 8
#define CHUNK 125

typedef __attribute__((ext_vector_type(8))) short short8;
typedef __attribute__((ext_vector_type(4))) float f32x4;
typedef unsigned short ushort_t;

__device__ __forceinline__ ushort_t f2bf(float f){
    union { float f; unsigned u; } v; v.f = f;
    unsigned r = (v.u + 0x7FFF + ((v.u >> 16) & 1)) >> 16;  // RNE
    return (ushort_t)r;
}
__device__ __forceinline__ float bfu_lo(unsigned u){
    union { unsigned u; float f; } v; v.u = u << 16; return v.f;
}
__device__ __forceinline__ float bfu_hi(unsigned u){
    union { unsigned u; float f; } v; v.u = u & 0xFFFF0000u; return v.f;
}

// ---------------- CSR build ----------------
__global__ __launch_bounds__(256) void count_edges(const int* __restrict__ col, int* __restrict__ cnt){
    int e = blockIdx.x*256 + threadIdx.x;
    if (e < NEDGES) atomicAdd(&cnt[col[e]], 1);
}

__global__ __launch_bounds__(256) void compute_dinv(const int* __restrict__ cnt, float* __restrict__ dinv){
    int i = blockIdx.x*256 + threadIdx.x;
    if (i < NNODES) dinv[i] = rsqrtf((float)cnt[i] + 1.0f);
}

__global__ __launch_bounds__(256) void scan_a(const int* __restrict__ cnt, int* __restrict__ offs, int* __restrict__ bsum){
    __shared__ int tmp[256];
    int tid = threadIdx.x;
    int g = blockIdx.x*256 + tid;
    int v = cnt[g];
    tmp[tid] = v;
    __syncthreads();
    for (int o=1;o<256;o<<=1){
        int a = (tid>=o)? tmp[tid-o] : 0;
        __syncthreads();
        tmp[tid] += a;
        __syncthreads();
    }
    offs[g] = tmp[tid] - v;
    if (tid==255) bsum[blockIdx.x] = tmp[255];
}

__global__ __launch_bounds__(512) void scan_b(int* __restrict__ bsum, int NB){
    __shared__ int tmp[512];
    int tid = threadIdx.x;
    int v = (tid<NB)? bsum[tid] : 0;
    tmp[tid] = v;
    __syncthreads();
    for (int o=1;o<512;o<<=1){
        int a = (tid>=o)? tmp[tid-o] : 0;
        __syncthreads();
        tmp[tid] += a;
        __syncthreads();
    }
    if (tid<NB) bsum[tid] = tmp[tid] - v;
}

__global__ __launch_bounds__(256) void scan_c(int* __restrict__ offs, const int* __restrict__ bsum){
    int g = blockIdx.x*256 + threadIdx.x;
    offs[g] += bsum[g>>8];
    if (g==0) offs[NNODES] = NEDGES;
}

__global__ __launch_bounds__(256) void fill_csr(const int* __restrict__ row, const int* __restrict__ col,
        const int* __restrict__ offs, int* __restrict__ cur, const float* __restrict__ dinv,
        int2* __restrict__ ee){
    int e = blockIdx.x*256 + threadIdx.x;
    if (e >= NEDGES) return;
    int c = col[e], r = row[e];
    int p = atomicAdd(&cur[c], 1);
    int idx = offs[c] + p;
    float w = dinv[r]*dinv[c];
    ee[idx] = make_int2(r, __float_as_int(w));
}

// ---------------- weight conversions ----------------
__global__ __launch_bounds__(256) void conv_w(const float* __restrict__ gcn_w,
        const float* __restrict__ ca_qkv_w, ushort_t* __restrict__ Wb){
    int i = blockIdx.x*256 + threadIdx.x;   // < 5*16384
    int slot = i >> 14, off = i & 16383;
    float v = (slot < 3) ? gcn_w[slot*16384 + off]
                         : ca_qkv_w[16384 + (slot-3)*16384 + off];
    Wb[i] = f2bf(v);
}

// in_w [128][16] -> bf16 padded [128][32] (zeros k>=16)
__global__ __launch_bounds__(256) void conv_wpad(const float* __restrict__ in_w, ushort_t* __restrict__ Wpad){
    int i = blockIdx.x*256 + threadIdx.x;   // < 4096
    int n = i >> 5, k = i & 31;
    Wpad[i] = (k < 16) ? f2bf(in_w[n*16 + k]) : (ushort_t)0;
}

// decoder weights: ca_out (128x128) | ff1 (512x128) | ff2 (128x512)
__global__ __launch_bounds__(256) void conv_wdec(const float* __restrict__ caout,
        const float* __restrict__ ff1, const float* __restrict__ ff2, ushort_t* __restrict__ Wd){
    int i = blockIdx.x*256 + threadIdx.x;   // < 147456
    float v;
    if (i < 16384) v = caout[i];
    else if (i < 81920) v = ff1[i - 16384];
    else v = ff2[i - 81920];
    Wd[i] = f2bf(v);
}

// ---------------- input projection via MFMA (bf16 out only) ----------------
__global__ __launch_bounds__(256) void in_proj_mfma(const float* __restrict__ x,
        const ushort_t* __restrict__ Wpad, const float* __restrict__ bias,
        ushort_t* __restrict__ hbf){
    __shared__ __align__(16) ushort_t xs[64*32];
    int tid = threadIdx.x;
    int m0 = blockIdx.x*64;
    if (tid < 128){
        short8 z = {0,0,0,0,0,0,0,0};
        *(short8*)&xs[(tid>>1)*32 + 16 + (tid&1)*8] = z;
    }
    float4 xv = *(const float4*)(x + (size_t)m0*16 + tid*4);
    uint2 pk2;
    pk2.x = (unsigned)f2bf(xv.x) | ((unsigned)f2bf(xv.y) << 16);
    pk2.y = (unsigned)f2bf(xv.z) | ((unsigned)f2bf(xv.w) << 16);
    *(uint2*)&xs[(tid>>2)*32 + (tid&3)*4] = pk2;
    __syncthreads();
    int lane = tid & 63, w = tid >> 6;
    int lr = lane & 15, lk = (lane>>4)*8;
    short8 bfrag[8];
    #pragma unroll
    for (int nt=0; nt<8; ++nt)
        bfrag[nt] = *(const short8*)&Wpad[(nt*16 + lr)*32 + lk];
    short8 a = *(const short8*)&xs[(w*16 + lr)*32 + lk];
    f32x4 acc[8];
    #pragma unroll
    for (int nt=0; nt<8; ++nt)
        acc[nt] = __builtin_amdgcn_mfma_f32_16x16x32_bf16(a, bfrag[nt], (f32x4){0,0,0,0}, 0, 0, 0);
    size_t orow = (size_t)m0 + w*16 + (lane>>4)*4;
    #pragma unroll
    for (int nt=0; nt<8; ++nt){
        int col = nt*16 + lr;
        float bv = bias[col];
        #pragma unroll
        for (int r=0; r<4; ++r)
            hbf[(orow + r)*128 + col] = f2bf(acc[nt][r] + bv);
    }
}

// ---------------- MFMA GEMM, swapped operands (D rows = n, cols = m) --------------
// W staged in LDS (row stride 136 ushorts). 32 m-rows/wave, 128 rows/block.
// Lane owns output row m = m0 + t*16 + (lane&15); n = nt*16 + (lane>>4)*4 + r -> uint2 stores.
__global__ __launch_bounds__(256) void gemm_mfma(const ushort_t* __restrict__ A,
        const ushort_t* __restrict__ Wb, const float* __restrict__ bias, ushort_t* __restrict__ out){
    __shared__ __align__(16) ushort_t wl[128*136];
    int tid = threadIdx.x;
    #pragma unroll
    for (int i=0;i<8;++i){
        int elem = tid*8 + i*2048;
        int row = elem >> 7, k = elem & 127;
        *(short8*)&wl[row*136 + k] = *(const short8*)&Wb[elem];
    }
    __syncthreads();
    int lane = tid & 63, wave = tid >> 6;
    int m0 = blockIdx.x*128 + wave*32;
    int lr = lane & 15, hi4 = lane >> 4;
    int lk = hi4 * 8;
    f32x4 acc[2][8];
    #pragma unroll
    for (int t=0;t<2;++t)
        #pragma unroll
        for (int nt=0;nt<8;++nt) acc[t][nt] = (f32x4){0.f,0.f,0.f,0.f};
    const ushort_t* arow0 = A + (size_t)(m0 + lr)*128 + lk;
    const ushort_t* arow1 = arow0 + 16*128;
    #pragma unroll
    for (int kc=0; kc<4; ++kc){
        short8 h0 = *(const short8*)(arow0 + kc*32);
        short8 h1 = *(const short8*)(arow1 + kc*32);
        #pragma unroll
        for (int nt=0; nt<8; ++nt){
            short8 wf = *(const short8*)&wl[(nt*16 + lr)*136 + kc*32 + lk];
            acc[0][nt] = __builtin_amdgcn_mfma_f32_16x16x32_bf16(wf, h0, acc[0][nt], 0, 0, 0);
            acc[1][nt] = __builtin_amdgcn_mfma_f32_16x16x32_bf16(wf, h1, acc[1][nt], 0, 0, 0);
        }
    }
    #pragma unroll
    for (int nt=0; nt<8; ++nt){
        int n0 = nt*16 + hi4*4;
        float b0=0.f,b1=0.f,b2=0.f,b3=0.f;
        if (bias){
            float4 bv = *(const float4*)&bias[n0];
            b0=bv.x; b1=bv.y; b2=bv.z; b3=bv.w;
        }
        #pragma unroll
        for (int t=0; t<2; ++t){
            size_t m = (size_t)m0 + t*16 + lr;
            uint2 pk;
            pk.x = (unsigned)f2bf(acc[t][nt][0]+b0) | ((unsigned)f2bf(acc[t][nt][1]+b1)<<16);
            pk.y = (unsigned)f2bf(acc[t][nt][2]+b2) | ((unsigned)f2bf(acc[t][nt][3]+b3)<<16);
            *(uint2*)&out[m*128 + n0] = pk;
        }
    }
}

// ---------------- GCN aggregate: flat 64-lane x 2-dim, serial edge loop + LN ----------
__global__ __launch_bounds__(256) void gcn_agg(ushort_t* __restrict__ hbf, const ushort_t* __restrict__ hwbf,
        const int* __restrict__ offs, const int2* __restrict__ ee,
        const float* __restrict__ dinv, const float* __restrict__ bias,
        const float* __restrict__ lnw, const float* __restrict__ lnb, int last){
    int node = blockIdx.x*4 + (threadIdx.x>>6);
    int lane = threadIdx.x & 63;
    const unsigned* hwu = (const unsigned*)hwbf;
    unsigned* hbu = (unsigned*)hbf;
    unsigned su = hwu[(size_t)node*64 + lane];
    unsigned rv = 0;
    if (!last) rv = hbu[(size_t)node*64 + lane];   // bf16 residual, issued early
    float di = dinv[node];
    float sw = di*di;
    float ax = sw*bfu_lo(su), ay = sw*bfu_hi(su);
    float bx = 0.f, by = 0.f;
    int e0 = offs[node], e1 = offs[node+1];
    int e = e0;
    for (; e + 2 <= e1; e += 2){
        int2 p0 = ee[e];
        int2 p1 = ee[e+1];
        unsigned u0 = hwu[(size_t)p0.x*64 + lane];
        unsigned u1 = hwu[(size_t)p1.x*64 + lane];
        float w0 = __int_as_float(p0.y), w1 = __int_as_float(p1.y);
        ax += w0*bfu_lo(u0); ay += w0*bfu_hi(u0);
        bx += w1*bfu_lo(u1); by += w1*bfu_hi(u1);
    }
    if (e < e1){
        int2 p0 = ee[e];
        unsigned u0 = hwu[(size_t)p0.x*64 + lane];
        float w0 = __int_as_float(p0.y);
        ax += w0*bfu_lo(u0); ay += w0*bfu_hi(u0);
    }
    ax += bx; ay += by;
    float2 b2 = ((const float2*)bias)[lane];
    ax += b2.x; ay += b2.y;
    float s = ax + ay;
    for (int o=32;o>0;o>>=1) s += __shfl_xor(s,o);
    float mean = s*(1.f/128.f);
    float dx = ax-mean, dy = ay-mean;
    float var = dx*dx + dy*dy;
    for (int o=32;o>0;o>>=1) var += __shfl_xor(var,o);
    float rs = rsqrtf(var*(1.f/128.f) + 1e-5f);
    float2 w2 = ((const float2*)lnw)[lane], lb2 = ((const float2*)lnb)[lane];
    float yx = dx*rs*w2.x + lb2.x;
    float yy = dy*rs*w2.y + lb2.y;
    if (!last){
        yx = fmaxf(yx,0.f) + bfu_lo(rv);
        yy = fmaxf(yy,0.f) + bfu_hi(rv);
    }
    hbu[(size_t)node*64 + lane] = (unsigned)f2bf(yx) | ((unsigned)f2bf(yy)<<16);
}

// ---------------- decoder MFMA GEMM: flexible K (mult of 128), NO via grid.y ----------------
// flags: 1=accumulate into out(fp32), 2=relu, 4=write outbf, 8=write out fp32
__global__ __launch_bounds__(256) void dec_gemm(const ushort_t* __restrict__ A,
        const ushort_t* __restrict__ Wb, const float* __restrict__ bias,
        float* __restrict__ out, ushort_t* __restrict__ outbf,
        int K, int NO, int flags){
    int lane = threadIdx.x & 63, wave = threadIdx.x >> 6;
    int m0 = blockIdx.x*64 + wave*16;
    int n0 = blockIdx.y*128;
    int lr = lane & 15, lk = (lane>>4)*8;
    f32x4 acc[8];
    #pragma unroll
    for (int nt=0; nt<8; ++nt) acc[nt] = (f32x4){0.f,0.f,0.f,0.f};
    for (int ko = 0; ko < K; ko += 128){
        short8 bfrag[4][8];
        #pragma unroll
        for (int nt=0; nt<8; ++nt)
            #pragma unroll
            for (int kc=0; kc<4; ++kc)
                bfrag[kc][nt] = *(const short8*)&Wb[(size_t)(n0 + nt*16 + lr)*K + ko + kc*32 + lk];
        const ushort_t* arow = A + (size_t)(m0 + lr)*K + ko + lk;
        #pragma unroll
        for (int kc=0; kc<4; ++kc){
            short8 a = *(const short8*)(arow + kc*32);
            #pragma unroll
            for (int nt=0; nt<8; ++nt)
                acc[nt] = __builtin_amdgcn_mfma_f32_16x16x32_bf16(a, bfrag[kc][nt], acc[nt], 0, 0, 0);
        }
    }
    int orow0 = m0 + (lane>>4)*4;
    #pragma unroll
    for (int nt=0; nt<8; ++nt){
        int col = n0 + nt*16 + lr;
        float bv = bias[col];
        #pragma unroll
        for (int r=0; r<4; ++r){
            size_t idx = (size_t)(orow0 + r)*NO + col;
            float val = acc[nt][r] + bv;
            if (flags & 2) val = fmaxf(val, 0.f);
            if (flags & 1) val += out[idx];
            if (flags & 8) out[idx] = val;
            if (flags & 4) outbf[idx] = f2bf(val);
        }
    }
}

// ---------------- decoder small ops ----------------
__global__ __launch_bounds__(256) void ln_rows(const float* __restrict__ x, float* __restrict__ y,
        const float* __restrict__ w, const float* __restrict__ b){
    int r = blockIdx.x*4 + (threadIdx.x>>6);
    int lane = threadIdx.x & 63;
    const float2* x2 = (const float2*)(x + (size_t)r*128);
    float2 v = x2[lane];
    float s = v.x+v.y;
    for (int o=32;o>0;o>>=1) s += __shfl_xor(s,o);
    float mean = s*(1.f/128.f);
    float dx=v.x-mean, dy=v.y-mean;
    float var = dx*dx+dy*dy;
    for (int o=32;o>0;o>>=1) var += __shfl_xor(var,o);
    float rs = rsqrtf(var*(1.f/128.f) + 1e-5f);
    float2 w2=((const float2*)w)[lane], b2=((const float2*)b)[lane];
    ((float2*)(y + (size_t)r*128))[lane] = make_float2(dx*rs*w2.x+b2.x, dy*rs*w2.y+b2.y);
}

__global__ __launch_bounds__(256) void ln_rows_bf(const float* __restrict__ x, ushort_t* __restrict__ y,
        const float* __restrict__ w, const float* __restrict__ b){
    int r = blockIdx.x*4 + (threadIdx.x>>6);
    int lane = threadIdx.x & 63;
    const float2* x2 = (const float2*)(x + (size_t)r*128);
    float2 v = x2[lane];
    float s = v.x+v.y;
    for (int o=32;o>0;o>>=1) s += __shfl_xor(s,o);
    float mean = s*(1.f/128.f);
    float dx=v.x-mean, dy=v.y-mean;
    float var = dx*dx+dy*dy;
    for (int o=32;o>0;o>>=1) var += __shfl_xor(var,o);
    float rs = rsqrtf(var*(1.f/128.f) + 1e-5f);
    float2 w2=((const float2*)w)[lane], b2=((const float2*)b)[lane];
    float yx = dx*rs*w2.x+b2.x, yy = dy*rs*w2.y+b2.y;
    ((unsigned*)y)[(size_t)r*64 + lane] = (unsigned)f2bf(yx) | ((unsigned)f2bf(yy)<<16);
}

// naive fp32 gemm for 12-row prefix. flags: 1=acc, 2=relu
__global__ __launch_bounds__(256) void small_gemm(const float* __restrict__ x, const float* __restrict__ W,
        const float* __restrict__ bias, float* __restrict__ out, int R, int K, int NO, int flags){
    int idx = blockIdx.x*256 + threadIdx.x;
    if (idx >= R*NO) return;
    int r = idx / NO, n = idx - r*NO;
    const float4* xr = (const float4*)(x + (size_t)r*K);
    const float4* wr = (const float4*)(W + (size_t)n*K);
    float a = bias ? bias[n] : 0.0f;
    int K4 = K>>2;
    for (int k=0;k<K4;++k){
        float4 xv = xr[k], wv = wr[k];
        a += xv.x*wv.x + xv.y*wv.y + xv.z*wv.z + xv.w*wv.w;
    }
    if (flags & 2) a = fmaxf(a, 0.f);
    if (flags & 1) a += out[idx];
    out[idx] = a;
}

__global__ __launch_bounds__(256) void copy12(const float* __restrict__ cq, float* __restrict__ t12){
    int i = blockIdx.x*256 + threadIdx.x;   // < 1536
    t12[i] = cq[i];
}

__global__ __launch_bounds__(256) void bcast_t(const float* __restrict__ t12, float* __restrict__ t_full){
    int idx = blockIdx.x*256 + threadIdx.x;  // < 1536*128
    int r = idx >> 7;
    t_full[idx] = t12[(r % 12)*128 + (idx & 127)];
}

__global__ __launch_bounds__(64) void self_attn12(const float* __restrict__ qkv, float* __restrict__ out){
    int hh = blockIdx.x;
    int lane = threadIdx.x;
    __shared__ float q[12][32], k[12][32], v[12][32], sc[12][12];
    for (int idx = lane; idx < 12*32; idx += 64){
        int c = idx>>5, d = idx&31;
        size_t base = (size_t)c*384 + hh*32 + d;
        q[c][d] = qkv[base] * 0.17677669529663687f;
        k[c][d] = qkv[base+128];
        v[c][d] = qkv[base+256];
    }
    __syncthreads();
    for (int p = lane; p < 144; p += 64){
        int qi = p/12, ki = p%12;
        float a = 0;
        #pragma unroll
        for (int d=0; d<32; ++d) a += q[qi][d]*k[ki][d];
        sc[qi][ki] = a;
    }
    __syncthreads();
    if (lane < 12){
        float m = -1e30f;
        for (int j=0;j<12;++j) m = fmaxf(m, sc[lane][j]);
        float sum=0;
        for (int j=0;j<12;++j){ float e=__expf(sc[lane][j]-m); sc[lane][j]=e; sum+=e; }
        float inv=1.f/sum;
        for (int j=0;j<12;++j) sc[lane][j]*=inv;
    }
    __syncthreads();
    for (int p = lane; p < 384; p += 64){
        int c = p>>5, d = p&31;
        float a=0;
        #pragma unroll
        for (int j=0;j<12;++j) a += sc[c][j]*v[j][d];
        out[(size_t)c*128 + hh*32 + d] = a;
    }
}

// ---------------- flash cross-attention, k-split, MFMA; shared q12 ----------------
__global__ __launch_bounds__(512) void cross_attn_part(const float* __restrict__ q12,
        const ushort_t* __restrict__ K, const ushort_t* __restrict__ V,
        float* __restrict__ opart, float2* __restrict__ mlpart){
    __shared__ __align__(16) ushort_t qs[16*136];
    __shared__ __align__(16) unsigned char uni[128*136*2];
    __shared__ __align__(16) ushort_t pbf[4*16*136];
    __shared__ float2 ml[48];
    float* s32 = (float*)uni;
    ushort_t* vt = (ushort_t*)uni;

    int tid = threadIdx.x;
    int b = blockIdx.x / NSPLIT, sp = blockIdx.x % NSPLIT;
    int k0 = sp * CHUNK;
    int lane = tid & 63, w = tid >> 6;
    int lr = lane & 15, hi8 = (lane >> 4) * 8;

    const unsigned* Vu = (const unsigned*)V + ((size_t)b*1000 + k0)*64;
    unsigned vreg[16];
    #pragma unroll
    for (int j=0;j<15;++j) vreg[j] = Vu[tid + j*512];
    if (tid < 320) vreg[15] = Vu[tid + 7680];

    for (int i = tid; i < 16*128; i += 512){
        int r = i >> 7, c = i & 127;
        ushort_t v = 0;
        if (r < 12) v = f2bf(q12[r*128 + c] * 0.17677669529663687f);
        qs[r*136 + c] = v;
    }
    for (int i = tid; i < 4352; i += 512) ((unsigned*)pbf)[i] = 0;
    __syncthreads();

    {
        int krow = k0 + w*16 + lr; if (krow > k0 + 124) krow = k0 + 124;
        const ushort_t* Krow = K + ((size_t)b*1000 + krow)*128 + hi8;
        #pragma unroll
        for (int h=0; h<4; ++h){
            short8 kf = *(const short8*)(Krow + h*32);
            short8 qf = *(const short8*)&qs[lr*136 + h*32 + hi8];
            f32x4 d = __builtin_amdgcn_mfma_f32_16x16x32_bf16(qf, kf, (f32x4){0,0,0,0}, 0, 0, 0);
            int qbase = (lane>>4)*4;
            #pragma unroll
            for (int r=0; r<4; ++r){
                int qq = qbase + r;
                if (qq < 12) s32[(h*12+qq)*130 + w*16 + lr] = d[r];
            }
        }
    }
    __syncthreads();

    if (tid < 192){
        int hq = tid >> 2, sub = tid & 3;
        int h = hq / 12, qq = hq - h*12;
        float m = -1e30f;
        for (int kk = sub; kk < CHUNK; kk += 4) m = fmaxf(m, s32[hq*130 + kk]);
        m = fmaxf(m, __shfl_xor(m, 1));
        m = fmaxf(m, __shfl_xor(m, 2));
        float l = 0.f;
        for (int kk = sub; kk < CHUNK; kk += 4){
            float e = __expf(s32[hq*130 + kk] - m);
            l += e;
            pbf[(h*16+qq)*136 + kk] = f2bf(e);
        }
        l += __shfl_xor(l, 1);
        l += __shfl_xor(l, 2);
        if (sub == 0) ml[hq] = make_float2(m, l);
    }
    __syncthreads();

    #pragma unroll
    for (int j=0;j<15;++j){
        int i = tid + j*512;
        int kk = i >> 6, dp = (i & 63)*2;
        unsigned u = vreg[j];
        vt[dp*136 + kk]     = (ushort_t)(u & 0xFFFF);
        vt[(dp+1)*136 + kk] = (ushort_t)(u >> 16);
    }
    if (tid < 320){
        int i = tid + 7680;
        int kk = i >> 6, dp = (i & 63)*2;
        unsigned u = vreg[15];
        vt[dp*136 + kk]     = (ushort_t)(u & 0xFFFF);
        vt[(dp+1)*136 + kk] = (ushort_t)(u >> 16);
    }
    if (tid < 384){
        int dp = tid / 3, kk = 125 + tid % 3;
        vt[dp*136 + kk] = 0;
    }
    __syncthreads();

    {
        int h = w >> 1;
        f32x4 acc = (f32x4){0,0,0,0};
        #pragma unroll
        for (int kc=0; kc<4; ++kc){
            short8 pf = *(const short8*)&pbf[(h*16+lr)*136 + kc*32 + hi8];
            short8 vf = *(const short8*)&vt[(w*16+lr)*136 + kc*32 + hi8];
            acc = __builtin_amdgcn_mfma_f32_16x16x32_bf16(pf, vf, acc, 0, 0, 0);
        }
        int qbase = (lane>>4)*4;
        float* ob = opart + ((size_t)(b*NSPLIT+sp)*12)*128;
        #pragma unroll
        for (int r=0; r<4; ++r){
            int qq = qbase + r;
            if (qq < 12) ob[(size_t)qq*128 + w*16 + lr] = acc[r];
        }
    }
    if (tid < 48) mlpart[(size_t)(b*NSPLIT+sp)*48 + tid] = ml[tid];
}

__global__ __launch_bounds__(256) void cross_attn_comb(const float* __restrict__ opart,
        const float* __restrict__ mlpart, ushort_t* __restrict__ attbf){
    int b = blockIdx.x, tid = threadIdx.x;
    __shared__ float mls[NSPLIT*48*2];
    for (int i = tid; i < NSPLIT*48*2; i += 256) mls[i] = mlpart[(size_t)b*NSPLIT*96 + i];
    __syncthreads();
    for (int p = tid; p < 1536; p += 256){
        int qq = p >> 7, dp = p & 127, h = dp >> 5, hq = h*12 + qq;
        float M = -1e30f;
        #pragma unroll
        for (int sp=0; sp<NSPLIT; ++sp) M = fmaxf(M, mls[sp*96 + hq*2]);
        float L = 0.f, O = 0.f;
        #pragma unroll
        for (int sp=0; sp<NSPLIT; ++sp){
            float wgt = __expf(mls[sp*96 + hq*2] - M);
            L += wgt * mls[sp*96 + hq*2 + 1];
            O += wgt * opart[((size_t)(b*NSPLIT+sp)*12 + qq)*128 + dp];
        }
        attbf[((size_t)b*12 + qq)*128 + dp] = f2bf(O / L);
    }
}

__global__ __launch_bounds__(256) void final_out(const float* __restrict__ t,
        const float* __restrict__ lw, const float* __restrict__ lb,
        const float* __restrict__ ow, const float* __restrict__ ob, float* __restrict__ out){
    int r = blockIdx.x*4 + (threadIdx.x>>6);
    int lane = threadIdx.x & 63;
    const float2* x2 = (const float2*)(t + (size_t)r*128);
    float2 v = x2[lane];
    float s = v.x+v.y;
    for (int o=32;o>0;o>>=1) s += __shfl_xor(s,o);
    float mean = s*(1.f/128.f);
    float dx=v.x-mean, dy=v.y-mean;
    float var = dx*dx+dy*dy;
    for (int o=32;o>0;o>>=1) var += __shfl_xor(var,o);
    float rs = rsqrtf(var*(1.f/128.f)+1e-5f);
    float2 w2=((const float2*)lw)[lane], b2=((const float2*)lb)[lane];
    float2 o2=((const float2*)ow)[lane];
    float d = (dx*rs*w2.x+b2.x)*o2.x + (dy*rs*w2.y+b2.y)*o2.y;
    for (int o=32;o>0;o>>=1) d += __shfl_xor(d,o);
    if (lane==0) out[r] = d + ob[0];
}

extern "C" void kernel_launch(void* const* d_in, const int* in_sizes, int n_in,
                              void* d_out, int out_size, void* d_ws, size_t ws_size,
                              hipStream_t stream){
    (void)in_sizes; (void)n_in; (void)out_size; (void)ws_size;
    const float* x        = (const float*)d_in[0];
    const int*   eidx     = (const int*)d_in[1];
    const float* in_w     = (const float*)d_in[3];
    const float* in_b     = (const float*)d_in[4];
    const float* gcn_w    = (const float*)d_in[5];
    const float* gcn_b    = (const float*)d_in[6];
    const float* ln_w     = (const float*)d_in[7];
    const float* ln_b     = (const float*)d_in[8];
    const float* cq       = (const float*)d_in[9];
    const float* sa_qkv_w = (const float*)d_in[10];
    const float* sa_qkv_b = (const float*)d_in[11];
    const float* sa_out_w = (const float*)d_in[12];
    const float* sa_out_b = (const float*)d_in[13];
    const float* ca_qkv_w = (const float*)d_in[14];
    const float* ca_qkv_b = (const float*)d_in[15];
    const float* ca_out_w = (const float*)d_in[16];
    const float* ca_out_b = (const float*)d_in[17];
    const float* n1w=(const float*)d_in[18]; const float* n1b=(const float*)d_in[19];
    const float* n2w=(const float*)d_in[20]; const float* n2b=(const float*)d_in[21];
    const float* n3w=(const float*)d_in[22]; const float* n3b=(const float*)d_in[23];
    const float* ff1w=(const float*)d_in[24]; const float* ff1b=(const float*)d_in[25];
    const float* ff2w=(const float*)d_in[26]; const float* ff2b=(const float*)d_in[27];
    const float* opln_w=(const float*)d_in[28]; const float* opln_b=(const float*)d_in[29];
    const float* opw=(const float*)d_in[30]; const float* opb=(const float*)d_in[31];
    float* out = (float*)d_out;

    char* base = (char*)d_ws;
    size_t off = 0;
    auto alloc = [&](size_t bytes)->void*{
        void* r = base + off; off += (bytes + 255) & ~(size_t)255; return r;
    };
    ushort_t* hbf   = (ushort_t*)alloc((size_t)NNODES*DD*2);
    ushort_t* kbf   = (ushort_t*)alloc((size_t)NNODES*DD*2);  // also hwbf during GCN loop
    ushort_t* vbf   = (ushort_t*)alloc((size_t)NNODES*DD*2);
    ushort_t* Wb    = (ushort_t*)alloc((size_t)5*DD*DD*2);
    ushort_t* Wpad  = (ushort_t*)alloc((size_t)DD*32*2);
    ushort_t* Wdec  = (ushort_t*)alloc((size_t)147456*2);
    float*    dinv  = (float*)alloc((size_t)NNODES*4);
    int*      cnt   = (int*)  alloc((size_t)NNODES*4);
    int*      offs  = (int*)  alloc((size_t)(NNODES+1)*4);
    int*      bsum  = (int*)  alloc(512*4);
    int2*     ee    = (int2*) alloc((size_t)NEDGES*8);
    float*    t12   = (float*)alloc((size_t)12*DD*4);
    float*    tn12  = (float*)alloc((size_t)12*DD*4);
    float*    sq12  = (float*)alloc((size_t)12*384*4);
    float*    att12 = (float*)alloc((size_t)12*DD*4);
    float*    q12   = (float*)alloc((size_t)12*DD*4);
    float*    tfull = (float*)alloc((size_t)NROWS*DD*4);
    ushort_t* tnbf  = (ushort_t*)alloc((size_t)NROWS*DD*2);
    ushort_t* attbf = (ushort_t*)alloc((size_t)NROWS*DD*2);
    ushort_t* ffhbf = (ushort_t*)alloc((size_t)NROWS*512*2);
    float*    opart = (float*)alloc((size_t)BB*NSPLIT*12*128*4);
    float2*   mlprt = (float2*)alloc((size_t)BB*NSPLIT*48*8);
    ushort_t* hwbf  = kbf;

    const int* erow = eidx;
    const int* ecol = eidx + NEDGES;

    // CSR build (once, reused by all 3 GCN layers)
    hipMemsetAsync(cnt, 0, (size_t)NNODES*4, stream);
    count_edges<<<NEDGES/256, 256, 0, stream>>>(ecol, cnt);
    compute_dinv<<<NNODES/256, 256, 0, stream>>>(cnt, dinv);
    scan_a<<<NNODES/256, 256, 0, stream>>>(cnt, offs, bsum);
    scan_b<<<1, 512, 0, stream>>>(bsum, NNODES/256);
    scan_c<<<NNODES/256, 256, 0, stream>>>(offs, bsum);
    hipMemsetAsync(cnt, 0, (size_t)NNODES*4, stream);
    fill_csr<<<NEDGES/256, 256, 0, stream>>>(erow, ecol, offs, cnt, dinv, ee);

    conv_w<<<5*DD*DD/256, 256, 0, stream>>>(gcn_w, ca_qkv_w, Wb);
    conv_wpad<<<DD*32/256, 256, 0, stream>>>(in_w, Wpad);
    conv_wdec<<<576, 256, 0, stream>>>(ca_out_w, ff1w, ff2w, Wdec);

    // node pipeline (residual lives in hbf as bf16)
    in_proj_mfma<<<NNODES/64, 256, 0, stream>>>(x, Wpad, in_b, hbf);
    for (int i=0;i<3;++i){
        gemm_mfma<<<NNODES/128, 256, 0, stream>>>(hbf, Wb + (size_t)i*DD*DD, nullptr, hwbf);
        gcn_agg<<<NNODES/4, 256, 0, stream>>>(hbf, hwbf, offs, ee, dinv,
                gcn_b + (size_t)i*DD, ln_w + (size_t)i*DD, ln_b + (size_t)i*DD, i==2);
    }
    // cross-attn K,V projections (bf16 out)
    gemm_mfma<<<NNODES/128, 256, 0, stream>>>(hbf, Wb + (size_t)3*DD*DD, ca_qkv_b + DD,   kbf);
    gemm_mfma<<<NNODES/128, 256, 0, stream>>>(hbf, Wb + (size_t)4*DD*DD, ca_qkv_b + 2*DD, vbf);

    // ---- decoder: batch-invariant 12-row prefix (fp32, exact) ----
    ln_rows<<<3, 256, 0, stream>>>(cq, tn12, n1w, n1b);
    small_gemm<<<18, 256, 0, stream>>>(tn12, sa_qkv_w, sa_qkv_b, sq12, 12, 128, 384, 0);
    self_attn12<<<4, 64, 0, stream>>>(sq12, att12);
    copy12<<<6, 256, 0, stream>>>(cq, t12);
    small_gemm<<<6, 256, 0, stream>>>(att12, sa_out_w, sa_out_b, t12, 12, 128, 128, 1);
    ln_rows<<<3, 256, 0, stream>>>(t12, tn12, n2w, n2b);
    small_gemm<<<6, 256, 0, stream>>>(tn12, ca_qkv_w, ca_qkv_b, q12, 12, 128, 128, 0);

    // ---- per-batch: cross-attention + FF (bf16 MFMA) ----
    cross_attn_part<<<BB*NSPLIT, 512, 0, stream>>>(q12, kbf, vbf, opart, mlprt);
    cross_attn_comb<<<BB, 256, 0, stream>>>(opart, (const float*)mlprt, attbf);
    bcast_t<<<NROWS*DD/256, 256, 0, stream>>>(t12, tfull);
    dim3 g24_1(24,1), g24_4(24,4);
    dec_gemm<<<g24_1, 256, 0, stream>>>(attbf, Wdec, ca_out_b, tfull, nullptr, 128, 128, 1|8);
    ln_rows_bf<<<NROWS/4, 256, 0, stream>>>(tfull, tnbf, n3w, n3b);
    dec_gemm<<<g24_4, 256, 0, stream>>>(tnbf, Wdec + 16384, ff1b, nullptr, ffhbf, 128, 512, 2|4);
    dec_gemm<<<g24_1, 256, 0, stream>>>(ffhbf, Wdec + 81920, ff2b, tfull, nullptr, 512, 128, 1|8);
    final_out<<<NROWS/4, 256, 0, stream>>>(tfull, opln_w, opln_b, opw, opb, out);
}